// Round 6
// baseline (1025.063 us; speedup 1.0000x reference)
//
#include <hip/hip_runtime.h>
#include <hip/hip_fp16.h>
#include <math.h>

#define N_NODES 100000
#define N_EDGES 1000000
#define F_IN    128
#define HID     64
#define HEADS   4
#define NCLS    4
#define SCAN_BLK 98   // ceil(N_NODES / 1024)

// ---------------- helpers ----------------
__device__ __forceinline__ float wsum(float v) {
#pragma unroll
  for (int o = 32; o > 0; o >>= 1) v += __shfl_xor(v, o, 64);
  return v;
}
struct Half4 { __half2 a, b; };
__device__ __forceinline__ float4 ld_half4(const __half* p) {
  Half4 h = *reinterpret_cast<const Half4*>(p);
  float2 f0 = __half22float2(h.a), f1 = __half22float2(h.b);
  return make_float4(f0.x, f0.y, f1.x, f1.y);
}

// ---------------- CSR build (by dst) ----------------
__global__ void k_zero_cnt(int* __restrict__ cnt) {
  int i = blockIdx.x * 256 + threadIdx.x;
  if (i < N_NODES) cnt[i] = 0;
}
__global__ void k_hist(const int* __restrict__ dst, int* __restrict__ cnt) {
  int e = blockIdx.x * 256 + threadIdx.x;
  if (e < N_EDGES) atomicAdd(&cnt[dst[e]], 1);
}
__global__ __launch_bounds__(256) void k_scan1(const int* __restrict__ cnt,
                                               int* __restrict__ partial,
                                               int* __restrict__ bsum) {
  __shared__ int lds[256];
  int t = threadIdx.x;
  int base = blockIdx.x * 1024 + t * 4;
  int v0 = (base + 0 < N_NODES) ? cnt[base + 0] : 0;
  int v1 = (base + 1 < N_NODES) ? cnt[base + 1] : 0;
  int v2 = (base + 2 < N_NODES) ? cnt[base + 2] : 0;
  int v3 = (base + 3 < N_NODES) ? cnt[base + 3] : 0;
  int s = v0 + v1 + v2 + v3;
  lds[t] = s;
  __syncthreads();
  for (int o = 1; o < 256; o <<= 1) {
    int x = (t >= o) ? lds[t - o] : 0;
    __syncthreads();
    lds[t] += x;
    __syncthreads();
  }
  int excl = lds[t] - s;
  if (base + 0 < N_NODES) partial[base + 0] = excl;
  if (base + 1 < N_NODES) partial[base + 1] = excl + v0;
  if (base + 2 < N_NODES) partial[base + 2] = excl + v0 + v1;
  if (base + 3 < N_NODES) partial[base + 3] = excl + v0 + v1 + v2;
  if (t == 255) bsum[blockIdx.x] = lds[255];
}
__global__ void k_scan2(int* __restrict__ bsum) {  // 1 block, 128 threads
  __shared__ int lds[128];
  int t = threadIdx.x;
  int v = (t < SCAN_BLK) ? bsum[t] : 0;
  lds[t] = v;
  __syncthreads();
  for (int o = 1; o < 128; o <<= 1) {
    int x = (t >= o) ? lds[t - o] : 0;
    __syncthreads();
    lds[t] += x;
    __syncthreads();
  }
  if (t < SCAN_BLK) bsum[t] = lds[t] - v;  // exclusive
}
__global__ void k_scan3(const int* __restrict__ partial, const int* __restrict__ bsum,
                        int* __restrict__ row_ptr, int* __restrict__ cursor) {
  int i = blockIdx.x * 256 + threadIdx.x;
  if (i < N_NODES) {
    int v = partial[i] + bsum[i >> 10];
    row_ptr[i] = v;
    cursor[i] = v;
  }
  if (i == 0) row_ptr[N_NODES] = N_EDGES;
}
__global__ void k_fill(const int* __restrict__ src, const int* __restrict__ dst,
                       const float* __restrict__ ew, int* __restrict__ cursor,
                       int* __restrict__ csr_src, float* __restrict__ csr_w) {
  int e = blockIdx.x * 256 + threadIdx.x;
  if (e >= N_EDGES) return;
  int d = dst[e];
  int p = atomicAdd(&cursor[d], 1);
  csr_src[p] = src[e];
  csr_w[p] = ew[e];
}

// ---------------- dense: xw16 = half(x@gcn_W) ; xp = x@proj_W + proj_b ----------
__global__ __launch_bounds__(128) void k_in_gemm(
    const float* __restrict__ x, const float* __restrict__ gcn_W,
    const float* __restrict__ proj_W, const float* __restrict__ proj_b,
    __half* __restrict__ xw16, float* __restrict__ xp) {
  int f = threadIdx.x & 63;
  bool is_proj = threadIdx.x >= 64;
  const float* W = is_proj ? proj_W : gcn_W;
  int n0 = blockIdx.x * 8;
  float acc[8] = {0.f,0.f,0.f,0.f,0.f,0.f,0.f,0.f};
  for (int k = 0; k < F_IN; ++k) {
    float w = W[k * HID + f];
#pragma unroll
    for (int j = 0; j < 8; ++j) acc[j] += x[(size_t)(n0 + j) * F_IN + k] * w;
  }
  if (is_proj) {
    float b = proj_b[f];
#pragma unroll
    for (int j = 0; j < 8; ++j) xp[(size_t)(n0 + j) * HID + f] = acc[j] + b;
  } else {
#pragma unroll
    for (int j = 0; j < 8; ++j) xw16[(size_t)(n0 + j) * HID + f] = __float2half(acc[j]);
  }
}

// ---------------- GCN: deg/dinv from CSR (no atomics) ----------------
__global__ void k_deg(const int* __restrict__ row_ptr, const float* __restrict__ csr_w,
                      float* __restrict__ dinv) {
  int n = blockIdx.x * 256 + threadIdx.x;
  if (n >= N_NODES) return;
  float deg = 1.0f;  // self-loop weight
  int end = row_ptr[n + 1];
  for (int i = row_ptr[n]; i < end; ++i) deg += csr_w[i];
  dinv[n] = rsqrtf(deg);  // deg >= 1 always
}

// pull-gather + LN + relu + residual, one wave per node
__global__ __launch_bounds__(256) void k_gcn_fused(
    const int* __restrict__ row_ptr, const int* __restrict__ csr_src,
    const float* __restrict__ csr_w, const float* __restrict__ dinv,
    const __half* __restrict__ xw16, const float* __restrict__ xp,
    const float* __restrict__ gcn_b, const float* __restrict__ g,
    const float* __restrict__ bb, float* __restrict__ h_init) {
  int n = blockIdx.x * 4 + (threadIdx.x >> 6);
  int lane = threadIdx.x & 63;
  float di = dinv[n];
  float acc = di * di * __half2float(xw16[(size_t)n * HID + lane]);  // self loop
  int beg = row_ptr[n], end = row_ptr[n + 1];
  for (int i = beg; i < end; ++i) {
    int s = csr_src[i];
    float nrm = dinv[s] * csr_w[i] * di;
    acc += nrm * __half2float(xw16[(size_t)s * HID + lane]);
  }
  float v = acc + gcn_b[lane];
  float mu = wsum(v) * (1.f / HID);
  float dv = v - mu;
  float var = wsum(dv * dv) * (1.f / HID);
  float h = dv * rsqrtf(var + 1e-5f) * g[lane] + bb[lane];
  h = h > 0.f ? h : 0.f;
  h_init[(size_t)n * HID + lane] = h + xp[(size_t)n * HID + lane];
}

// ---------------- GATv2 linear: xl = h@Wl, xr = h@Wr (fp16 out, each [N,256]) ----
__global__ __launch_bounds__(512) void k_gat_gemm(
    const float* __restrict__ h, const float* __restrict__ Wl,
    const float* __restrict__ Wr, __half* __restrict__ xl, __half* __restrict__ xr) {
  int f = threadIdx.x & 255;
  bool right = threadIdx.x >= 256;
  const float* W = right ? Wr : Wl;
  __half* out = right ? xr : xl;
  int n0 = blockIdx.x * 8;
  float acc[8] = {0.f,0.f,0.f,0.f,0.f,0.f,0.f,0.f};
  for (int k = 0; k < HID; ++k) {
    float w = W[k * 256 + f];
#pragma unroll
    for (int j = 0; j < 8; ++j) acc[j] += h[(size_t)(n0 + j) * HID + k] * w;
  }
#pragma unroll
  for (int j = 0; j < 8; ++j) out[(size_t)(n0 + j) * 256 + f] = __float2half(acc[j]);
}

// ---------------- GATv2 fused: softmax (no max shift) + aggregate + mean + LN ---
// One wave per dst node. Lane holds feats 4*lane..4*lane+3 of [H*C]=256; head = lane>>4.
// Score magnitudes are bounded (|score| << 88), so exp() without max-shift equals
// shifted softmax exactly (shift invariance); removes 1 exp + fmax + rescale/edge.
__global__ __launch_bounds__(256) void k_gat_fused(
    const int* __restrict__ row_ptr, const int* __restrict__ csr_src,
    const __half* __restrict__ xl, const __half* __restrict__ xr,
    const float* __restrict__ att, const float* __restrict__ gat_b,
    const float* __restrict__ g, const float* __restrict__ bb,
    const float* __restrict__ h_init, float* __restrict__ h2,
    __half* __restrict__ h2_16) {
  int n = blockIdx.x * 4 + (threadIdx.x >> 6);
  int lane = threadIdx.x & 63;
  float4 atv = *reinterpret_cast<const float4*>(att + lane * 4);
  float4 xrv = ld_half4(xr + (size_t)n * 256 + lane * 4);
  float4 xlv = ld_half4(xl + (size_t)n * 256 + lane * 4);

  // self-loop score (per-head dot across 16-lane group)
  float q, v;
  v = xlv.x + xrv.x; q  = (v > 0.f ? v : 0.2f * v) * atv.x;
  v = xlv.y + xrv.y; q += (v > 0.f ? v : 0.2f * v) * atv.y;
  v = xlv.z + xrv.z; q += (v > 0.f ? v : 0.2f * v) * atv.z;
  v = xlv.w + xrv.w; q += (v > 0.f ? v : 0.2f * v) * atv.w;
  q += __shfl_xor(q, 1); q += __shfl_xor(q, 2);
  q += __shfl_xor(q, 4); q += __shfl_xor(q, 8);
  float w = __expf(q);
  float den = w;
  float4 acc = make_float4(w * xlv.x, w * xlv.y, w * xlv.z, w * xlv.w);

  int beg = row_ptr[n], end = row_ptr[n + 1];
  for (int i = beg; i < end; ++i) {
    int s = csr_src[i];
    float4 a = ld_half4(xl + (size_t)s * 256 + lane * 4);
    v = a.x + xrv.x; q  = (v > 0.f ? v : 0.2f * v) * atv.x;
    v = a.y + xrv.y; q += (v > 0.f ? v : 0.2f * v) * atv.y;
    v = a.z + xrv.z; q += (v > 0.f ? v : 0.2f * v) * atv.z;
    v = a.w + xrv.w; q += (v > 0.f ? v : 0.2f * v) * atv.w;
    q += __shfl_xor(q, 1); q += __shfl_xor(q, 2);
    q += __shfl_xor(q, 4); q += __shfl_xor(q, 8);
    w = __expf(q);
    den += w;
    acc.x += w * a.x; acc.y += w * a.y;
    acc.z += w * a.z; acc.w += w * a.w;
  }
  float inv = 1.f / den;
  acc.x *= inv; acc.y *= inv; acc.z *= inv; acc.w *= inv;
  // mean over heads: lanes l, l^16, l^32, l^48 hold same feature of different heads
  acc.x += __shfl_xor(acc.x, 16); acc.y += __shfl_xor(acc.y, 16);
  acc.z += __shfl_xor(acc.z, 16); acc.w += __shfl_xor(acc.w, 16);
  acc.x += __shfl_xor(acc.x, 32); acc.y += __shfl_xor(acc.y, 32);
  acc.z += __shfl_xor(acc.z, 32); acc.w += __shfl_xor(acc.w, 32);
  // redistribute: feature `lane` = component (lane&3) of lane (lane>>2)
  int srcl = lane >> 2;
  float t0 = __shfl(acc.x, srcl), t1 = __shfl(acc.y, srcl);
  float t2 = __shfl(acc.z, srcl), t3 = __shfl(acc.w, srcl);
  int r = lane & 3;
  float mean = (r == 0) ? t0 : (r == 1) ? t1 : (r == 2) ? t2 : t3;
  float val = mean * 0.25f + gat_b[lane];
  float mu = wsum(val) * (1.f / HID);
  float dv = val - mu;
  float var = wsum(dv * dv) * (1.f / HID);
  float h = dv * rsqrtf(var + 1e-5f) * g[lane] + bb[lane];
  h = h > 0.f ? h : 0.f;
  float outv = h + h_init[(size_t)n * HID + lane];
  h2[(size_t)n * HID + lane] = outv;
  h2_16[(size_t)n * HID + lane] = __float2half(outv);
}

// ---------------- SAGE stage 1: pull mean-gather (fp32 out) ----------------
__global__ __launch_bounds__(256) void k_sage_gather(
    const int* __restrict__ row_ptr, const int* __restrict__ csr_src,
    const __half* __restrict__ h2_16, float* __restrict__ nmean) {
  int n = blockIdx.x * 4 + (threadIdx.x >> 6);
  int lane = threadIdx.x & 63;
  int beg = row_ptr[n], end = row_ptr[n + 1];
  float sum = 0.f;
  for (int i = beg; i < end; ++i) {
    int s = csr_src[i];
    sum += __half2float(h2_16[(size_t)s * HID + lane]);
  }
  nmean[(size_t)n * HID + lane] = sum / fmaxf((float)(end - beg), 1.f);
}

// ---------------- SAGE stage 2: dense nmean@Wl + h2@Wr + LN (s_load acts) ------
// 64-thread blocks, 8 nodes/block: activation addresses derive only from blockIdx
// -> compiler emits scalar loads; K-loop is 16 FMA per 2 W-column vector loads.
__global__ __launch_bounds__(64) void k_sage_gemm_ln(
    const float* __restrict__ nmean, const float* __restrict__ h2,
    const float* __restrict__ Wl, const float* __restrict__ Wr,
    const float* __restrict__ sage_bl, const float* __restrict__ g,
    const float* __restrict__ bb, float* __restrict__ h3) {
  int f = threadIdx.x;
  int n0 = blockIdx.x * 8;
  float acc[8] = {0.f,0.f,0.f,0.f,0.f,0.f,0.f,0.f};
  for (int k = 0; k < HID; ++k) {
    float wl = Wl[k * HID + f], wr = Wr[k * HID + f];
#pragma unroll
    for (int j = 0; j < 8; ++j)
      acc[j] += nmean[(size_t)(n0 + j) * HID + k] * wl +
                h2[(size_t)(n0 + j) * HID + k] * wr;
  }
  float blv = sage_bl[f], gv = g[f], bbv = bb[f];
#pragma unroll
  for (int j = 0; j < 8; ++j) {
    float v = acc[j] + blv;
    float mu = wsum(v) * (1.f / HID);
    float dv = v - mu;
    float var = wsum(dv * dv) * (1.f / HID);
    float h = dv * rsqrtf(var + 1e-5f) * gv + bbv;
    h = h > 0.f ? h : 0.f;
    h3[(size_t)(n0 + j) * HID + f] = h + h2[(size_t)(n0 + j) * HID + f];
  }
}

// ---------------- heads ----------------
__global__ __launch_bounds__(256) void k_heads(
    const float* __restrict__ h_init, const float* __restrict__ h2,
    const float* __restrict__ h3, const int* __restrict__ mask,
    const float* __restrict__ mort_W, const float* __restrict__ mort_b,
    const float* __restrict__ hours_W, const float* __restrict__ hours_b,
    const float* __restrict__ disc_W, const float* __restrict__ disc_b,
    float* __restrict__ out) {
  int n = blockIdx.x * 4 + (threadIdx.x >> 6);
  int lane = threadIdx.x & 63;
  float m = (mask[n] != 0) ? 1.f : 0.f;
  size_t base = (size_t)n * HID;
  float v0 = h_init[base + lane] * m;
  float v1 = h2[base + lane] * m;
  float v2 = h3[base + lane] * m;
  float pm = v0 * mort_W[lane] + v1 * mort_W[64 + lane] + v2 * mort_W[128 + lane];
  float ph = v0 * hours_W[lane] + v1 * hours_W[64 + lane] + v2 * hours_W[128 + lane];
  float d0 = v0 * disc_W[lane * 4 + 0] + v1 * disc_W[(64 + lane) * 4 + 0] + v2 * disc_W[(128 + lane) * 4 + 0];
  float d1 = v0 * disc_W[lane * 4 + 1] + v1 * disc_W[(64 + lane) * 4 + 1] + v2 * disc_W[(128 + lane) * 4 + 1];
  float d2 = v0 * disc_W[lane * 4 + 2] + v1 * disc_W[(64 + lane) * 4 + 2] + v2 * disc_W[(128 + lane) * 4 + 2];
  float d3 = v0 * disc_W[lane * 4 + 3] + v1 * disc_W[(64 + lane) * 4 + 3] + v2 * disc_W[(128 + lane) * 4 + 3];
  pm = wsum(pm); ph = wsum(ph);
  d0 = wsum(d0); d1 = wsum(d1); d2 = wsum(d2); d3 = wsum(d3);
  if (lane == 0) {
    out[n] = pm + mort_b[0];
    out[N_NODES + n] = ph + hours_b[0];
    float* dd = out + 2 * N_NODES + (size_t)n * 4;
    dd[0] = d0 + disc_b[0];
    dd[1] = d1 + disc_b[1];
    dd[2] = d2 + disc_b[2];
    dd[3] = d3 + disc_b[3];
  }
}

extern "C" void kernel_launch(void* const* d_in, const int* in_sizes, int n_in,
                              void* d_out, int out_size, void* d_ws, size_t ws_size,
                              hipStream_t stream) {
  const float* x       = (const float*)d_in[0];
  const int*   ei      = (const int*)d_in[1];
  const float* ew      = (const float*)d_in[2];
  const int*   mask    = (const int*)d_in[3];
  const float* gcn_W   = (const float*)d_in[4];
  const float* gcn_b   = (const float*)d_in[5];
  const float* proj_W  = (const float*)d_in[6];
  const float* proj_b  = (const float*)d_in[7];
  const float* ln1_g   = (const float*)d_in[8];
  const float* ln1_b   = (const float*)d_in[9];
  const float* gat_Wl  = (const float*)d_in[10];
  const float* gat_Wr  = (const float*)d_in[11];
  const float* gat_att = (const float*)d_in[12];
  const float* gat_b   = (const float*)d_in[13];
  const float* ln2_g   = (const float*)d_in[14];
  const float* ln2_b   = (const float*)d_in[15];
  const float* sage_Wl = (const float*)d_in[16];
  const float* sage_bl = (const float*)d_in[17];
  const float* sage_Wr = (const float*)d_in[18];
  const float* ln3_g   = (const float*)d_in[19];
  const float* ln3_b   = (const float*)d_in[20];
  // d_in[21..24]: edge-MLP params — output unused by the reference; skipped.
  const float* mort_W  = (const float*)d_in[25];
  const float* mort_b  = (const float*)d_in[26];
  const float* hours_W = (const float*)d_in[27];
  const float* hours_b = (const float*)d_in[28];
  const float* disc_W  = (const float*)d_in[29];
  const float* disc_b  = (const float*)d_in[30];

  const int* src = ei;
  const int* dst = ei + N_EDGES;
  float* out = (float*)d_out;

  // ---- workspace layout (~49M floats = 196 MB) ----
  float* ws = (float*)d_ws;
  const size_t F = (size_t)N_NODES * HID;  // 6.4M floats
  float* h_init = ws;
  float* h2     = ws + 1 * F;
  float* h3     = ws + 2 * F;
  float* xp     = h3;                              // fp32, dead before h3 written
  __half* xl    = (__half*)(ws + 3 * F);           // N*256 halfs
  __half* xw16  = xl;                              // N*64 halfs, dead before xl written
  float* nmean  = ws + 3 * F;                      // fp32 N*64, xl dead by SAGE
  __half* xr    = (__half*)(ws + 3 * F + (size_t)N_NODES * 128);
  __half* h2_16 = (__half*)(ws + 3 * F + (size_t)N_NODES * 256);
  float* tail   = ws + 3 * F + (size_t)N_NODES * 256 + (size_t)N_NODES * 32;
  int*   csr_src = (int*)tail;           tail += N_EDGES;
  float* csr_w   = tail;                 tail += N_EDGES;
  int*   row_ptr = (int*)tail;           tail += N_NODES + 64;
  int*   cursor  = (int*)tail;           tail += N_NODES;
  int*   cnt     = (int*)tail;           tail += N_NODES;
  int*   partial = (int*)tail;           tail += N_NODES;
  int*   bsum    = (int*)tail;           tail += 128;
  float* dinv    = tail;

  const int GE = (N_EDGES + 255) / 256;
  const int GN = (N_NODES + 255) / 256;

  // --- CSR build (by dst) ---
  k_zero_cnt<<<GN, 256, 0, stream>>>(cnt);
  k_hist<<<GE, 256, 0, stream>>>(dst, cnt);
  k_scan1<<<SCAN_BLK, 256, 0, stream>>>(cnt, partial, bsum);
  k_scan2<<<1, 128, 0, stream>>>(bsum);
  k_scan3<<<GN, 256, 0, stream>>>(partial, bsum, row_ptr, cursor);
  k_fill<<<GE, 256, 0, stream>>>(src, dst, ew, cursor, csr_src, csr_w);

  // --- GCN layer ---
  k_in_gemm<<<N_NODES / 8, 128, 0, stream>>>(x, gcn_W, proj_W, proj_b, xw16, xp);
  k_deg<<<GN, 256, 0, stream>>>(row_ptr, csr_w, dinv);
  k_gcn_fused<<<N_NODES / 4, 256, 0, stream>>>(row_ptr, csr_src, csr_w, dinv, xw16,
                                               xp, gcn_b, ln1_g, ln1_b, h_init);

  // --- GATv2 layer ---
  k_gat_gemm<<<N_NODES / 8, 512, 0, stream>>>(h_init, gat_Wl, gat_Wr, xl, xr);
  k_gat_fused<<<N_NODES / 4, 256, 0, stream>>>(row_ptr, csr_src, xl, xr, gat_att,
                                               gat_b, ln2_g, ln2_b, h_init, h2, h2_16);

  // --- SAGE layer ---
  k_sage_gather<<<N_NODES / 4, 256, 0, stream>>>(row_ptr, csr_src, h2_16, nmean);
  k_sage_gemm_ln<<<N_NODES / 8, 64, 0, stream>>>(nmean, h2, sage_Wl, sage_Wr,
                                                 sage_bl, ln3_g, ln3_b, h3);

  // --- heads ---
  k_heads<<<N_NODES / 4, 256, 0, stream>>>(h_init, h2, h3, mask, mort_W, mort_b,
                                           hours_W, hours_b, disc_W, disc_b, out);
}

// Round 7
// 921.567 us; speedup vs baseline: 1.1123x; 1.1123x over previous
//
#include <hip/hip_runtime.h>
#include <hip/hip_fp16.h>
#include <math.h>

#define N_NODES 100000
#define N_EDGES 1000000
#define F_IN    128
#define HID     64
#define HEADS   4
#define NCLS    4
#define SCAN_BLK 98   // ceil(N_NODES / 1024)

// ---------------- helpers ----------------
__device__ __forceinline__ float wsum(float v) {
#pragma unroll
  for (int o = 32; o > 0; o >>= 1) v += __shfl_xor(v, o, 64);
  return v;
}
struct Half4 { __half2 a, b; };
__device__ __forceinline__ float4 ld_half4(const __half* p) {
  Half4 h = *reinterpret_cast<const Half4*>(p);
  float2 f0 = __half22float2(h.a), f1 = __half22float2(h.b);
  return make_float4(f0.x, f0.y, f1.x, f1.y);
}
// wave-uniform node id -> SGPR, so row_ptr/csr reads become scalar loads and
// gather addresses are SGPR-base + fixed lane offset (frees the VALU).
__device__ __forceinline__ int wave_node() {
  return __builtin_amdgcn_readfirstlane(blockIdx.x * 4 + (threadIdx.x >> 6));
}

// ---------------- CSR build (by dst) ----------------
__global__ void k_zero_cnt(int* __restrict__ cnt) {
  int i = blockIdx.x * 256 + threadIdx.x;
  if (i < N_NODES) cnt[i] = 0;
}
__global__ void k_hist(const int* __restrict__ dst, int* __restrict__ cnt) {
  int e = blockIdx.x * 256 + threadIdx.x;
  if (e < N_EDGES) atomicAdd(&cnt[dst[e]], 1);
}
__global__ __launch_bounds__(256) void k_scan1(const int* __restrict__ cnt,
                                               int* __restrict__ partial,
                                               int* __restrict__ bsum) {
  __shared__ int lds[256];
  int t = threadIdx.x;
  int base = blockIdx.x * 1024 + t * 4;
  int v0 = (base + 0 < N_NODES) ? cnt[base + 0] : 0;
  int v1 = (base + 1 < N_NODES) ? cnt[base + 1] : 0;
  int v2 = (base + 2 < N_NODES) ? cnt[base + 2] : 0;
  int v3 = (base + 3 < N_NODES) ? cnt[base + 3] : 0;
  int s = v0 + v1 + v2 + v3;
  lds[t] = s;
  __syncthreads();
  for (int o = 1; o < 256; o <<= 1) {
    int x = (t >= o) ? lds[t - o] : 0;
    __syncthreads();
    lds[t] += x;
    __syncthreads();
  }
  int excl = lds[t] - s;
  if (base + 0 < N_NODES) partial[base + 0] = excl;
  if (base + 1 < N_NODES) partial[base + 1] = excl + v0;
  if (base + 2 < N_NODES) partial[base + 2] = excl + v0 + v1;
  if (base + 3 < N_NODES) partial[base + 3] = excl + v0 + v1 + v2;
  if (t == 255) bsum[blockIdx.x] = lds[255];
}
__global__ void k_scan2(int* __restrict__ bsum) {  // 1 block, 128 threads
  __shared__ int lds[128];
  int t = threadIdx.x;
  int v = (t < SCAN_BLK) ? bsum[t] : 0;
  lds[t] = v;
  __syncthreads();
  for (int o = 1; o < 128; o <<= 1) {
    int x = (t >= o) ? lds[t - o] : 0;
    __syncthreads();
    lds[t] += x;
    __syncthreads();
  }
  if (t < SCAN_BLK) bsum[t] = lds[t] - v;  // exclusive
}
__global__ void k_scan3(const int* __restrict__ partial, const int* __restrict__ bsum,
                        int* __restrict__ row_ptr, int* __restrict__ cursor) {
  int i = blockIdx.x * 256 + threadIdx.x;
  if (i < N_NODES) {
    int v = partial[i] + bsum[i >> 10];
    row_ptr[i] = v;
    cursor[i] = v;
  }
  if (i == 0) row_ptr[N_NODES] = N_EDGES;
}
__global__ void k_fill(const int* __restrict__ src, const int* __restrict__ dst,
                       const float* __restrict__ ew, int* __restrict__ cursor,
                       int* __restrict__ csr_src, float* __restrict__ csr_w) {
  int e = blockIdx.x * 256 + threadIdx.x;
  if (e >= N_EDGES) return;
  int d = dst[e];
  int p = atomicAdd(&cursor[d], 1);
  csr_src[p] = src[e];
  csr_w[p] = ew[e];
}

// ---------------- dense: xw16 = half(x@gcn_W) ; xp = x@proj_W + proj_b ----------
__global__ __launch_bounds__(128) void k_in_gemm(
    const float* __restrict__ x, const float* __restrict__ gcn_W,
    const float* __restrict__ proj_W, const float* __restrict__ proj_b,
    __half* __restrict__ xw16, float* __restrict__ xp) {
  int f = threadIdx.x & 63;
  bool is_proj = threadIdx.x >= 64;
  const float* W = is_proj ? proj_W : gcn_W;
  int n0 = blockIdx.x * 8;
  float acc[8] = {0.f,0.f,0.f,0.f,0.f,0.f,0.f,0.f};
  for (int k = 0; k < F_IN; ++k) {
    float w = W[k * HID + f];
#pragma unroll
    for (int j = 0; j < 8; ++j) acc[j] += x[(size_t)(n0 + j) * F_IN + k] * w;
  }
  if (is_proj) {
    float b = proj_b[f];
#pragma unroll
    for (int j = 0; j < 8; ++j) xp[(size_t)(n0 + j) * HID + f] = acc[j] + b;
  } else {
#pragma unroll
    for (int j = 0; j < 8; ++j) xw16[(size_t)(n0 + j) * HID + f] = __float2half(acc[j]);
  }
}

// ---------------- GCN: deg/dinv from CSR (no atomics) ----------------
__global__ void k_deg(const int* __restrict__ row_ptr, const float* __restrict__ csr_w,
                      float* __restrict__ dinv) {
  int n = blockIdx.x * 256 + threadIdx.x;
  if (n >= N_NODES) return;
  float deg = 1.0f;  // self-loop weight
  int end = row_ptr[n + 1];
  for (int i = row_ptr[n]; i < end; ++i) deg += csr_w[i];
  dinv[n] = rsqrtf(deg);  // deg >= 1 always
}

// pull-gather + LN + relu + residual, one wave per node (n in SGPR)
__global__ __launch_bounds__(256) void k_gcn_fused(
    const int* __restrict__ row_ptr, const int* __restrict__ csr_src,
    const float* __restrict__ csr_w, const float* __restrict__ dinv,
    const __half* __restrict__ xw16, const float* __restrict__ xp,
    const float* __restrict__ gcn_b, const float* __restrict__ g,
    const float* __restrict__ bb, float* __restrict__ h_init) {
  int n = wave_node();
  int lane = threadIdx.x & 63;
  float di = dinv[n];
  float acc = di * di * __half2float(xw16[(size_t)n * HID + lane]);  // self loop
  int beg = row_ptr[n], end = row_ptr[n + 1];
  for (int i = beg; i < end; ++i) {
    int s = __builtin_amdgcn_readfirstlane(csr_src[i]);
    float nrm = dinv[s] * csr_w[i] * di;
    acc += nrm * __half2float(xw16[(size_t)s * HID + lane]);
  }
  float v = acc + gcn_b[lane];
  float mu = wsum(v) * (1.f / HID);
  float dv = v - mu;
  float var = wsum(dv * dv) * (1.f / HID);
  float h = dv * rsqrtf(var + 1e-5f) * g[lane] + bb[lane];
  h = h > 0.f ? h : 0.f;
  h_init[(size_t)n * HID + lane] = h + xp[(size_t)n * HID + lane];
}

// ---------------- GATv2 linear: xl = h@Wl, xr = h@Wr (fp16 out, each [N,256]) ----
__global__ __launch_bounds__(512) void k_gat_gemm(
    const float* __restrict__ h, const float* __restrict__ Wl,
    const float* __restrict__ Wr, __half* __restrict__ xl, __half* __restrict__ xr) {
  int f = threadIdx.x & 255;
  bool right = threadIdx.x >= 256;
  const float* W = right ? Wr : Wl;
  __half* out = right ? xr : xl;
  int n0 = blockIdx.x * 8;
  float acc[8] = {0.f,0.f,0.f,0.f,0.f,0.f,0.f,0.f};
  for (int k = 0; k < HID; ++k) {
    float w = W[k * 256 + f];
#pragma unroll
    for (int j = 0; j < 8; ++j) acc[j] += h[(size_t)(n0 + j) * HID + k] * w;
  }
#pragma unroll
  for (int j = 0; j < 8; ++j) out[(size_t)(n0 + j) * 256 + f] = __float2half(acc[j]);
}

// ---------------- GATv2 fused: softmax (no max shift) + aggregate + mean + LN ---
// One wave per dst node (n in SGPR). Lane holds feats 4*lane..4*lane+3 of 256.
// Edge loop unrolled x2: two independent gather->score->swizzle->exp streams.
__global__ __launch_bounds__(256) void k_gat_fused(
    const int* __restrict__ row_ptr, const int* __restrict__ csr_src,
    const __half* __restrict__ xl, const __half* __restrict__ xr,
    const float* __restrict__ att, const float* __restrict__ gat_b,
    const float* __restrict__ g, const float* __restrict__ bb,
    const float* __restrict__ h_init, float* __restrict__ h2,
    __half* __restrict__ h2_16) {
  int n = wave_node();
  int lane = threadIdx.x & 63;
  float4 atv = *reinterpret_cast<const float4*>(att + lane * 4);
  float4 xrv = ld_half4(xr + (size_t)n * 256 + lane * 4);
  float4 xlv = ld_half4(xl + (size_t)n * 256 + lane * 4);

  // self-loop score (per-head dot across 16-lane group)
  float q, v;
  v = xlv.x + xrv.x; q  = (v > 0.f ? v : 0.2f * v) * atv.x;
  v = xlv.y + xrv.y; q += (v > 0.f ? v : 0.2f * v) * atv.y;
  v = xlv.z + xrv.z; q += (v > 0.f ? v : 0.2f * v) * atv.z;
  v = xlv.w + xrv.w; q += (v > 0.f ? v : 0.2f * v) * atv.w;
  q += __shfl_xor(q, 1); q += __shfl_xor(q, 2);
  q += __shfl_xor(q, 4); q += __shfl_xor(q, 8);
  float w = __expf(q);
  float den = w;
  float4 acc = make_float4(w * xlv.x, w * xlv.y, w * xlv.z, w * xlv.w);

  int beg = row_ptr[n], end = row_ptr[n + 1];
  int i = beg;
  for (; i + 2 <= end; i += 2) {
    int s0 = __builtin_amdgcn_readfirstlane(csr_src[i]);
    int s1 = __builtin_amdgcn_readfirstlane(csr_src[i + 1]);
    float4 a0 = ld_half4(xl + (size_t)s0 * 256 + lane * 4);
    float4 a1 = ld_half4(xl + (size_t)s1 * 256 + lane * 4);
    float q0, q1;
    v = a0.x + xrv.x; q0  = (v > 0.f ? v : 0.2f * v) * atv.x;
    v = a0.y + xrv.y; q0 += (v > 0.f ? v : 0.2f * v) * atv.y;
    v = a0.z + xrv.z; q0 += (v > 0.f ? v : 0.2f * v) * atv.z;
    v = a0.w + xrv.w; q0 += (v > 0.f ? v : 0.2f * v) * atv.w;
    v = a1.x + xrv.x; q1  = (v > 0.f ? v : 0.2f * v) * atv.x;
    v = a1.y + xrv.y; q1 += (v > 0.f ? v : 0.2f * v) * atv.y;
    v = a1.z + xrv.z; q1 += (v > 0.f ? v : 0.2f * v) * atv.z;
    v = a1.w + xrv.w; q1 += (v > 0.f ? v : 0.2f * v) * atv.w;
    q0 += __shfl_xor(q0, 1); q1 += __shfl_xor(q1, 1);
    q0 += __shfl_xor(q0, 2); q1 += __shfl_xor(q1, 2);
    q0 += __shfl_xor(q0, 4); q1 += __shfl_xor(q1, 4);
    q0 += __shfl_xor(q0, 8); q1 += __shfl_xor(q1, 8);
    float w0 = __expf(q0), w1 = __expf(q1);
    den += w0 + w1;
    acc.x += w0 * a0.x + w1 * a1.x;
    acc.y += w0 * a0.y + w1 * a1.y;
    acc.z += w0 * a0.z + w1 * a1.z;
    acc.w += w0 * a0.w + w1 * a1.w;
  }
  if (i < end) {
    int s0 = __builtin_amdgcn_readfirstlane(csr_src[i]);
    float4 a0 = ld_half4(xl + (size_t)s0 * 256 + lane * 4);
    v = a0.x + xrv.x; q  = (v > 0.f ? v : 0.2f * v) * atv.x;
    v = a0.y + xrv.y; q += (v > 0.f ? v : 0.2f * v) * atv.y;
    v = a0.z + xrv.z; q += (v > 0.f ? v : 0.2f * v) * atv.z;
    v = a0.w + xrv.w; q += (v > 0.f ? v : 0.2f * v) * atv.w;
    q += __shfl_xor(q, 1); q += __shfl_xor(q, 2);
    q += __shfl_xor(q, 4); q += __shfl_xor(q, 8);
    w = __expf(q);
    den += w;
    acc.x += w * a0.x; acc.y += w * a0.y;
    acc.z += w * a0.z; acc.w += w * a0.w;
  }
  float inv = 1.f / den;
  acc.x *= inv; acc.y *= inv; acc.z *= inv; acc.w *= inv;
  // mean over heads: lanes l, l^16, l^32, l^48 hold same feature of different heads
  acc.x += __shfl_xor(acc.x, 16); acc.y += __shfl_xor(acc.y, 16);
  acc.z += __shfl_xor(acc.z, 16); acc.w += __shfl_xor(acc.w, 16);
  acc.x += __shfl_xor(acc.x, 32); acc.y += __shfl_xor(acc.y, 32);
  acc.z += __shfl_xor(acc.z, 32); acc.w += __shfl_xor(acc.w, 32);
  // redistribute: feature `lane` = component (lane&3) of lane (lane>>2)
  int srcl = lane >> 2;
  float t0 = __shfl(acc.x, srcl), t1 = __shfl(acc.y, srcl);
  float t2 = __shfl(acc.z, srcl), t3 = __shfl(acc.w, srcl);
  int r = lane & 3;
  float mean = (r == 0) ? t0 : (r == 1) ? t1 : (r == 2) ? t2 : t3;
  float val = mean * 0.25f + gat_b[lane];
  float mu = wsum(val) * (1.f / HID);
  float dv = val - mu;
  float var = wsum(dv * dv) * (1.f / HID);
  float h = dv * rsqrtf(var + 1e-5f) * g[lane] + bb[lane];
  h = h > 0.f ? h : 0.f;
  float outv = h + h_init[(size_t)n * HID + lane];
  h2[(size_t)n * HID + lane] = outv;
  h2_16[(size_t)n * HID + lane] = __float2half(outv);
}

// ---------------- SAGE stage 1: pull mean-gather (fp32 out, n in SGPR) ---------
__global__ __launch_bounds__(256) void k_sage_gather(
    const int* __restrict__ row_ptr, const int* __restrict__ csr_src,
    const __half* __restrict__ h2_16, float* __restrict__ nmean) {
  int n = wave_node();
  int lane = threadIdx.x & 63;
  int beg = row_ptr[n], end = row_ptr[n + 1];
  float sum = 0.f;
  for (int i = beg; i < end; ++i) {
    int s = __builtin_amdgcn_readfirstlane(csr_src[i]);
    sum += __half2float(h2_16[(size_t)s * HID + lane]);
  }
  nmean[(size_t)n * HID + lane] = sum / fmaxf((float)(end - beg), 1.f);
}

// ---------------- SAGE stage 2: dense nmean@Wl + h2@Wr + LN (s_load acts) ------
__global__ __launch_bounds__(64) void k_sage_gemm_ln(
    const float* __restrict__ nmean, const float* __restrict__ h2,
    const float* __restrict__ Wl, const float* __restrict__ Wr,
    const float* __restrict__ sage_bl, const float* __restrict__ g,
    const float* __restrict__ bb, float* __restrict__ h3) {
  int f = threadIdx.x;
  int n0 = blockIdx.x * 8;
  float acc[8] = {0.f,0.f,0.f,0.f,0.f,0.f,0.f,0.f};
  for (int k = 0; k < HID; ++k) {
    float wl = Wl[k * HID + f], wr = Wr[k * HID + f];
#pragma unroll
    for (int j = 0; j < 8; ++j)
      acc[j] += nmean[(size_t)(n0 + j) * HID + k] * wl +
                h2[(size_t)(n0 + j) * HID + k] * wr;
  }
  float blv = sage_bl[f], gv = g[f], bbv = bb[f];
#pragma unroll
  for (int j = 0; j < 8; ++j) {
    float v = acc[j] + blv;
    float mu = wsum(v) * (1.f / HID);
    float dv = v - mu;
    float var = wsum(dv * dv) * (1.f / HID);
    float h = dv * rsqrtf(var + 1e-5f) * gv + bbv;
    h = h > 0.f ? h : 0.f;
    h3[(size_t)(n0 + j) * HID + f] = h + h2[(size_t)(n0 + j) * HID + f];
  }
}

// ---------------- heads ----------------
__global__ __launch_bounds__(256) void k_heads(
    const float* __restrict__ h_init, const float* __restrict__ h2,
    const float* __restrict__ h3, const int* __restrict__ mask,
    const float* __restrict__ mort_W, const float* __restrict__ mort_b,
    const float* __restrict__ hours_W, const float* __restrict__ hours_b,
    const float* __restrict__ disc_W, const float* __restrict__ disc_b,
    float* __restrict__ out) {
  int n = wave_node();
  int lane = threadIdx.x & 63;
  float m = (mask[n] != 0) ? 1.f : 0.f;
  size_t base = (size_t)n * HID;
  float v0 = h_init[base + lane] * m;
  float v1 = h2[base + lane] * m;
  float v2 = h3[base + lane] * m;
  float pm = v0 * mort_W[lane] + v1 * mort_W[64 + lane] + v2 * mort_W[128 + lane];
  float ph = v0 * hours_W[lane] + v1 * hours_W[64 + lane] + v2 * hours_W[128 + lane];
  float d0 = v0 * disc_W[lane * 4 + 0] + v1 * disc_W[(64 + lane) * 4 + 0] + v2 * disc_W[(128 + lane) * 4 + 0];
  float d1 = v0 * disc_W[lane * 4 + 1] + v1 * disc_W[(64 + lane) * 4 + 1] + v2 * disc_W[(128 + lane) * 4 + 1];
  float d2 = v0 * disc_W[lane * 4 + 2] + v1 * disc_W[(64 + lane) * 4 + 2] + v2 * disc_W[(128 + lane) * 4 + 2];
  float d3 = v0 * disc_W[lane * 4 + 3] + v1 * disc_W[(64 + lane) * 4 + 3] + v2 * disc_W[(128 + lane) * 4 + 3];
  pm = wsum(pm); ph = wsum(ph);
  d0 = wsum(d0); d1 = wsum(d1); d2 = wsum(d2); d3 = wsum(d3);
  if (lane == 0) {
    out[n] = pm + mort_b[0];
    out[N_NODES + n] = ph + hours_b[0];
    float* dd = out + 2 * N_NODES + (size_t)n * 4;
    dd[0] = d0 + disc_b[0];
    dd[1] = d1 + disc_b[1];
    dd[2] = d2 + disc_b[2];
    dd[3] = d3 + disc_b[3];
  }
}

extern "C" void kernel_launch(void* const* d_in, const int* in_sizes, int n_in,
                              void* d_out, int out_size, void* d_ws, size_t ws_size,
                              hipStream_t stream) {
  const float* x       = (const float*)d_in[0];
  const int*   ei      = (const int*)d_in[1];
  const float* ew      = (const float*)d_in[2];
  const int*   mask    = (const int*)d_in[3];
  const float* gcn_W   = (const float*)d_in[4];
  const float* gcn_b   = (const float*)d_in[5];
  const float* proj_W  = (const float*)d_in[6];
  const float* proj_b  = (const float*)d_in[7];
  const float* ln1_g   = (const float*)d_in[8];
  const float* ln1_b   = (const float*)d_in[9];
  const float* gat_Wl  = (const float*)d_in[10];
  const float* gat_Wr  = (const float*)d_in[11];
  const float* gat_att = (const float*)d_in[12];
  const float* gat_b   = (const float*)d_in[13];
  const float* ln2_g   = (const float*)d_in[14];
  const float* ln2_b   = (const float*)d_in[15];
  const float* sage_Wl = (const float*)d_in[16];
  const float* sage_bl = (const float*)d_in[17];
  const float* sage_Wr = (const float*)d_in[18];
  const float* ln3_g   = (const float*)d_in[19];
  const float* ln3_b   = (const float*)d_in[20];
  // d_in[21..24]: edge-MLP params — output unused by the reference; skipped.
  const float* mort_W  = (const float*)d_in[25];
  const float* mort_b  = (const float*)d_in[26];
  const float* hours_W = (const float*)d_in[27];
  const float* hours_b = (const float*)d_in[28];
  const float* disc_W  = (const float*)d_in[29];
  const float* disc_b  = (const float*)d_in[30];

  const int* src = ei;
  const int* dst = ei + N_EDGES;
  float* out = (float*)d_out;

  // ---- workspace layout (~49M floats = 196 MB) ----
  float* ws = (float*)d_ws;
  const size_t F = (size_t)N_NODES * HID;  // 6.4M floats
  float* h_init = ws;
  float* h2     = ws + 1 * F;
  float* h3     = ws + 2 * F;
  float* xp     = h3;                              // fp32, dead before h3 written
  __half* xl    = (__half*)(ws + 3 * F);           // N*256 halfs
  __half* xw16  = xl;                              // N*64 halfs, dead before xl written
  float* nmean  = ws + 3 * F;                      // fp32 N*64, xl dead by SAGE
  __half* xr    = (__half*)(ws + 3 * F + (size_t)N_NODES * 128);
  __half* h2_16 = (__half*)(ws + 3 * F + (size_t)N_NODES * 256);
  float* tail   = ws + 3 * F + (size_t)N_NODES * 256 + (size_t)N_NODES * 32;
  int*   csr_src = (int*)tail;           tail += N_EDGES;
  float* csr_w   = tail;                 tail += N_EDGES;
  int*   row_ptr = (int*)tail;           tail += N_NODES + 64;
  int*   cursor  = (int*)tail;           tail += N_NODES;
  int*   cnt     = (int*)tail;           tail += N_NODES;
  int*   partial = (int*)tail;           tail += N_NODES;
  int*   bsum    = (int*)tail;           tail += 128;
  float* dinv    = tail;

  const int GE = (N_EDGES + 255) / 256;
  const int GN = (N_NODES + 255) / 256;

  // --- CSR build (by dst) ---
  k_zero_cnt<<<GN, 256, 0, stream>>>(cnt);
  k_hist<<<GE, 256, 0, stream>>>(dst, cnt);
  k_scan1<<<SCAN_BLK, 256, 0, stream>>>(cnt, partial, bsum);
  k_scan2<<<1, 128, 0, stream>>>(bsum);
  k_scan3<<<GN, 256, 0, stream>>>(partial, bsum, row_ptr, cursor);
  k_fill<<<GE, 256, 0, stream>>>(src, dst, ew, cursor, csr_src, csr_w);

  // --- GCN layer ---
  k_in_gemm<<<N_NODES / 8, 128, 0, stream>>>(x, gcn_W, proj_W, proj_b, xw16, xp);
  k_deg<<<GN, 256, 0, stream>>>(row_ptr, csr_w, dinv);
  k_gcn_fused<<<N_NODES / 4, 256, 0, stream>>>(row_ptr, csr_src, csr_w, dinv, xw16,
                                               xp, gcn_b, ln1_g, ln1_b, h_init);

  // --- GATv2 layer ---
  k_gat_gemm<<<N_NODES / 8, 512, 0, stream>>>(h_init, gat_Wl, gat_Wr, xl, xr);
  k_gat_fused<<<N_NODES / 4, 256, 0, stream>>>(row_ptr, csr_src, xl, xr, gat_att,
                                               gat_b, ln2_g, ln2_b, h_init, h2, h2_16);

  // --- SAGE layer ---
  k_sage_gather<<<N_NODES / 4, 256, 0, stream>>>(row_ptr, csr_src, h2_16, nmean);
  k_sage_gemm_ln<<<N_NODES / 8, 64, 0, stream>>>(nmean, h2, sage_Wl, sage_Wr,
                                                 sage_bl, ln3_g, ln3_b, h3);

  // --- heads ---
  k_heads<<<N_NODES / 4, 256, 0, stream>>>(h_init, h2, h3, mask, mort_W, mort_b,
                                           hours_W, hours_b, disc_W, disc_b, out);
}

// Round 8
// 766.837 us; speedup vs baseline: 1.3367x; 1.2018x over previous
//
#include <hip/hip_runtime.h>
#include <hip/hip_fp16.h>
#include <math.h>

#define N_NODES 100000
#define N_EDGES 1000000
#define F_IN    128
#define HID     64
#define HEADS   4
#define NCLS    4
#define SCAN_BLK 98   // ceil(N_NODES / 1024)

// ---------------- helpers ----------------
__device__ __forceinline__ float wsum(float v) {
#pragma unroll
  for (int o = 32; o > 0; o >>= 1) v += __shfl_xor(v, o, 64);
  return v;
}
struct Half4 { __half2 a, b; };
__device__ __forceinline__ float4 ld_half4(const __half* p) {
  Half4 h = *reinterpret_cast<const Half4*>(p);
  float2 f0 = __half22float2(h.a), f1 = __half22float2(h.b);
  return make_float4(f0.x, f0.y, f1.x, f1.y);
}
// wave-uniform node id -> SGPR (row_ptr/csr reads become scalar loads)
__device__ __forceinline__ int wave_node() {
  return __builtin_amdgcn_readfirstlane(blockIdx.x * 4 + (threadIdx.x >> 6));
}

// ---------------- CSR build (by dst) ----------------
__global__ void k_zero_cnt(int* __restrict__ cnt) {
  int i = blockIdx.x * 256 + threadIdx.x;
  if (i < N_NODES) cnt[i] = 0;
}
__global__ void k_hist(const int* __restrict__ dst, int* __restrict__ cnt) {
  int e = blockIdx.x * 256 + threadIdx.x;
  if (e < N_EDGES) atomicAdd(&cnt[dst[e]], 1);
}
__global__ __launch_bounds__(256) void k_scan1(const int* __restrict__ cnt,
                                               int* __restrict__ partial,
                                               int* __restrict__ bsum) {
  __shared__ int lds[256];
  int t = threadIdx.x;
  int base = blockIdx.x * 1024 + t * 4;
  int v0 = (base + 0 < N_NODES) ? cnt[base + 0] : 0;
  int v1 = (base + 1 < N_NODES) ? cnt[base + 1] : 0;
  int v2 = (base + 2 < N_NODES) ? cnt[base + 2] : 0;
  int v3 = (base + 3 < N_NODES) ? cnt[base + 3] : 0;
  int s = v0 + v1 + v2 + v3;
  lds[t] = s;
  __syncthreads();
  for (int o = 1; o < 256; o <<= 1) {
    int x = (t >= o) ? lds[t - o] : 0;
    __syncthreads();
    lds[t] += x;
    __syncthreads();
  }
  int excl = lds[t] - s;
  if (base + 0 < N_NODES) partial[base + 0] = excl;
  if (base + 1 < N_NODES) partial[base + 1] = excl + v0;
  if (base + 2 < N_NODES) partial[base + 2] = excl + v0 + v1;
  if (base + 3 < N_NODES) partial[base + 3] = excl + v0 + v1 + v2;
  if (t == 255) bsum[blockIdx.x] = lds[255];
}
__global__ void k_scan2(int* __restrict__ bsum) {  // 1 block, 128 threads
  __shared__ int lds[128];
  int t = threadIdx.x;
  int v = (t < SCAN_BLK) ? bsum[t] : 0;
  lds[t] = v;
  __syncthreads();
  for (int o = 1; o < 128; o <<= 1) {
    int x = (t >= o) ? lds[t - o] : 0;
    __syncthreads();
    lds[t] += x;
    __syncthreads();
  }
  if (t < SCAN_BLK) bsum[t] = lds[t] - v;  // exclusive
}
__global__ void k_scan3(const int* __restrict__ partial, const int* __restrict__ bsum,
                        int* __restrict__ row_ptr, int* __restrict__ cursor) {
  int i = blockIdx.x * 256 + threadIdx.x;
  if (i < N_NODES) {
    int v = partial[i] + bsum[i >> 10];
    row_ptr[i] = v;
    cursor[i] = v;
  }
  if (i == 0) row_ptr[N_NODES] = N_EDGES;
}
__global__ void k_fill(const int* __restrict__ src, const int* __restrict__ dst,
                       const float* __restrict__ ew, int* __restrict__ cursor,
                       int* __restrict__ csr_src, float* __restrict__ csr_w) {
  int e = blockIdx.x * 256 + threadIdx.x;
  if (e >= N_EDGES) return;
  int d = dst[e];
  int p = atomicAdd(&cursor[d], 1);
  csr_src[p] = src[e];
  csr_w[p] = ew[e];
}

// ---------------- dense: xw16 = half(x@gcn_W) ; xp = x@proj_W + proj_b ----------
// LDS-staged x tile (8 nodes x 128, 4 KB). K-loop: broadcast ds_read_b128 for x,
// coalesced vloads for W columns -> no scalar-load serialization.
__global__ __launch_bounds__(128) void k_in_gemm(
    const float* __restrict__ x, const float* __restrict__ gcn_W,
    const float* __restrict__ proj_W, const float* __restrict__ proj_b,
    __half* __restrict__ xw16, float* __restrict__ xp) {
  __shared__ float xt[8][F_IN];
  int t = threadIdx.x;
  int n0 = blockIdx.x * 8;
  {
    const float4* xg = reinterpret_cast<const float4*>(x + (size_t)n0 * F_IN);
    float4* xs = reinterpret_cast<float4*>(&xt[0][0]);
    xs[t] = xg[t];
    xs[t + 128] = xg[t + 128];
  }
  __syncthreads();
  int f = t & 63;
  bool is_proj = t >= 64;
  const float* W = is_proj ? proj_W : gcn_W;
  float acc[8] = {0.f,0.f,0.f,0.f,0.f,0.f,0.f,0.f};
  for (int k = 0; k < F_IN; k += 4) {
    float w0 = W[(k + 0) * HID + f];
    float w1 = W[(k + 1) * HID + f];
    float w2 = W[(k + 2) * HID + f];
    float w3 = W[(k + 3) * HID + f];
#pragma unroll
    for (int j = 0; j < 8; ++j) {
      float4 xv = *reinterpret_cast<const float4*>(&xt[j][k]);
      acc[j] += xv.x * w0 + xv.y * w1 + xv.z * w2 + xv.w * w3;
    }
  }
  if (is_proj) {
    float b = proj_b[f];
#pragma unroll
    for (int j = 0; j < 8; ++j) xp[(size_t)(n0 + j) * HID + f] = acc[j] + b;
  } else {
#pragma unroll
    for (int j = 0; j < 8; ++j) xw16[(size_t)(n0 + j) * HID + f] = __float2half(acc[j]);
  }
}

// ---------------- GCN: deg/dinv from CSR (no atomics) ----------------
__global__ void k_deg(const int* __restrict__ row_ptr, const float* __restrict__ csr_w,
                      float* __restrict__ dinv) {
  int n = blockIdx.x * 256 + threadIdx.x;
  if (n >= N_NODES) return;
  float deg = 1.0f;  // self-loop weight
  int end = row_ptr[n + 1];
  for (int i = row_ptr[n]; i < end; ++i) deg += csr_w[i];
  dinv[n] = rsqrtf(deg);  // deg >= 1 always
}

// pull-gather + LN + relu + residual, one wave per node (n in SGPR), 2x ILP
__global__ __launch_bounds__(256) void k_gcn_fused(
    const int* __restrict__ row_ptr, const int* __restrict__ csr_src,
    const float* __restrict__ csr_w, const float* __restrict__ dinv,
    const __half* __restrict__ xw16, const float* __restrict__ xp,
    const float* __restrict__ gcn_b, const float* __restrict__ g,
    const float* __restrict__ bb, float* __restrict__ h_init) {
  int n = wave_node();
  int lane = threadIdx.x & 63;
  float di = dinv[n];
  float acc = di * di * __half2float(xw16[(size_t)n * HID + lane]);  // self loop
  int beg = row_ptr[n], end = row_ptr[n + 1];
  int i = beg;
  for (; i + 2 <= end; i += 2) {
    int s0 = __builtin_amdgcn_readfirstlane(csr_src[i]);
    int s1 = __builtin_amdgcn_readfirstlane(csr_src[i + 1]);
    float nrm0 = dinv[s0] * csr_w[i] * di;
    float nrm1 = dinv[s1] * csr_w[i + 1] * di;
    float v0 = __half2float(xw16[(size_t)s0 * HID + lane]);
    float v1 = __half2float(xw16[(size_t)s1 * HID + lane]);
    acc += nrm0 * v0 + nrm1 * v1;
  }
  if (i < end) {
    int s = __builtin_amdgcn_readfirstlane(csr_src[i]);
    float nrm = dinv[s] * csr_w[i] * di;
    acc += nrm * __half2float(xw16[(size_t)s * HID + lane]);
  }
  float v = acc + gcn_b[lane];
  float mu = wsum(v) * (1.f / HID);
  float dv = v - mu;
  float var = wsum(dv * dv) * (1.f / HID);
  float h = dv * rsqrtf(var + 1e-5f) * g[lane] + bb[lane];
  h = h > 0.f ? h : 0.f;
  h_init[(size_t)n * HID + lane] = h + xp[(size_t)n * HID + lane];
}

// ---------------- GATv2 linear: xl = h@Wl, xr = h@Wr (fp16 out, each [N,256]) ----
// LDS-staged h tile (8 nodes x 64, 2 KB); same broadcast pattern as k_in_gemm.
__global__ __launch_bounds__(512) void k_gat_gemm(
    const float* __restrict__ h, const float* __restrict__ Wl,
    const float* __restrict__ Wr, __half* __restrict__ xl, __half* __restrict__ xr) {
  __shared__ float ht[8][HID];
  int t = threadIdx.x;
  int n0 = blockIdx.x * 8;
  if (t < 128) {
    reinterpret_cast<float4*>(&ht[0][0])[t] =
        reinterpret_cast<const float4*>(h + (size_t)n0 * HID)[t];
  }
  __syncthreads();
  int f = t & 255;
  bool right = t >= 256;
  const float* W = right ? Wr : Wl;
  __half* out = right ? xr : xl;
  float acc[8] = {0.f,0.f,0.f,0.f,0.f,0.f,0.f,0.f};
  for (int k = 0; k < HID; k += 4) {
    float w0 = W[(k + 0) * 256 + f];
    float w1 = W[(k + 1) * 256 + f];
    float w2 = W[(k + 2) * 256 + f];
    float w3 = W[(k + 3) * 256 + f];
#pragma unroll
    for (int j = 0; j < 8; ++j) {
      float4 hv = *reinterpret_cast<const float4*>(&ht[j][k]);
      acc[j] += hv.x * w0 + hv.y * w1 + hv.z * w2 + hv.w * w3;
    }
  }
#pragma unroll
  for (int j = 0; j < 8; ++j) out[(size_t)(n0 + j) * 256 + f] = __float2half(acc[j]);
}

// ---------------- GATv2 fused: softmax (no max shift) + aggregate + mean + LN ---
__global__ __launch_bounds__(256) void k_gat_fused(
    const int* __restrict__ row_ptr, const int* __restrict__ csr_src,
    const __half* __restrict__ xl, const __half* __restrict__ xr,
    const float* __restrict__ att, const float* __restrict__ gat_b,
    const float* __restrict__ g, const float* __restrict__ bb,
    const float* __restrict__ h_init, float* __restrict__ h2,
    __half* __restrict__ h2_16) {
  int n = wave_node();
  int lane = threadIdx.x & 63;
  float4 atv = *reinterpret_cast<const float4*>(att + lane * 4);
  float4 xrv = ld_half4(xr + (size_t)n * 256 + lane * 4);
  float4 xlv = ld_half4(xl + (size_t)n * 256 + lane * 4);

  float q, v;
  v = xlv.x + xrv.x; q  = (v > 0.f ? v : 0.2f * v) * atv.x;
  v = xlv.y + xrv.y; q += (v > 0.f ? v : 0.2f * v) * atv.y;
  v = xlv.z + xrv.z; q += (v > 0.f ? v : 0.2f * v) * atv.z;
  v = xlv.w + xrv.w; q += (v > 0.f ? v : 0.2f * v) * atv.w;
  q += __shfl_xor(q, 1); q += __shfl_xor(q, 2);
  q += __shfl_xor(q, 4); q += __shfl_xor(q, 8);
  float w = __expf(q);
  float den = w;
  float4 acc = make_float4(w * xlv.x, w * xlv.y, w * xlv.z, w * xlv.w);

  int beg = row_ptr[n], end = row_ptr[n + 1];
  int i = beg;
  for (; i + 2 <= end; i += 2) {
    int s0 = __builtin_amdgcn_readfirstlane(csr_src[i]);
    int s1 = __builtin_amdgcn_readfirstlane(csr_src[i + 1]);
    float4 a0 = ld_half4(xl + (size_t)s0 * 256 + lane * 4);
    float4 a1 = ld_half4(xl + (size_t)s1 * 256 + lane * 4);
    float q0, q1;
    v = a0.x + xrv.x; q0  = (v > 0.f ? v : 0.2f * v) * atv.x;
    v = a0.y + xrv.y; q0 += (v > 0.f ? v : 0.2f * v) * atv.y;
    v = a0.z + xrv.z; q0 += (v > 0.f ? v : 0.2f * v) * atv.z;
    v = a0.w + xrv.w; q0 += (v > 0.f ? v : 0.2f * v) * atv.w;
    v = a1.x + xrv.x; q1  = (v > 0.f ? v : 0.2f * v) * atv.x;
    v = a1.y + xrv.y; q1 += (v > 0.f ? v : 0.2f * v) * atv.y;
    v = a1.z + xrv.z; q1 += (v > 0.f ? v : 0.2f * v) * atv.z;
    v = a1.w + xrv.w; q1 += (v > 0.f ? v : 0.2f * v) * atv.w;
    q0 += __shfl_xor(q0, 1); q1 += __shfl_xor(q1, 1);
    q0 += __shfl_xor(q0, 2); q1 += __shfl_xor(q1, 2);
    q0 += __shfl_xor(q0, 4); q1 += __shfl_xor(q1, 4);
    q0 += __shfl_xor(q0, 8); q1 += __shfl_xor(q1, 8);
    float w0 = __expf(q0), w1 = __expf(q1);
    den += w0 + w1;
    acc.x += w0 * a0.x + w1 * a1.x;
    acc.y += w0 * a0.y + w1 * a1.y;
    acc.z += w0 * a0.z + w1 * a1.z;
    acc.w += w0 * a0.w + w1 * a1.w;
  }
  if (i < end) {
    int s0 = __builtin_amdgcn_readfirstlane(csr_src[i]);
    float4 a0 = ld_half4(xl + (size_t)s0 * 256 + lane * 4);
    v = a0.x + xrv.x; q  = (v > 0.f ? v : 0.2f * v) * atv.x;
    v = a0.y + xrv.y; q += (v > 0.f ? v : 0.2f * v) * atv.y;
    v = a0.z + xrv.z; q += (v > 0.f ? v : 0.2f * v) * atv.z;
    v = a0.w + xrv.w; q += (v > 0.f ? v : 0.2f * v) * atv.w;
    q += __shfl_xor(q, 1); q += __shfl_xor(q, 2);
    q += __shfl_xor(q, 4); q += __shfl_xor(q, 8);
    w = __expf(q);
    den += w;
    acc.x += w * a0.x; acc.y += w * a0.y;
    acc.z += w * a0.z; acc.w += w * a0.w;
  }
  float inv = 1.f / den;
  acc.x *= inv; acc.y *= inv; acc.z *= inv; acc.w *= inv;
  acc.x += __shfl_xor(acc.x, 16); acc.y += __shfl_xor(acc.y, 16);
  acc.z += __shfl_xor(acc.z, 16); acc.w += __shfl_xor(acc.w, 16);
  acc.x += __shfl_xor(acc.x, 32); acc.y += __shfl_xor(acc.y, 32);
  acc.z += __shfl_xor(acc.z, 32); acc.w += __shfl_xor(acc.w, 32);
  int srcl = lane >> 2;
  float t0 = __shfl(acc.x, srcl), t1 = __shfl(acc.y, srcl);
  float t2 = __shfl(acc.z, srcl), t3 = __shfl(acc.w, srcl);
  int r = lane & 3;
  float mean = (r == 0) ? t0 : (r == 1) ? t1 : (r == 2) ? t2 : t3;
  float val = mean * 0.25f + gat_b[lane];
  float mu = wsum(val) * (1.f / HID);
  float dv = val - mu;
  float var = wsum(dv * dv) * (1.f / HID);
  float h = dv * rsqrtf(var + 1e-5f) * g[lane] + bb[lane];
  h = h > 0.f ? h : 0.f;
  float outv = h + h_init[(size_t)n * HID + lane];
  h2[(size_t)n * HID + lane] = outv;
  h2_16[(size_t)n * HID + lane] = __float2half(outv);
}

// ---------------- SAGE stage 1: pull mean-gather (fp32 out, n in SGPR, 2x ILP) --
__global__ __launch_bounds__(256) void k_sage_gather(
    const int* __restrict__ row_ptr, const int* __restrict__ csr_src,
    const __half* __restrict__ h2_16, float* __restrict__ nmean) {
  int n = wave_node();
  int lane = threadIdx.x & 63;
  int beg = row_ptr[n], end = row_ptr[n + 1];
  float sum = 0.f;
  int i = beg;
  for (; i + 2 <= end; i += 2) {
    int s0 = __builtin_amdgcn_readfirstlane(csr_src[i]);
    int s1 = __builtin_amdgcn_readfirstlane(csr_src[i + 1]);
    float v0 = __half2float(h2_16[(size_t)s0 * HID + lane]);
    float v1 = __half2float(h2_16[(size_t)s1 * HID + lane]);
    sum += v0 + v1;
  }
  if (i < end) {
    int s = __builtin_amdgcn_readfirstlane(csr_src[i]);
    sum += __half2float(h2_16[(size_t)s * HID + lane]);
  }
  nmean[(size_t)n * HID + lane] = sum / fmaxf((float)(end - beg), 1.f);
}

// ---------------- SAGE stage 2: dense nmean@Wl + h2@Wr + LN (LDS-staged acts) ---
__global__ __launch_bounds__(64) void k_sage_gemm_ln(
    const float* __restrict__ nmean, const float* __restrict__ h2,
    const float* __restrict__ Wl, const float* __restrict__ Wr,
    const float* __restrict__ sage_bl, const float* __restrict__ g,
    const float* __restrict__ bb, float* __restrict__ h3) {
  __shared__ float nt[8][HID];
  __shared__ float ht[8][HID];
  int t = threadIdx.x;
  int n0 = blockIdx.x * 8;
  {
    const float4* ng = reinterpret_cast<const float4*>(nmean + (size_t)n0 * HID);
    const float4* hg = reinterpret_cast<const float4*>(h2 + (size_t)n0 * HID);
    float4* ns = reinterpret_cast<float4*>(&nt[0][0]);
    float4* hs = reinterpret_cast<float4*>(&ht[0][0]);
#pragma unroll
    for (int r = 0; r < 2; ++r) { ns[t + r * 64] = ng[t + r * 64]; hs[t + r * 64] = hg[t + r * 64]; }
  }
  __syncthreads();
  int f = t;
  float acc[8] = {0.f,0.f,0.f,0.f,0.f,0.f,0.f,0.f};
  for (int k = 0; k < HID; k += 4) {
    float wl0 = Wl[(k + 0) * HID + f], wr0 = Wr[(k + 0) * HID + f];
    float wl1 = Wl[(k + 1) * HID + f], wr1 = Wr[(k + 1) * HID + f];
    float wl2 = Wl[(k + 2) * HID + f], wr2 = Wr[(k + 2) * HID + f];
    float wl3 = Wl[(k + 3) * HID + f], wr3 = Wr[(k + 3) * HID + f];
#pragma unroll
    for (int j = 0; j < 8; ++j) {
      float4 nv = *reinterpret_cast<const float4*>(&nt[j][k]);
      float4 hv = *reinterpret_cast<const float4*>(&ht[j][k]);
      acc[j] += nv.x * wl0 + nv.y * wl1 + nv.z * wl2 + nv.w * wl3
              + hv.x * wr0 + hv.y * wr1 + hv.z * wr2 + hv.w * wr3;
    }
  }
  float blv = sage_bl[f], gv = g[f], bbv = bb[f];
#pragma unroll
  for (int j = 0; j < 8; ++j) {
    float v = acc[j] + blv;
    float mu = wsum(v) * (1.f / HID);
    float dv = v - mu;
    float var = wsum(dv * dv) * (1.f / HID);
    float h = dv * rsqrtf(var + 1e-5f) * gv + bbv;
    h = h > 0.f ? h : 0.f;
    h3[(size_t)(n0 + j) * HID + f] = h + ht[j][f];
  }
}

// ---------------- heads ----------------
__global__ __launch_bounds__(256) void k_heads(
    const float* __restrict__ h_init, const float* __restrict__ h2,
    const float* __restrict__ h3, const int* __restrict__ mask,
    const float* __restrict__ mort_W, const float* __restrict__ mort_b,
    const float* __restrict__ hours_W, const float* __restrict__ hours_b,
    const float* __restrict__ disc_W, const float* __restrict__ disc_b,
    float* __restrict__ out) {
  int n = wave_node();
  int lane = threadIdx.x & 63;
  float m = (mask[n] != 0) ? 1.f : 0.f;
  size_t base = (size_t)n * HID;
  float v0 = h_init[base + lane] * m;
  float v1 = h2[base + lane] * m;
  float v2 = h3[base + lane] * m;
  float pm = v0 * mort_W[lane] + v1 * mort_W[64 + lane] + v2 * mort_W[128 + lane];
  float ph = v0 * hours_W[lane] + v1 * hours_W[64 + lane] + v2 * hours_W[128 + lane];
  float d0 = v0 * disc_W[lane * 4 + 0] + v1 * disc_W[(64 + lane) * 4 + 0] + v2 * disc_W[(128 + lane) * 4 + 0];
  float d1 = v0 * disc_W[lane * 4 + 1] + v1 * disc_W[(64 + lane) * 4 + 1] + v2 * disc_W[(128 + lane) * 4 + 1];
  float d2 = v0 * disc_W[lane * 4 + 2] + v1 * disc_W[(64 + lane) * 4 + 2] + v2 * disc_W[(128 + lane) * 4 + 2];
  float d3 = v0 * disc_W[lane * 4 + 3] + v1 * disc_W[(64 + lane) * 4 + 3] + v2 * disc_W[(128 + lane) * 4 + 3];
  pm = wsum(pm); ph = wsum(ph);
  d0 = wsum(d0); d1 = wsum(d1); d2 = wsum(d2); d3 = wsum(d3);
  if (lane == 0) {
    out[n] = pm + mort_b[0];
    out[N_NODES + n] = ph + hours_b[0];
    float* dd = out + 2 * N_NODES + (size_t)n * 4;
    dd[0] = d0 + disc_b[0];
    dd[1] = d1 + disc_b[1];
    dd[2] = d2 + disc_b[2];
    dd[3] = d3 + disc_b[3];
  }
}

extern "C" void kernel_launch(void* const* d_in, const int* in_sizes, int n_in,
                              void* d_out, int out_size, void* d_ws, size_t ws_size,
                              hipStream_t stream) {
  const float* x       = (const float*)d_in[0];
  const int*   ei      = (const int*)d_in[1];
  const float* ew      = (const float*)d_in[2];
  const int*   mask    = (const int*)d_in[3];
  const float* gcn_W   = (const float*)d_in[4];
  const float* gcn_b   = (const float*)d_in[5];
  const float* proj_W  = (const float*)d_in[6];
  const float* proj_b  = (const float*)d_in[7];
  const float* ln1_g   = (const float*)d_in[8];
  const float* ln1_b   = (const float*)d_in[9];
  const float* gat_Wl  = (const float*)d_in[10];
  const float* gat_Wr  = (const float*)d_in[11];
  const float* gat_att = (const float*)d_in[12];
  const float* gat_b   = (const float*)d_in[13];
  const float* ln2_g   = (const float*)d_in[14];
  const float* ln2_b   = (const float*)d_in[15];
  const float* sage_Wl = (const float*)d_in[16];
  const float* sage_bl = (const float*)d_in[17];
  const float* sage_Wr = (const float*)d_in[18];
  const float* ln3_g   = (const float*)d_in[19];
  const float* ln3_b   = (const float*)d_in[20];
  // d_in[21..24]: edge-MLP params — output unused by the reference; skipped.
  const float* mort_W  = (const float*)d_in[25];
  const float* mort_b  = (const float*)d_in[26];
  const float* hours_W = (const float*)d_in[27];
  const float* hours_b = (const float*)d_in[28];
  const float* disc_W  = (const float*)d_in[29];
  const float* disc_b  = (const float*)d_in[30];

  const int* src = ei;
  const int* dst = ei + N_EDGES;
  float* out = (float*)d_out;

  // ---- workspace layout (~49M floats = 196 MB) ----
  float* ws = (float*)d_ws;
  const size_t F = (size_t)N_NODES * HID;  // 6.4M floats
  float* h_init = ws;
  float* h2     = ws + 1 * F;
  float* h3     = ws + 2 * F;
  float* xp     = h3;                              // fp32, dead before h3 written
  __half* xl    = (__half*)(ws + 3 * F);           // N*256 halfs
  __half* xw16  = xl;                              // N*64 halfs, dead before xl written
  float* nmean  = ws + 3 * F;                      // fp32 N*64, xl dead by SAGE
  __half* xr    = (__half*)(ws + 3 * F + (size_t)N_NODES * 128);
  __half* h2_16 = (__half*)(ws + 3 * F + (size_t)N_NODES * 256);
  float* tail   = ws + 3 * F + (size_t)N_NODES * 256 + (size_t)N_NODES * 32;
  int*   csr_src = (int*)tail;           tail += N_EDGES;
  float* csr_w   = tail;                 tail += N_EDGES;
  int*   row_ptr = (int*)tail;           tail += N_NODES + 64;
  int*   cursor  = (int*)tail;           tail += N_NODES;
  int*   cnt     = (int*)tail;           tail += N_NODES;
  int*   partial = (int*)tail;           tail += N_NODES;
  int*   bsum    = (int*)tail;           tail += 128;
  float* dinv    = tail;

  const int GE = (N_EDGES + 255) / 256;
  const int GN = (N_NODES + 255) / 256;

  // --- CSR build (by dst) ---
  k_zero_cnt<<<GN, 256, 0, stream>>>(cnt);
  k_hist<<<GE, 256, 0, stream>>>(dst, cnt);
  k_scan1<<<SCAN_BLK, 256, 0, stream>>>(cnt, partial, bsum);
  k_scan2<<<1, 128, 0, stream>>>(bsum);
  k_scan3<<<GN, 256, 0, stream>>>(partial, bsum, row_ptr, cursor);
  k_fill<<<GE, 256, 0, stream>>>(src, dst, ew, cursor, csr_src, csr_w);

  // --- GCN layer ---
  k_in_gemm<<<N_NODES / 8, 128, 0, stream>>>(x, gcn_W, proj_W, proj_b, xw16, xp);
  k_deg<<<GN, 256, 0, stream>>>(row_ptr, csr_w, dinv);
  k_gcn_fused<<<N_NODES / 4, 256, 0, stream>>>(row_ptr, csr_src, csr_w, dinv, xw16,
                                               xp, gcn_b, ln1_g, ln1_b, h_init);

  // --- GATv2 layer ---
  k_gat_gemm<<<N_NODES / 8, 512, 0, stream>>>(h_init, gat_Wl, gat_Wr, xl, xr);
  k_gat_fused<<<N_NODES / 4, 256, 0, stream>>>(row_ptr, csr_src, xl, xr, gat_att,
                                               gat_b, ln2_g, ln2_b, h_init, h2, h2_16);

  // --- SAGE layer ---
  k_sage_gather<<<N_NODES / 4, 256, 0, stream>>>(row_ptr, csr_src, h2_16, nmean);
  k_sage_gemm_ln<<<N_NODES / 8, 64, 0, stream>>>(nmean, h2, sage_Wl, sage_Wr,
                                                 sage_bl, ln3_g, ln3_b, h3);

  // --- heads ---
  k_heads<<<N_NODES / 4, 256, 0, stream>>>(h_init, h2, h3, mask, mort_W, mort_b,
                                           hours_W, hours_b, disc_W, disc_b, out);
}

// Round 9
// 600.204 us; speedup vs baseline: 1.7079x; 1.2776x over previous
//
#include <hip/hip_runtime.h>
#include <hip/hip_fp16.h>
#include <math.h>

#define N_NODES 100000
#define N_EDGES 1000000
#define F_IN    128
#define HID     64
#define HEADS   4
#define NCLS    4
#define SCAN_BLK 98   // ceil(N_NODES / 1024)
#define GEMM_NT 5     // node-tiles per block in MFMA GEMMs (80 nodes/block)

typedef _Float16 half8 __attribute__((ext_vector_type(8)));
typedef float f32x4 __attribute__((ext_vector_type(4)));

// ---------------- helpers ----------------
__device__ __forceinline__ float wsum(float v) {
#pragma unroll
  for (int o = 32; o > 0; o >>= 1) v += __shfl_xor(v, o, 64);
  return v;
}
struct Half4 { __half2 a, b; };
__device__ __forceinline__ float4 ld_half4(const __half* p) {
  Half4 h = *reinterpret_cast<const Half4*>(p);
  float2 f0 = __half22float2(h.a), f1 = __half22float2(h.b);
  return make_float4(f0.x, f0.y, f1.x, f1.y);
}
// wave-uniform node id -> SGPR (row_ptr/csr reads become scalar loads)
__device__ __forceinline__ int wave_node() {
  return __builtin_amdgcn_readfirstlane(blockIdx.x * 4 + (threadIdx.x >> 6));
}

// ---------------- CSR build (by dst) ----------------
__global__ void k_zero_cnt(int* __restrict__ cnt) {
  int i = blockIdx.x * 256 + threadIdx.x;
  if (i < N_NODES) cnt[i] = 0;
}
__global__ void k_hist(const int* __restrict__ dst, int* __restrict__ cnt) {
  int e = blockIdx.x * 256 + threadIdx.x;
  if (e < N_EDGES) atomicAdd(&cnt[dst[e]], 1);
}
__global__ __launch_bounds__(256) void k_scan1(const int* __restrict__ cnt,
                                               int* __restrict__ partial,
                                               int* __restrict__ bsum) {
  __shared__ int lds[256];
  int t = threadIdx.x;
  int base = blockIdx.x * 1024 + t * 4;
  int v0 = (base + 0 < N_NODES) ? cnt[base + 0] : 0;
  int v1 = (base + 1 < N_NODES) ? cnt[base + 1] : 0;
  int v2 = (base + 2 < N_NODES) ? cnt[base + 2] : 0;
  int v3 = (base + 3 < N_NODES) ? cnt[base + 3] : 0;
  int s = v0 + v1 + v2 + v3;
  lds[t] = s;
  __syncthreads();
  for (int o = 1; o < 256; o <<= 1) {
    int x = (t >= o) ? lds[t - o] : 0;
    __syncthreads();
    lds[t] += x;
    __syncthreads();
  }
  int excl = lds[t] - s;
  if (base + 0 < N_NODES) partial[base + 0] = excl;
  if (base + 1 < N_NODES) partial[base + 1] = excl + v0;
  if (base + 2 < N_NODES) partial[base + 2] = excl + v0 + v1;
  if (base + 3 < N_NODES) partial[base + 3] = excl + v0 + v1 + v2;
  if (t == 255) bsum[blockIdx.x] = lds[255];
}
__global__ void k_scan2(int* __restrict__ bsum) {  // 1 block, 128 threads
  __shared__ int lds[128];
  int t = threadIdx.x;
  int v = (t < SCAN_BLK) ? bsum[t] : 0;
  lds[t] = v;
  __syncthreads();
  for (int o = 1; o < 128; o <<= 1) {
    int x = (t >= o) ? lds[t - o] : 0;
    __syncthreads();
    lds[t] += x;
    __syncthreads();
  }
  if (t < SCAN_BLK) bsum[t] = lds[t] - v;  // exclusive
}
__global__ void k_scan3(const int* __restrict__ partial, const int* __restrict__ bsum,
                        int* __restrict__ row_ptr, int* __restrict__ cursor) {
  int i = blockIdx.x * 256 + threadIdx.x;
  if (i < N_NODES) {
    int v = partial[i] + bsum[i >> 10];
    row_ptr[i] = v;
    cursor[i] = v;
  }
  if (i == 0) row_ptr[N_NODES] = N_EDGES;
}
__global__ void k_fill(const int* __restrict__ src, const int* __restrict__ dst,
                       const float* __restrict__ ew, int* __restrict__ cursor,
                       int* __restrict__ csr_src, float* __restrict__ csr_w) {
  int e = blockIdx.x * 256 + threadIdx.x;
  if (e >= N_EDGES) return;
  int d = dst[e];
  int p = atomicAdd(&cursor[d], 1);
  csr_src[p] = src[e];
  csr_w[p] = ew[e];
}

// ---------------- MFMA GEMM 1: [xw16|xp] = x @ [gcn_W|proj_W]  (K=128, N=128) ----
// A staged fp32->fp16 in LDS (row stride 136 halfs: 2-way banks = free).
// Layouts: A m=lane&15,k=q*8+j ; B n=lane&15,k=q*8+j ; C col=lane&15,row=q*4+r.
__global__ __launch_bounds__(512) void k_in_gemm_mfma(
    const float* __restrict__ x, const float* __restrict__ gcn_W,
    const float* __restrict__ proj_W, const float* __restrict__ proj_b,
    __half* __restrict__ xw16, float* __restrict__ xp) {
  __shared__ __half at[16 * 136];
  int t = threadIdx.x;
  int w = t >> 6, lane = t & 63;
  int m = lane & 15, q = lane >> 4;
  int ncol = w * 16 + m;                 // 0..127
  const float* W = (ncol < 64) ? gcn_W : proj_W;
  int nc = (ncol < 64) ? ncol : ncol - 64;
  half8 bf[4];
#pragma unroll
  for (int ch = 0; ch < 4; ++ch) {
    int kb = ch * 32 + q * 8;
#pragma unroll
    for (int j = 0; j < 8; ++j)
      bf[ch][j] = (_Float16)W[(kb + j) * 64 + nc];
  }
  float pb = (ncol >= 64) ? proj_b[nc] : 0.f;
  int nb0 = blockIdx.x * (16 * GEMM_NT);
  for (int nt = 0; nt < GEMM_NT; ++nt) {
    int nb = nb0 + nt * 16;
    {
      int row = t >> 5, col = (t & 31) * 4;
      float4 v = *reinterpret_cast<const float4*>(x + (size_t)(nb + row) * F_IN + col);
      __half2* d = reinterpret_cast<__half2*>(&at[row * 136 + col]);
      d[0] = __floats2half2_rn(v.x, v.y);
      d[1] = __floats2half2_rn(v.z, v.w);
    }
    __syncthreads();
    f32x4 acc = {0.f, 0.f, 0.f, 0.f};
#pragma unroll
    for (int ch = 0; ch < 4; ++ch) {
      half8 af = *reinterpret_cast<const half8*>(&at[m * 136 + ch * 32 + q * 8]);
      acc = __builtin_amdgcn_mfma_f32_16x16x32_f16(af, bf[ch], acc, 0, 0, 0);
    }
    if (ncol < 64) {
#pragma unroll
      for (int r = 0; r < 4; ++r)
        xw16[(size_t)(nb + q * 4 + r) * HID + nc] = __float2half(acc[r]);
    } else {
#pragma unroll
      for (int r = 0; r < 4; ++r)
        xp[(size_t)(nb + q * 4 + r) * HID + nc] = acc[r] + pb;
    }
    __syncthreads();
  }
}

// ---------------- GCN: deg/dinv from CSR (no atomics) ----------------
__global__ void k_deg(const int* __restrict__ row_ptr, const float* __restrict__ csr_w,
                      float* __restrict__ dinv) {
  int n = blockIdx.x * 256 + threadIdx.x;
  if (n >= N_NODES) return;
  float deg = 1.0f;  // self-loop weight
  int end = row_ptr[n + 1];
  for (int i = row_ptr[n]; i < end; ++i) deg += csr_w[i];
  dinv[n] = rsqrtf(deg);  // deg >= 1 always
}

// pull-gather + LN + relu + residual, one wave per node (n in SGPR), 2x ILP
// also emits fp16 copy of h_init for the MFMA GAT GEMM.
__global__ __launch_bounds__(256) void k_gcn_fused(
    const int* __restrict__ row_ptr, const int* __restrict__ csr_src,
    const float* __restrict__ csr_w, const float* __restrict__ dinv,
    const __half* __restrict__ xw16, const float* __restrict__ xp,
    const float* __restrict__ gcn_b, const float* __restrict__ g,
    const float* __restrict__ bb, float* __restrict__ h_init,
    __half* __restrict__ h_init16) {
  int n = wave_node();
  int lane = threadIdx.x & 63;
  float di = dinv[n];
  float acc = di * di * __half2float(xw16[(size_t)n * HID + lane]);  // self loop
  int beg = row_ptr[n], end = row_ptr[n + 1];
  int i = beg;
  for (; i + 2 <= end; i += 2) {
    int s0 = __builtin_amdgcn_readfirstlane(csr_src[i]);
    int s1 = __builtin_amdgcn_readfirstlane(csr_src[i + 1]);
    float nrm0 = dinv[s0] * csr_w[i] * di;
    float nrm1 = dinv[s1] * csr_w[i + 1] * di;
    float v0 = __half2float(xw16[(size_t)s0 * HID + lane]);
    float v1 = __half2float(xw16[(size_t)s1 * HID + lane]);
    acc += nrm0 * v0 + nrm1 * v1;
  }
  if (i < end) {
    int s = __builtin_amdgcn_readfirstlane(csr_src[i]);
    float nrm = dinv[s] * csr_w[i] * di;
    acc += nrm * __half2float(xw16[(size_t)s * HID + lane]);
  }
  float v = acc + gcn_b[lane];
  float mu = wsum(v) * (1.f / HID);
  float dv = v - mu;
  float var = wsum(dv * dv) * (1.f / HID);
  float h = dv * rsqrtf(var + 1e-5f) * g[lane] + bb[lane];
  h = h > 0.f ? h : 0.f;
  float outv = h + xp[(size_t)n * HID + lane];
  h_init[(size_t)n * HID + lane] = outv;
  h_init16[(size_t)n * HID + lane] = __float2half(outv);
}

// ---------------- MFMA GEMM 2: [xl|xr] = h16 @ [Wl|Wr]  (K=64, N=512) ----------
// A-tile (16x64 fp16, stride 72) shared by all 8 waves; each wave owns 4 col-tiles.
__global__ __launch_bounds__(512) void k_gat_gemm_mfma(
    const __half* __restrict__ h16, const float* __restrict__ Wl,
    const float* __restrict__ Wr, __half* __restrict__ xl, __half* __restrict__ xr) {
  __shared__ __half at[16 * 72];
  int t = threadIdx.x;
  int w = t >> 6, lane = t & 63;
  int m = lane & 15, q = lane >> 4;
  half8 bf[4][2];
#pragma unroll
  for (int tt = 0; tt < 4; ++tt) {
    int c = w * 16 + tt * 128 + m;          // 0..511
    const float* W = (c < 256) ? Wl : Wr;
    int nc = (c < 256) ? c : c - 256;
#pragma unroll
    for (int ch = 0; ch < 2; ++ch) {
      int kb = ch * 32 + q * 8;
#pragma unroll
      for (int j = 0; j < 8; ++j)
        bf[tt][ch][j] = (_Float16)W[(kb + j) * 256 + nc];
    }
  }
  int nb0 = blockIdx.x * (16 * GEMM_NT);
  for (int nt = 0; nt < GEMM_NT; ++nt) {
    int nb = nb0 + nt * 16;
    {
      int row = t >> 5, col = (t & 31) * 2;
      *reinterpret_cast<__half2*>(&at[row * 72 + col]) =
          *reinterpret_cast<const __half2*>(h16 + (size_t)(nb + row) * HID + col);
    }
    __syncthreads();
    half8 a0 = *reinterpret_cast<const half8*>(&at[m * 72 + q * 8]);
    half8 a1 = *reinterpret_cast<const half8*>(&at[m * 72 + 32 + q * 8]);
#pragma unroll
    for (int tt = 0; tt < 4; ++tt) {
      f32x4 acc = {0.f, 0.f, 0.f, 0.f};
      acc = __builtin_amdgcn_mfma_f32_16x16x32_f16(a0, bf[tt][0], acc, 0, 0, 0);
      acc = __builtin_amdgcn_mfma_f32_16x16x32_f16(a1, bf[tt][1], acc, 0, 0, 0);
      int c = w * 16 + tt * 128 + m;
      __half* out = (c < 256) ? (xl + c) : (xr + (c - 256));
#pragma unroll
      for (int r = 0; r < 4; ++r)
        out[(size_t)(nb + q * 4 + r) * 256] = __float2half(acc[r]);
    }
    __syncthreads();
  }
}

// ---------------- GATv2 fused: softmax (no max shift) + aggregate + mean + LN ---
__global__ __launch_bounds__(256) void k_gat_fused(
    const int* __restrict__ row_ptr, const int* __restrict__ csr_src,
    const __half* __restrict__ xl, const __half* __restrict__ xr,
    const float* __restrict__ att, const float* __restrict__ gat_b,
    const float* __restrict__ g, const float* __restrict__ bb,
    const float* __restrict__ h_init, float* __restrict__ h2,
    __half* __restrict__ h2_16) {
  int n = wave_node();
  int lane = threadIdx.x & 63;
  float4 atv = *reinterpret_cast<const float4*>(att + lane * 4);
  float4 xrv = ld_half4(xr + (size_t)n * 256 + lane * 4);
  float4 xlv = ld_half4(xl + (size_t)n * 256 + lane * 4);

  float q, v;
  v = xlv.x + xrv.x; q  = (v > 0.f ? v : 0.2f * v) * atv.x;
  v = xlv.y + xrv.y; q += (v > 0.f ? v : 0.2f * v) * atv.y;
  v = xlv.z + xrv.z; q += (v > 0.f ? v : 0.2f * v) * atv.z;
  v = xlv.w + xrv.w; q += (v > 0.f ? v : 0.2f * v) * atv.w;
  q += __shfl_xor(q, 1); q += __shfl_xor(q, 2);
  q += __shfl_xor(q, 4); q += __shfl_xor(q, 8);
  float w = __expf(q);
  float den = w;
  float4 acc = make_float4(w * xlv.x, w * xlv.y, w * xlv.z, w * xlv.w);

  int beg = row_ptr[n], end = row_ptr[n + 1];
  int i = beg;
  for (; i + 2 <= end; i += 2) {
    int s0 = __builtin_amdgcn_readfirstlane(csr_src[i]);
    int s1 = __builtin_amdgcn_readfirstlane(csr_src[i + 1]);
    float4 a0 = ld_half4(xl + (size_t)s0 * 256 + lane * 4);
    float4 a1 = ld_half4(xl + (size_t)s1 * 256 + lane * 4);
    float q0, q1;
    v = a0.x + xrv.x; q0  = (v > 0.f ? v : 0.2f * v) * atv.x;
    v = a0.y + xrv.y; q0 += (v > 0.f ? v : 0.2f * v) * atv.y;
    v = a0.z + xrv.z; q0 += (v > 0.f ? v : 0.2f * v) * atv.z;
    v = a0.w + xrv.w; q0 += (v > 0.f ? v : 0.2f * v) * atv.w;
    v = a1.x + xrv.x; q1  = (v > 0.f ? v : 0.2f * v) * atv.x;
    v = a1.y + xrv.y; q1 += (v > 0.f ? v : 0.2f * v) * atv.y;
    v = a1.z + xrv.z; q1 += (v > 0.f ? v : 0.2f * v) * atv.z;
    v = a1.w + xrv.w; q1 += (v > 0.f ? v : 0.2f * v) * atv.w;
    q0 += __shfl_xor(q0, 1); q1 += __shfl_xor(q1, 1);
    q0 += __shfl_xor(q0, 2); q1 += __shfl_xor(q1, 2);
    q0 += __shfl_xor(q0, 4); q1 += __shfl_xor(q1, 4);
    q0 += __shfl_xor(q0, 8); q1 += __shfl_xor(q1, 8);
    float w0 = __expf(q0), w1 = __expf(q1);
    den += w0 + w1;
    acc.x += w0 * a0.x + w1 * a1.x;
    acc.y += w0 * a0.y + w1 * a1.y;
    acc.z += w0 * a0.z + w1 * a1.z;
    acc.w += w0 * a0.w + w1 * a1.w;
  }
  if (i < end) {
    int s0 = __builtin_amdgcn_readfirstlane(csr_src[i]);
    float4 a0 = ld_half4(xl + (size_t)s0 * 256 + lane * 4);
    v = a0.x + xrv.x; q  = (v > 0.f ? v : 0.2f * v) * atv.x;
    v = a0.y + xrv.y; q += (v > 0.f ? v : 0.2f * v) * atv.y;
    v = a0.z + xrv.z; q += (v > 0.f ? v : 0.2f * v) * atv.z;
    v = a0.w + xrv.w; q += (v > 0.f ? v : 0.2f * v) * atv.w;
    q += __shfl_xor(q, 1); q += __shfl_xor(q, 2);
    q += __shfl_xor(q, 4); q += __shfl_xor(q, 8);
    w = __expf(q);
    den += w;
    acc.x += w * a0.x; acc.y += w * a0.y;
    acc.z += w * a0.z; acc.w += w * a0.w;
  }
  float inv = 1.f / den;
  acc.x *= inv; acc.y *= inv; acc.z *= inv; acc.w *= inv;
  acc.x += __shfl_xor(acc.x, 16); acc.y += __shfl_xor(acc.y, 16);
  acc.z += __shfl_xor(acc.z, 16); acc.w += __shfl_xor(acc.w, 16);
  acc.x += __shfl_xor(acc.x, 32); acc.y += __shfl_xor(acc.y, 32);
  acc.z += __shfl_xor(acc.z, 32); acc.w += __shfl_xor(acc.w, 32);
  int srcl = lane >> 2;
  float t0 = __shfl(acc.x, srcl), t1 = __shfl(acc.y, srcl);
  float t2 = __shfl(acc.z, srcl), t3 = __shfl(acc.w, srcl);
  int r = lane & 3;
  float mean = (r == 0) ? t0 : (r == 1) ? t1 : (r == 2) ? t2 : t3;
  float val = mean * 0.25f + gat_b[lane];
  float mu = wsum(val) * (1.f / HID);
  float dv = val - mu;
  float var = wsum(dv * dv) * (1.f / HID);
  float h = dv * rsqrtf(var + 1e-5f) * g[lane] + bb[lane];
  h = h > 0.f ? h : 0.f;
  float outv = h + h_init[(size_t)n * HID + lane];
  h2[(size_t)n * HID + lane] = outv;
  h2_16[(size_t)n * HID + lane] = __float2half(outv);
}

// ---------------- SAGE stage 1: pull mean-gather (fp32 out, n in SGPR, 2x ILP) --
__global__ __launch_bounds__(256) void k_sage_gather(
    const int* __restrict__ row_ptr, const int* __restrict__ csr_src,
    const __half* __restrict__ h2_16, float* __restrict__ nmean) {
  int n = wave_node();
  int lane = threadIdx.x & 63;
  int beg = row_ptr[n], end = row_ptr[n + 1];
  float sum = 0.f;
  int i = beg;
  for (; i + 2 <= end; i += 2) {
    int s0 = __builtin_amdgcn_readfirstlane(csr_src[i]);
    int s1 = __builtin_amdgcn_readfirstlane(csr_src[i + 1]);
    float v0 = __half2float(h2_16[(size_t)s0 * HID + lane]);
    float v1 = __half2float(h2_16[(size_t)s1 * HID + lane]);
    sum += v0 + v1;
  }
  if (i < end) {
    int s = __builtin_amdgcn_readfirstlane(csr_src[i]);
    sum += __half2float(h2_16[(size_t)s * HID + lane]);
  }
  nmean[(size_t)n * HID + lane] = sum / fmaxf((float)(end - beg), 1.f);
}

// ---------------- SAGE stage 2: dense nmean@Wl + h2@Wr + LN (LDS-staged acts) ---
__global__ __launch_bounds__(64) void k_sage_gemm_ln(
    const float* __restrict__ nmean, const float* __restrict__ h2,
    const float* __restrict__ Wl, const float* __restrict__ Wr,
    const float* __restrict__ sage_bl, const float* __restrict__ g,
    const float* __restrict__ bb, float* __restrict__ h3) {
  __shared__ float nt[8][HID];
  __shared__ float ht[8][HID];
  int t = threadIdx.x;
  int n0 = blockIdx.x * 8;
  {
    const float4* ng = reinterpret_cast<const float4*>(nmean + (size_t)n0 * HID);
    const float4* hg = reinterpret_cast<const float4*>(h2 + (size_t)n0 * HID);
    float4* ns = reinterpret_cast<float4*>(&nt[0][0]);
    float4* hs = reinterpret_cast<float4*>(&ht[0][0]);
#pragma unroll
    for (int r = 0; r < 2; ++r) { ns[t + r * 64] = ng[t + r * 64]; hs[t + r * 64] = hg[t + r * 64]; }
  }
  __syncthreads();
  int f = t;
  float acc[8] = {0.f,0.f,0.f,0.f,0.f,0.f,0.f,0.f};
  for (int k = 0; k < HID; k += 4) {
    float wl0 = Wl[(k + 0) * HID + f], wr0 = Wr[(k + 0) * HID + f];
    float wl1 = Wl[(k + 1) * HID + f], wr1 = Wr[(k + 1) * HID + f];
    float wl2 = Wl[(k + 2) * HID + f], wr2 = Wr[(k + 2) * HID + f];
    float wl3 = Wl[(k + 3) * HID + f], wr3 = Wr[(k + 3) * HID + f];
#pragma unroll
    for (int j = 0; j < 8; ++j) {
      float4 nv = *reinterpret_cast<const float4*>(&nt[j][k]);
      float4 hv = *reinterpret_cast<const float4*>(&ht[j][k]);
      acc[j] += nv.x * wl0 + nv.y * wl1 + nv.z * wl2 + nv.w * wl3
              + hv.x * wr0 + hv.y * wr1 + hv.z * wr2 + hv.w * wr3;
    }
  }
  float blv = sage_bl[f], gv = g[f], bbv = bb[f];
#pragma unroll
  for (int j = 0; j < 8; ++j) {
    float v = acc[j] + blv;
    float mu = wsum(v) * (1.f / HID);
    float dv = v - mu;
    float var = wsum(dv * dv) * (1.f / HID);
    float h = dv * rsqrtf(var + 1e-5f) * gv + bbv;
    h = h > 0.f ? h : 0.f;
    h3[(size_t)(n0 + j) * HID + f] = h + ht[j][f];
  }
}

// ---------------- heads ----------------
__global__ __launch_bounds__(256) void k_heads(
    const float* __restrict__ h_init, const float* __restrict__ h2,
    const float* __restrict__ h3, const int* __restrict__ mask,
    const float* __restrict__ mort_W, const float* __restrict__ mort_b,
    const float* __restrict__ hours_W, const float* __restrict__ hours_b,
    const float* __restrict__ disc_W, const float* __restrict__ disc_b,
    float* __restrict__ out) {
  int n = wave_node();
  int lane = threadIdx.x & 63;
  float m = (mask[n] != 0) ? 1.f : 0.f;
  size_t base = (size_t)n * HID;
  float v0 = h_init[base + lane] * m;
  float v1 = h2[base + lane] * m;
  float v2 = h3[base + lane] * m;
  float pm = v0 * mort_W[lane] + v1 * mort_W[64 + lane] + v2 * mort_W[128 + lane];
  float ph = v0 * hours_W[lane] + v1 * hours_W[64 + lane] + v2 * hours_W[128 + lane];
  float d0 = v0 * disc_W[lane * 4 + 0] + v1 * disc_W[(64 + lane) * 4 + 0] + v2 * disc_W[(128 + lane) * 4 + 0];
  float d1 = v0 * disc_W[lane * 4 + 1] + v1 * disc_W[(64 + lane) * 4 + 1] + v2 * disc_W[(128 + lane) * 4 + 1];
  float d2 = v0 * disc_W[lane * 4 + 2] + v1 * disc_W[(64 + lane) * 4 + 2] + v2 * disc_W[(128 + lane) * 4 + 2];
  float d3 = v0 * disc_W[lane * 4 + 3] + v1 * disc_W[(64 + lane) * 4 + 3] + v2 * disc_W[(128 + lane) * 4 + 3];
  pm = wsum(pm); ph = wsum(ph);
  d0 = wsum(d0); d1 = wsum(d1); d2 = wsum(d2); d3 = wsum(d3);
  if (lane == 0) {
    out[n] = pm + mort_b[0];
    out[N_NODES + n] = ph + hours_b[0];
    float* dd = out + 2 * N_NODES + (size_t)n * 4;
    dd[0] = d0 + disc_b[0];
    dd[1] = d1 + disc_b[1];
    dd[2] = d2 + disc_b[2];
    dd[3] = d3 + disc_b[3];
  }
}

extern "C" void kernel_launch(void* const* d_in, const int* in_sizes, int n_in,
                              void* d_out, int out_size, void* d_ws, size_t ws_size,
                              hipStream_t stream) {
  const float* x       = (const float*)d_in[0];
  const int*   ei      = (const int*)d_in[1];
  const float* ew      = (const float*)d_in[2];
  const int*   mask    = (const int*)d_in[3];
  const float* gcn_W   = (const float*)d_in[4];
  const float* gcn_b   = (const float*)d_in[5];
  const float* proj_W  = (const float*)d_in[6];
  const float* proj_b  = (const float*)d_in[7];
  const float* ln1_g   = (const float*)d_in[8];
  const float* ln1_b   = (const float*)d_in[9];
  const float* gat_Wl  = (const float*)d_in[10];
  const float* gat_Wr  = (const float*)d_in[11];
  const float* gat_att = (const float*)d_in[12];
  const float* gat_b   = (const float*)d_in[13];
  const float* ln2_g   = (const float*)d_in[14];
  const float* ln2_b   = (const float*)d_in[15];
  const float* sage_Wl = (const float*)d_in[16];
  const float* sage_bl = (const float*)d_in[17];
  const float* sage_Wr = (const float*)d_in[18];
  const float* ln3_g   = (const float*)d_in[19];
  const float* ln3_b   = (const float*)d_in[20];
  // d_in[21..24]: edge-MLP params — output unused by the reference; skipped.
  const float* mort_W  = (const float*)d_in[25];
  const float* mort_b  = (const float*)d_in[26];
  const float* hours_W = (const float*)d_in[27];
  const float* hours_b = (const float*)d_in[28];
  const float* disc_W  = (const float*)d_in[29];
  const float* disc_b  = (const float*)d_in[30];

  const int* src = ei;
  const int* dst = ei + N_EDGES;
  float* out = (float*)d_out;

  // ---- workspace layout (~52M floats ≈ 209 MB) ----
  float* ws = (float*)d_ws;
  const size_t F = (size_t)N_NODES * HID;  // 6.4M floats
  float* h_init = ws;
  float* h2     = ws + 1 * F;
  float* h3     = ws + 2 * F;
  float* xp     = h3;                              // fp32, dead before h3 written
  __half* xl    = (__half*)(ws + 3 * F);           // N*256 halfs
  __half* xw16  = xl;                              // N*64 halfs, dead before xl written
  float* nmean  = ws + 3 * F;                      // fp32 N*64, xl dead by SAGE
  __half* xr    = (__half*)(ws + 3 * F + (size_t)N_NODES * 128);
  __half* h2_16 = (__half*)(ws + 3 * F + (size_t)N_NODES * 256);
  __half* h_init16 = (__half*)(ws + 3 * F + (size_t)N_NODES * 288);
  float* tail   = ws + 3 * F + (size_t)N_NODES * 320;
  int*   csr_src = (int*)tail;           tail += N_EDGES;
  float* csr_w   = tail;                 tail += N_EDGES;
  int*   row_ptr = (int*)tail;           tail += N_NODES + 64;
  int*   cursor  = (int*)tail;           tail += N_NODES;
  int*   cnt     = (int*)tail;           tail += N_NODES;
  int*   partial = (int*)tail;           tail += N_NODES;
  int*   bsum    = (int*)tail;           tail += 128;
  float* dinv    = tail;

  const int GE = (N_EDGES + 255) / 256;
  const int GN = (N_NODES + 255) / 256;
  const int GB = N_NODES / (16 * GEMM_NT);  // 1250 blocks for MFMA GEMMs

  // --- CSR build (by dst) ---
  k_zero_cnt<<<GN, 256, 0, stream>>>(cnt);
  k_hist<<<GE, 256, 0, stream>>>(dst, cnt);
  k_scan1<<<SCAN_BLK, 256, 0, stream>>>(cnt, partial, bsum);
  k_scan2<<<1, 128, 0, stream>>>(bsum);
  k_scan3<<<GN, 256, 0, stream>>>(partial, bsum, row_ptr, cursor);
  k_fill<<<GE, 256, 0, stream>>>(src, dst, ew, cursor, csr_src, csr_w);

  // --- GCN layer ---
  k_in_gemm_mfma<<<GB, 512, 0, stream>>>(x, gcn_W, proj_W, proj_b, xw16, xp);
  k_deg<<<GN, 256, 0, stream>>>(row_ptr, csr_w, dinv);
  k_gcn_fused<<<N_NODES / 4, 256, 0, stream>>>(row_ptr, csr_src, csr_w, dinv, xw16,
                                               xp, gcn_b, ln1_g, ln1_b, h_init, h_init16);

  // --- GATv2 layer ---
  k_gat_gemm_mfma<<<GB, 512, 0, stream>>>(h_init16, gat_Wl, gat_Wr, xl, xr);
  k_gat_fused<<<N_NODES / 4, 256, 0, stream>>>(row_ptr, csr_src, xl, xr, gat_att,
                                               gat_b, ln2_g, ln2_b, h_init, h2, h2_16);

  // --- SAGE layer ---
  k_sage_gather<<<N_NODES / 4, 256, 0, stream>>>(row_ptr, csr_src, h2_16, nmean);
  k_sage_gemm_ln<<<N_NODES / 8, 64, 0, stream>>>(nmean, h2, sage_Wl, sage_Wr,
                                                 sage_bl, ln3_g, ln3_b, h3);

  // --- heads ---
  k_heads<<<N_NODES / 4, 256, 0, stream>>>(h_init, h2, h3, mask, mort_W, mort_b,
                                           hours_W, hours_b, disc_W, disc_b, out);
}

// Round 10
// 575.186 us; speedup vs baseline: 1.7821x; 1.0435x over previous
//
#include <hip/hip_runtime.h>
#include <hip/hip_fp16.h>
#include <math.h>

#define N_NODES 100000
#define N_EDGES 1000000
#define F_IN    128
#define HID     64
#define HEADS   4
#define NCLS    4
#define SCAN_BLK 98   // ceil(N_NODES / 1024)
#define GEMM_NT 5     // node-tiles per block in MFMA GEMMs (80 nodes/block)

typedef _Float16 half8 __attribute__((ext_vector_type(8)));
typedef _Float16 fp16x2 __attribute__((ext_vector_type(2)));
typedef float f32x4 __attribute__((ext_vector_type(4)));

// ---------------- helpers ----------------
__device__ __forceinline__ float wsum(float v) {
#pragma unroll
  for (int o = 32; o > 0; o >>= 1) v += __shfl_xor(v, o, 64);
  return v;
}
struct Half4 { __half2 a, b; };
__device__ __forceinline__ float4 ld_half4(const __half* p) {
  Half4 h = *reinterpret_cast<const Half4*>(p);
  float2 f0 = __half22float2(h.a), f1 = __half22float2(h.b);
  return make_float4(f0.x, f0.y, f1.x, f1.y);
}
__device__ __forceinline__ __half2 absh2(__half2 v) {
  unsigned u; __builtin_memcpy(&u, &v, 4);
  u &= 0x7FFF7FFFu;
  __half2 r; __builtin_memcpy(&r, &u, 4);
  return r;
}
__device__ __forceinline__ float fdot2f(__half2 a, __half2 b, float c) {
#if defined(__has_builtin) && __has_builtin(__builtin_amdgcn_fdot2)
  fp16x2 av, bv;
  __builtin_memcpy(&av, &a, 4); __builtin_memcpy(&bv, &b, 4);
  return __builtin_amdgcn_fdot2(av, bv, c, false);
#else
  float2 af = __half22float2(a), bf = __half22float2(b);
  return c + af.x * bf.x + af.y * bf.y;
#endif
}
// score = sum att_h * leaky(xl+xr) over this lane's 4 elems; leaky(t)=0.6t+0.4|t|
__device__ __forceinline__ float edge_score(Half4 A, __half2 Ra, __half2 Rb,
                                            __half2 at0, __half2 at1,
                                            __half2 c06, __half2 c04) {
  __half2 t0 = __hadd2(A.a, Ra), t1 = __hadd2(A.b, Rb);
  __half2 l0 = __hfma2(t0, c06, __hmul2(absh2(t0), c04));
  __half2 l1 = __hfma2(t1, c06, __hmul2(absh2(t1), c04));
  return fdot2f(l1, at1, fdot2f(l0, at0, 0.f));
}
// wave-uniform node id -> SGPR (row_ptr/csr reads become scalar loads)
__device__ __forceinline__ int wave_node() {
  return __builtin_amdgcn_readfirstlane(blockIdx.x * 4 + (threadIdx.x >> 6));
}

// ---------------- CSR build (by dst) ----------------
__global__ void k_zero_cnt(int* __restrict__ cnt) {
  int i = blockIdx.x * 256 + threadIdx.x;
  if (i < N_NODES) cnt[i] = 0;
}
__global__ void k_hist(const int* __restrict__ dst, int* __restrict__ cnt) {
  int e = blockIdx.x * 256 + threadIdx.x;
  if (e < N_EDGES) atomicAdd(&cnt[dst[e]], 1);
}
__global__ __launch_bounds__(256) void k_scan1(const int* __restrict__ cnt,
                                               int* __restrict__ partial,
                                               int* __restrict__ bsum) {
  __shared__ int lds[256];
  int t = threadIdx.x;
  int base = blockIdx.x * 1024 + t * 4;
  int v0 = (base + 0 < N_NODES) ? cnt[base + 0] : 0;
  int v1 = (base + 1 < N_NODES) ? cnt[base + 1] : 0;
  int v2 = (base + 2 < N_NODES) ? cnt[base + 2] : 0;
  int v3 = (base + 3 < N_NODES) ? cnt[base + 3] : 0;
  int s = v0 + v1 + v2 + v3;
  lds[t] = s;
  __syncthreads();
  for (int o = 1; o < 256; o <<= 1) {
    int x = (t >= o) ? lds[t - o] : 0;
    __syncthreads();
    lds[t] += x;
    __syncthreads();
  }
  int excl = lds[t] - s;
  if (base + 0 < N_NODES) partial[base + 0] = excl;
  if (base + 1 < N_NODES) partial[base + 1] = excl + v0;
  if (base + 2 < N_NODES) partial[base + 2] = excl + v0 + v1;
  if (base + 3 < N_NODES) partial[base + 3] = excl + v0 + v1 + v2;
  if (t == 255) bsum[blockIdx.x] = lds[255];
}
__global__ void k_scan2(int* __restrict__ bsum) {  // 1 block, 128 threads
  __shared__ int lds[128];
  int t = threadIdx.x;
  int v = (t < SCAN_BLK) ? bsum[t] : 0;
  lds[t] = v;
  __syncthreads();
  for (int o = 1; o < 128; o <<= 1) {
    int x = (t >= o) ? lds[t - o] : 0;
    __syncthreads();
    lds[t] += x;
    __syncthreads();
  }
  if (t < SCAN_BLK) bsum[t] = lds[t] - v;  // exclusive
}
__global__ void k_scan3(const int* __restrict__ partial, const int* __restrict__ bsum,
                        int* __restrict__ row_ptr, int* __restrict__ cursor) {
  int i = blockIdx.x * 256 + threadIdx.x;
  if (i < N_NODES) {
    int v = partial[i] + bsum[i >> 10];
    row_ptr[i] = v;
    cursor[i] = v;
  }
  if (i == 0) row_ptr[N_NODES] = N_EDGES;
}
__global__ void k_fill(const int* __restrict__ src, const int* __restrict__ dst,
                       const float* __restrict__ ew, int* __restrict__ cursor,
                       int* __restrict__ csr_src, float* __restrict__ csr_w) {
  int e = blockIdx.x * 256 + threadIdx.x;
  if (e >= N_EDGES) return;
  int d = dst[e];
  int p = atomicAdd(&cursor[d], 1);
  csr_src[p] = src[e];
  csr_w[p] = ew[e];
}

// ---------------- MFMA GEMM 1: [xw16|xp] = x @ [gcn_W|proj_W]  (K=128, N=128) ----
__global__ __launch_bounds__(512) void k_in_gemm_mfma(
    const float* __restrict__ x, const float* __restrict__ gcn_W,
    const float* __restrict__ proj_W, const float* __restrict__ proj_b,
    __half* __restrict__ xw16, float* __restrict__ xp) {
  __shared__ __half at[16 * 136];
  int t = threadIdx.x;
  int w = t >> 6, lane = t & 63;
  int m = lane & 15, q = lane >> 4;
  int ncol = w * 16 + m;                 // 0..127
  const float* W = (ncol < 64) ? gcn_W : proj_W;
  int nc = (ncol < 64) ? ncol : ncol - 64;
  half8 bf[4];
#pragma unroll
  for (int ch = 0; ch < 4; ++ch) {
    int kb = ch * 32 + q * 8;
#pragma unroll
    for (int j = 0; j < 8; ++j)
      bf[ch][j] = (_Float16)W[(kb + j) * 64 + nc];
  }
  float pb = (ncol >= 64) ? proj_b[nc] : 0.f;
  int nb0 = blockIdx.x * (16 * GEMM_NT);
  for (int nt = 0; nt < GEMM_NT; ++nt) {
    int nb = nb0 + nt * 16;
    {
      int row = t >> 5, col = (t & 31) * 4;
      float4 v = *reinterpret_cast<const float4*>(x + (size_t)(nb + row) * F_IN + col);
      __half2* d = reinterpret_cast<__half2*>(&at[row * 136 + col]);
      d[0] = __floats2half2_rn(v.x, v.y);
      d[1] = __floats2half2_rn(v.z, v.w);
    }
    __syncthreads();
    f32x4 acc = {0.f, 0.f, 0.f, 0.f};
#pragma unroll
    for (int ch = 0; ch < 4; ++ch) {
      half8 af = *reinterpret_cast<const half8*>(&at[m * 136 + ch * 32 + q * 8]);
      acc = __builtin_amdgcn_mfma_f32_16x16x32_f16(af, bf[ch], acc, 0, 0, 0);
    }
    if (ncol < 64) {
#pragma unroll
      for (int r = 0; r < 4; ++r)
        xw16[(size_t)(nb + q * 4 + r) * HID + nc] = __float2half(acc[r]);
    } else {
#pragma unroll
      for (int r = 0; r < 4; ++r)
        xp[(size_t)(nb + q * 4 + r) * HID + nc] = acc[r] + pb;
    }
    __syncthreads();
  }
}

// ---------------- GCN: deg/dinv from CSR (no atomics) ----------------
__global__ void k_deg(const int* __restrict__ row_ptr, const float* __restrict__ csr_w,
                      float* __restrict__ dinv) {
  int n = blockIdx.x * 256 + threadIdx.x;
  if (n >= N_NODES) return;
  float deg = 1.0f;  // self-loop weight
  int end = row_ptr[n + 1];
  for (int i = row_ptr[n]; i < end; ++i) deg += csr_w[i];
  dinv[n] = rsqrtf(deg);  // deg >= 1 always
}

// pull-gather + LN + relu + residual, one wave per node (n in SGPR), 4x ILP
// emits only fp16 h_init (all consumers read fp16).
__global__ __launch_bounds__(256) void k_gcn_fused(
    const int* __restrict__ row_ptr, const int* __restrict__ csr_src,
    const float* __restrict__ csr_w, const float* __restrict__ dinv,
    const __half* __restrict__ xw16, const float* __restrict__ xp,
    const float* __restrict__ gcn_b, const float* __restrict__ g,
    const float* __restrict__ bb, __half* __restrict__ h_init16) {
  int n = wave_node();
  int lane = threadIdx.x & 63;
  float di = dinv[n];
  float acc = di * di * __half2float(xw16[(size_t)n * HID + lane]);  // self loop
  int beg = row_ptr[n], end = row_ptr[n + 1];
  int i = beg;
  for (; i + 4 <= end; i += 4) {
    int s0 = __builtin_amdgcn_readfirstlane(csr_src[i]);
    int s1 = __builtin_amdgcn_readfirstlane(csr_src[i + 1]);
    int s2 = __builtin_amdgcn_readfirstlane(csr_src[i + 2]);
    int s3 = __builtin_amdgcn_readfirstlane(csr_src[i + 3]);
    float nrm0 = dinv[s0] * csr_w[i] * di;
    float nrm1 = dinv[s1] * csr_w[i + 1] * di;
    float nrm2 = dinv[s2] * csr_w[i + 2] * di;
    float nrm3 = dinv[s3] * csr_w[i + 3] * di;
    float v0 = __half2float(xw16[(size_t)s0 * HID + lane]);
    float v1 = __half2float(xw16[(size_t)s1 * HID + lane]);
    float v2 = __half2float(xw16[(size_t)s2 * HID + lane]);
    float v3 = __half2float(xw16[(size_t)s3 * HID + lane]);
    acc += nrm0 * v0 + nrm1 * v1 + nrm2 * v2 + nrm3 * v3;
  }
  for (; i < end; ++i) {
    int s = __builtin_amdgcn_readfirstlane(csr_src[i]);
    float nrm = dinv[s] * csr_w[i] * di;
    acc += nrm * __half2float(xw16[(size_t)s * HID + lane]);
  }
  float v = acc + gcn_b[lane];
  float mu = wsum(v) * (1.f / HID);
  float dv = v - mu;
  float var = wsum(dv * dv) * (1.f / HID);
  float h = dv * rsqrtf(var + 1e-5f) * g[lane] + bb[lane];
  h = h > 0.f ? h : 0.f;
  h_init16[(size_t)n * HID + lane] = __float2half(h + xp[(size_t)n * HID + lane]);
}

// ---------------- MFMA GEMM 2: [xl|xr] = h16 @ [Wl|Wr]  (K=64, N=512) ----------
__global__ __launch_bounds__(512) void k_gat_gemm_mfma(
    const __half* __restrict__ h16, const float* __restrict__ Wl,
    const float* __restrict__ Wr, __half* __restrict__ xl, __half* __restrict__ xr) {
  __shared__ __half at[16 * 72];
  int t = threadIdx.x;
  int w = t >> 6, lane = t & 63;
  int m = lane & 15, q = lane >> 4;
  half8 bf[4][2];
#pragma unroll
  for (int tt = 0; tt < 4; ++tt) {
    int c = w * 16 + tt * 128 + m;          // 0..511
    const float* W = (c < 256) ? Wl : Wr;
    int nc = (c < 256) ? c : c - 256;
#pragma unroll
    for (int ch = 0; ch < 2; ++ch) {
      int kb = ch * 32 + q * 8;
#pragma unroll
      for (int j = 0; j < 8; ++j)
        bf[tt][ch][j] = (_Float16)W[(kb + j) * 256 + nc];
    }
  }
  int nb0 = blockIdx.x * (16 * GEMM_NT);
  for (int nt = 0; nt < GEMM_NT; ++nt) {
    int nb = nb0 + nt * 16;
    {
      int row = t >> 5, col = (t & 31) * 2;
      *reinterpret_cast<__half2*>(&at[row * 72 + col]) =
          *reinterpret_cast<const __half2*>(h16 + (size_t)(nb + row) * HID + col);
    }
    __syncthreads();
    half8 a0 = *reinterpret_cast<const half8*>(&at[m * 72 + q * 8]);
    half8 a1 = *reinterpret_cast<const half8*>(&at[m * 72 + 32 + q * 8]);
#pragma unroll
    for (int tt = 0; tt < 4; ++tt) {
      f32x4 acc = {0.f, 0.f, 0.f, 0.f};
      acc = __builtin_amdgcn_mfma_f32_16x16x32_f16(a0, bf[tt][0], acc, 0, 0, 0);
      acc = __builtin_amdgcn_mfma_f32_16x16x32_f16(a1, bf[tt][1], acc, 0, 0, 0);
      int c = w * 16 + tt * 128 + m;
      __half* out = (c < 256) ? (xl + c) : (xr + (c - 256));
#pragma unroll
      for (int r = 0; r < 4; ++r)
        out[(size_t)(nb + q * 4 + r) * 256] = __float2half(acc[r]);
    }
    __syncthreads();
  }
}

// ---------------- GATv2 fused: pk-fp16 score + softmax + aggregate + mean + LN --
__global__ __launch_bounds__(256) void k_gat_fused(
    const int* __restrict__ row_ptr, const int* __restrict__ csr_src,
    const __half* __restrict__ xl, const __half* __restrict__ xr,
    const float* __restrict__ att, const float* __restrict__ gat_b,
    const float* __restrict__ g, const float* __restrict__ bb,
    const __half* __restrict__ h_init16, __half* __restrict__ h2_16) {
  int n = wave_node();
  int lane = threadIdx.x & 63;
  const __half2 c06 = __float2half2_rn(0.6f);
  const __half2 c04 = __float2half2_rn(0.4f);
  float4 atv = *reinterpret_cast<const float4*>(att + lane * 4);
  __half2 at0 = __floats2half2_rn(atv.x, atv.y);
  __half2 at1 = __floats2half2_rn(atv.z, atv.w);
  Half4 R = *reinterpret_cast<const Half4*>(xr + (size_t)n * 256 + lane * 4);
  Half4 S = *reinterpret_cast<const Half4*>(xl + (size_t)n * 256 + lane * 4);

  float q = edge_score(S, R.a, R.b, at0, at1, c06, c04);
  q += __shfl_xor(q, 1); q += __shfl_xor(q, 2);
  q += __shfl_xor(q, 4); q += __shfl_xor(q, 8);
  float w = __expf(q);
  float den = w;
  float2 f0 = __half22float2(S.a), f1 = __half22float2(S.b);
  float4 acc = make_float4(w * f0.x, w * f0.y, w * f1.x, w * f1.y);

  int beg = row_ptr[n], end = row_ptr[n + 1];
  int i = beg;
  for (; i + 2 <= end; i += 2) {
    int s0 = __builtin_amdgcn_readfirstlane(csr_src[i]);
    int s1 = __builtin_amdgcn_readfirstlane(csr_src[i + 1]);
    Half4 A0 = *reinterpret_cast<const Half4*>(xl + (size_t)s0 * 256 + lane * 4);
    Half4 A1 = *reinterpret_cast<const Half4*>(xl + (size_t)s1 * 256 + lane * 4);
    float q0 = edge_score(A0, R.a, R.b, at0, at1, c06, c04);
    float q1 = edge_score(A1, R.a, R.b, at0, at1, c06, c04);
    q0 += __shfl_xor(q0, 1); q1 += __shfl_xor(q1, 1);
    q0 += __shfl_xor(q0, 2); q1 += __shfl_xor(q1, 2);
    q0 += __shfl_xor(q0, 4); q1 += __shfl_xor(q1, 4);
    q0 += __shfl_xor(q0, 8); q1 += __shfl_xor(q1, 8);
    float w0 = __expf(q0), w1 = __expf(q1);
    den += w0 + w1;
    float2 a00 = __half22float2(A0.a), a01 = __half22float2(A0.b);
    float2 a10 = __half22float2(A1.a), a11 = __half22float2(A1.b);
    acc.x += w0 * a00.x + w1 * a10.x;
    acc.y += w0 * a00.y + w1 * a10.y;
    acc.z += w0 * a01.x + w1 * a11.x;
    acc.w += w0 * a01.y + w1 * a11.y;
  }
  if (i < end) {
    int s0 = __builtin_amdgcn_readfirstlane(csr_src[i]);
    Half4 A0 = *reinterpret_cast<const Half4*>(xl + (size_t)s0 * 256 + lane * 4);
    q = edge_score(A0, R.a, R.b, at0, at1, c06, c04);
    q += __shfl_xor(q, 1); q += __shfl_xor(q, 2);
    q += __shfl_xor(q, 4); q += __shfl_xor(q, 8);
    w = __expf(q);
    den += w;
    float2 a00 = __half22float2(A0.a), a01 = __half22float2(A0.b);
    acc.x += w * a00.x; acc.y += w * a00.y;
    acc.z += w * a01.x; acc.w += w * a01.y;
  }
  float inv = 1.f / den;
  acc.x *= inv; acc.y *= inv; acc.z *= inv; acc.w *= inv;
  // mean over heads: lanes l, l^16, l^32, l^48 hold same feature of different heads
  acc.x += __shfl_xor(acc.x, 16); acc.y += __shfl_xor(acc.y, 16);
  acc.z += __shfl_xor(acc.z, 16); acc.w += __shfl_xor(acc.w, 16);
  acc.x += __shfl_xor(acc.x, 32); acc.y += __shfl_xor(acc.y, 32);
  acc.z += __shfl_xor(acc.z, 32); acc.w += __shfl_xor(acc.w, 32);
  // redistribute: feature `lane` = component (lane&3) of lane (lane>>2)
  int srcl = lane >> 2;
  float t0 = __shfl(acc.x, srcl), t1 = __shfl(acc.y, srcl);
  float t2 = __shfl(acc.z, srcl), t3 = __shfl(acc.w, srcl);
  int r = lane & 3;
  float mean = (r == 0) ? t0 : (r == 1) ? t1 : (r == 2) ? t2 : t3;
  float val = mean * 0.25f + gat_b[lane];
  float mu = wsum(val) * (1.f / HID);
  float dv = val - mu;
  float var = wsum(dv * dv) * (1.f / HID);
  float h = dv * rsqrtf(var + 1e-5f) * g[lane] + bb[lane];
  h = h > 0.f ? h : 0.f;
  float outv = h + __half2float(h_init16[(size_t)n * HID + lane]);
  h2_16[(size_t)n * HID + lane] = __float2half(outv);
}

// ---------------- SAGE stage 1: pull mean-gather (fp32 out, n in SGPR, 4x ILP) --
__global__ __launch_bounds__(256) void k_sage_gather(
    const int* __restrict__ row_ptr, const int* __restrict__ csr_src,
    const __half* __restrict__ h2_16, float* __restrict__ nmean) {
  int n = wave_node();
  int lane = threadIdx.x & 63;
  int beg = row_ptr[n], end = row_ptr[n + 1];
  float sum = 0.f;
  int i = beg;
  for (; i + 4 <= end; i += 4) {
    int s0 = __builtin_amdgcn_readfirstlane(csr_src[i]);
    int s1 = __builtin_amdgcn_readfirstlane(csr_src[i + 1]);
    int s2 = __builtin_amdgcn_readfirstlane(csr_src[i + 2]);
    int s3 = __builtin_amdgcn_readfirstlane(csr_src[i + 3]);
    float v0 = __half2float(h2_16[(size_t)s0 * HID + lane]);
    float v1 = __half2float(h2_16[(size_t)s1 * HID + lane]);
    float v2 = __half2float(h2_16[(size_t)s2 * HID + lane]);
    float v3 = __half2float(h2_16[(size_t)s3 * HID + lane]);
    sum += v0 + v1 + v2 + v3;
  }
  for (; i < end; ++i) {
    int s = __builtin_amdgcn_readfirstlane(csr_src[i]);
    sum += __half2float(h2_16[(size_t)s * HID + lane]);
  }
  nmean[(size_t)n * HID + lane] = sum / fmaxf((float)(end - beg), 1.f);
}

// ---------------- SAGE stage 2: dense nmean@Wl + h2@Wr + LN (LDS-staged acts) ---
__global__ __launch_bounds__(64) void k_sage_gemm_ln(
    const float* __restrict__ nmean, const __half* __restrict__ h2_16,
    const float* __restrict__ Wl, const float* __restrict__ Wr,
    const float* __restrict__ sage_bl, const float* __restrict__ g,
    const float* __restrict__ bb, float* __restrict__ h3) {
  __shared__ float nt[8][HID];
  __shared__ float ht[8][HID];
  int t = threadIdx.x;
  int n0 = blockIdx.x * 8;
  {
    const float4* ng = reinterpret_cast<const float4*>(nmean + (size_t)n0 * HID);
    float4* ns = reinterpret_cast<float4*>(&nt[0][0]);
    ns[t] = ng[t];
    ns[t + 64] = ng[t + 64];
    const __half* hp = h2_16 + (size_t)n0 * HID + t * 8;
    Half4 p0 = *reinterpret_cast<const Half4*>(hp);
    Half4 p1 = *reinterpret_cast<const Half4*>(hp + 4);
    float* dsth = &ht[0][0] + t * 8;
    float2 f;
    f = __half22float2(p0.a); dsth[0] = f.x; dsth[1] = f.y;
    f = __half22float2(p0.b); dsth[2] = f.x; dsth[3] = f.y;
    f = __half22float2(p1.a); dsth[4] = f.x; dsth[5] = f.y;
    f = __half22float2(p1.b); dsth[6] = f.x; dsth[7] = f.y;
  }
  __syncthreads();
  int f = t;
  float acc[8] = {0.f,0.f,0.f,0.f,0.f,0.f,0.f,0.f};
  for (int k = 0; k < HID; k += 4) {
    float wl0 = Wl[(k + 0) * HID + f], wr0 = Wr[(k + 0) * HID + f];
    float wl1 = Wl[(k + 1) * HID + f], wr1 = Wr[(k + 1) * HID + f];
    float wl2 = Wl[(k + 2) * HID + f], wr2 = Wr[(k + 2) * HID + f];
    float wl3 = Wl[(k + 3) * HID + f], wr3 = Wr[(k + 3) * HID + f];
#pragma unroll
    for (int j = 0; j < 8; ++j) {
      float4 nv = *reinterpret_cast<const float4*>(&nt[j][k]);
      float4 hv = *reinterpret_cast<const float4*>(&ht[j][k]);
      acc[j] += nv.x * wl0 + nv.y * wl1 + nv.z * wl2 + nv.w * wl3
              + hv.x * wr0 + hv.y * wr1 + hv.z * wr2 + hv.w * wr3;
    }
  }
  float blv = sage_bl[f], gv = g[f], bbv = bb[f];
#pragma unroll
  for (int j = 0; j < 8; ++j) {
    float v = acc[j] + blv;
    float mu = wsum(v) * (1.f / HID);
    float dv = v - mu;
    float var = wsum(dv * dv) * (1.f / HID);
    float h = dv * rsqrtf(var + 1e-5f) * gv + bbv;
    h = h > 0.f ? h : 0.f;
    h3[(size_t)(n0 + j) * HID + f] = h + ht[j][f];
  }
}

// ---------------- heads ----------------
__global__ __launch_bounds__(256) void k_heads(
    const __half* __restrict__ h_init16, const __half* __restrict__ h2_16,
    const float* __restrict__ h3, const int* __restrict__ mask,
    const float* __restrict__ mort_W, const float* __restrict__ mort_b,
    const float* __restrict__ hours_W, const float* __restrict__ hours_b,
    const float* __restrict__ disc_W, const float* __restrict__ disc_b,
    float* __restrict__ out) {
  int n = wave_node();
  int lane = threadIdx.x & 63;
  float m = (mask[n] != 0) ? 1.f : 0.f;
  size_t base = (size_t)n * HID;
  float v0 = __half2float(h_init16[base + lane]) * m;
  float v1 = __half2float(h2_16[base + lane]) * m;
  float v2 = h3[base + lane] * m;
  float pm = v0 * mort_W[lane] + v1 * mort_W[64 + lane] + v2 * mort_W[128 + lane];
  float ph = v0 * hours_W[lane] + v1 * hours_W[64 + lane] + v2 * hours_W[128 + lane];
  float d0 = v0 * disc_W[lane * 4 + 0] + v1 * disc_W[(64 + lane) * 4 + 0] + v2 * disc_W[(128 + lane) * 4 + 0];
  float d1 = v0 * disc_W[lane * 4 + 1] + v1 * disc_W[(64 + lane) * 4 + 1] + v2 * disc_W[(128 + lane) * 4 + 1];
  float d2 = v0 * disc_W[lane * 4 + 2] + v1 * disc_W[(64 + lane) * 4 + 2] + v2 * disc_W[(128 + lane) * 4 + 2];
  float d3 = v0 * disc_W[lane * 4 + 3] + v1 * disc_W[(64 + lane) * 4 + 3] + v2 * disc_W[(128 + lane) * 4 + 3];
  pm = wsum(pm); ph = wsum(ph);
  d0 = wsum(d0); d1 = wsum(d1); d2 = wsum(d2); d3 = wsum(d3);
  if (lane == 0) {
    out[n] = pm + mort_b[0];
    out[N_NODES + n] = ph + hours_b[0];
    float* dd = out + 2 * N_NODES + (size_t)n * 4;
    dd[0] = d0 + disc_b[0];
    dd[1] = d1 + disc_b[1];
    dd[2] = d2 + disc_b[2];
    dd[3] = d3 + disc_b[3];
  }
}

extern "C" void kernel_launch(void* const* d_in, const int* in_sizes, int n_in,
                              void* d_out, int out_size, void* d_ws, size_t ws_size,
                              hipStream_t stream) {
  const float* x       = (const float*)d_in[0];
  const int*   ei      = (const int*)d_in[1];
  const float* ew      = (const float*)d_in[2];
  const int*   mask    = (const int*)d_in[3];
  const float* gcn_W   = (const float*)d_in[4];
  const float* gcn_b   = (const float*)d_in[5];
  const float* proj_W  = (const float*)d_in[6];
  const float* proj_b  = (const float*)d_in[7];
  const float* ln1_g   = (const float*)d_in[8];
  const float* ln1_b   = (const float*)d_in[9];
  const float* gat_Wl  = (const float*)d_in[10];
  const float* gat_Wr  = (const float*)d_in[11];
  const float* gat_att = (const float*)d_in[12];
  const float* gat_b   = (const float*)d_in[13];
  const float* ln2_g   = (const float*)d_in[14];
  const float* ln2_b   = (const float*)d_in[15];
  const float* sage_Wl = (const float*)d_in[16];
  const float* sage_bl = (const float*)d_in[17];
  const float* sage_Wr = (const float*)d_in[18];
  const float* ln3_g   = (const float*)d_in[19];
  const float* ln3_b   = (const float*)d_in[20];
  // d_in[21..24]: edge-MLP params — output unused by the reference; skipped.
  const float* mort_W  = (const float*)d_in[25];
  const float* mort_b  = (const float*)d_in[26];
  const float* hours_W = (const float*)d_in[27];
  const float* hours_b = (const float*)d_in[28];
  const float* disc_W  = (const float*)d_in[29];
  const float* disc_b  = (const float*)d_in[30];

  const int* src = ei;
  const int* dst = ei + N_EDGES;
  float* out = (float*)d_out;

  // ---- workspace layout (~52M floats ≈ 209 MB; h_init/h2 fp32 slots now spare) --
  float* ws = (float*)d_ws;
  const size_t F = (size_t)N_NODES * HID;  // 6.4M floats
  float* h3     = ws + 2 * F;
  float* xp     = h3;                              // fp32, dead before h3 written
  __half* xl    = (__half*)(ws + 3 * F);           // N*256 halfs
  __half* xw16  = xl;                              // N*64 halfs, dead before xl written
  float* nmean  = ws + 3 * F;                      // fp32 N*64, xl dead by SAGE
  __half* xr    = (__half*)(ws + 3 * F + (size_t)N_NODES * 128);
  __half* h2_16 = (__half*)(ws + 3 * F + (size_t)N_NODES * 256);
  __half* h_init16 = (__half*)(ws + 3 * F + (size_t)N_NODES * 288);
  float* tail   = ws + 3 * F + (size_t)N_NODES * 320;
  int*   csr_src = (int*)tail;           tail += N_EDGES;
  float* csr_w   = tail;                 tail += N_EDGES;
  int*   row_ptr = (int*)tail;           tail += N_NODES + 64;
  int*   cursor  = (int*)tail;           tail += N_NODES;
  int*   cnt     = (int*)tail;           tail += N_NODES;
  int*   partial = (int*)tail;           tail += N_NODES;
  int*   bsum    = (int*)tail;           tail += 128;
  float* dinv    = tail;

  const int GE = (N_EDGES + 255) / 256;
  const int GN = (N_NODES + 255) / 256;
  const int GB = N_NODES / (16 * GEMM_NT);  // 1250 blocks for MFMA GEMMs

  // --- CSR build (by dst) ---
  k_zero_cnt<<<GN, 256, 0, stream>>>(cnt);
  k_hist<<<GE, 256, 0, stream>>>(dst, cnt);
  k_scan1<<<SCAN_BLK, 256, 0, stream>>>(cnt, partial, bsum);
  k_scan2<<<1, 128, 0, stream>>>(bsum);
  k_scan3<<<GN, 256, 0, stream>>>(partial, bsum, row_ptr, cursor);
  k_fill<<<GE, 256, 0, stream>>>(src, dst, ew, cursor, csr_src, csr_w);

  // --- GCN layer ---
  k_in_gemm_mfma<<<GB, 512, 0, stream>>>(x, gcn_W, proj_W, proj_b, xw16, xp);
  k_deg<<<GN, 256, 0, stream>>>(row_ptr, csr_w, dinv);
  k_gcn_fused<<<N_NODES / 4, 256, 0, stream>>>(row_ptr, csr_src, csr_w, dinv, xw16,
                                               xp, gcn_b, ln1_g, ln1_b, h_init16);

  // --- GATv2 layer ---
  k_gat_gemm_mfma<<<GB, 512, 0, stream>>>(h_init16, gat_Wl, gat_Wr, xl, xr);
  k_gat_fused<<<N_NODES / 4, 256, 0, stream>>>(row_ptr, csr_src, xl, xr, gat_att,
                                               gat_b, ln2_g, ln2_b, h_init16, h2_16);

  // --- SAGE layer ---
  k_sage_gather<<<N_NODES / 4, 256, 0, stream>>>(row_ptr, csr_src, h2_16, nmean);
  k_sage_gemm_ln<<<N_NODES / 8, 64, 0, stream>>>(nmean, h2_16, sage_Wl, sage_Wr,
                                                 sage_bl, ln3_g, ln3_b, h3);

  // --- heads ---
  k_heads<<<N_NODES / 4, 256, 0, stream>>>(h_init16, h2_16, h3, mask, mort_W, mort_b,
                                           hours_W, hours_b, disc_W, disc_b, out);
}

// Round 11
// 571.689 us; speedup vs baseline: 1.7930x; 1.0061x over previous
//
#include <hip/hip_runtime.h>
#include <hip/hip_fp16.h>
#include <math.h>

#define N_NODES 100000
#define N_EDGES 1000000
#define F_IN    128
#define HID     64
#define HEADS   4
#define NCLS    4
#define SCAN_BLK 98   // ceil(N_NODES / 1024)
#define GEMM_NT 5     // node-tiles per block in MFMA GEMMs (80 nodes/block)

typedef _Float16 half8 __attribute__((ext_vector_type(8)));
typedef _Float16 fp16x2 __attribute__((ext_vector_type(2)));
typedef float f32x4 __attribute__((ext_vector_type(4)));

// ---------------- helpers ----------------
__device__ __forceinline__ float wsum(float v) {
#pragma unroll
  for (int o = 32; o > 0; o >>= 1) v += __shfl_xor(v, o, 64);
  return v;
}
struct Half4 { __half2 a, b; };
__device__ __forceinline__ __half2 absh2(__half2 v) {
  unsigned u; __builtin_memcpy(&u, &v, 4);
  u &= 0x7FFF7FFFu;
  __half2 r; __builtin_memcpy(&r, &u, 4);
  return r;
}
__device__ __forceinline__ float fdot2f(__half2 a, __half2 b, float c) {
#if defined(__has_builtin) && __has_builtin(__builtin_amdgcn_fdot2)
  fp16x2 av, bv;
  __builtin_memcpy(&av, &a, 4); __builtin_memcpy(&bv, &b, 4);
  return __builtin_amdgcn_fdot2(av, bv, c, false);
#else
  float2 af = __half22float2(a), bf = __half22float2(b);
  return c + af.x * bf.x + af.y * bf.y;
#endif
}
// score = sum att_h * leaky(xl+xr) over this lane's 4 elems; leaky(t)=0.6t+0.4|t|
__device__ __forceinline__ float edge_score(Half4 A, __half2 Ra, __half2 Rb,
                                            __half2 at0, __half2 at1,
                                            __half2 c06, __half2 c04) {
  __half2 t0 = __hadd2(A.a, Ra), t1 = __hadd2(A.b, Rb);
  __half2 l0 = __hfma2(t0, c06, __hmul2(absh2(t0), c04));
  __half2 l1 = __hfma2(t1, c06, __hmul2(absh2(t1), c04));
  return fdot2f(l1, at1, fdot2f(l0, at0, 0.f));
}
__device__ __forceinline__ float reduce16(float q) {
  q += __shfl_xor(q, 1); q += __shfl_xor(q, 2);
  q += __shfl_xor(q, 4); q += __shfl_xor(q, 8);
  return q;
}
// wave-uniform node id -> SGPR (row_ptr/csr reads become scalar loads)
__device__ __forceinline__ int wave_node() {
  return __builtin_amdgcn_readfirstlane(blockIdx.x * 4 + (threadIdx.x >> 6));
}

// ---------------- CSR build (by dst) ----------------
__global__ void k_hist(const int* __restrict__ dst, int* __restrict__ cnt) {
  int e = blockIdx.x * 256 + threadIdx.x;
  if (e < N_EDGES) atomicAdd(&cnt[dst[e]], 1);
}
__global__ __launch_bounds__(256) void k_scan1(const int* __restrict__ cnt,
                                               int* __restrict__ partial,
                                               int* __restrict__ bsum) {
  __shared__ int lds[256];
  int t = threadIdx.x;
  int base = blockIdx.x * 1024 + t * 4;
  int v0 = (base + 0 < N_NODES) ? cnt[base + 0] : 0;
  int v1 = (base + 1 < N_NODES) ? cnt[base + 1] : 0;
  int v2 = (base + 2 < N_NODES) ? cnt[base + 2] : 0;
  int v3 = (base + 3 < N_NODES) ? cnt[base + 3] : 0;
  int s = v0 + v1 + v2 + v3;
  lds[t] = s;
  __syncthreads();
  for (int o = 1; o < 256; o <<= 1) {
    int x = (t >= o) ? lds[t - o] : 0;
    __syncthreads();
    lds[t] += x;
    __syncthreads();
  }
  int excl = lds[t] - s;
  if (base + 0 < N_NODES) partial[base + 0] = excl;
  if (base + 1 < N_NODES) partial[base + 1] = excl + v0;
  if (base + 2 < N_NODES) partial[base + 2] = excl + v0 + v1;
  if (base + 3 < N_NODES) partial[base + 3] = excl + v0 + v1 + v2;
  if (t == 255) bsum[blockIdx.x] = lds[255];
}
__global__ void k_scan2(int* __restrict__ bsum) {  // 1 block, 128 threads
  __shared__ int lds[128];
  int t = threadIdx.x;
  int v = (t < SCAN_BLK) ? bsum[t] : 0;
  lds[t] = v;
  __syncthreads();
  for (int o = 1; o < 128; o <<= 1) {
    int x = (t >= o) ? lds[t - o] : 0;
    __syncthreads();
    lds[t] += x;
    __syncthreads();
  }
  if (t < SCAN_BLK) bsum[t] = lds[t] - v;  // exclusive
}
__global__ void k_scan3(const int* __restrict__ partial, const int* __restrict__ bsum,
                        int* __restrict__ row_ptr, int* __restrict__ cursor) {
  int i = blockIdx.x * 256 + threadIdx.x;
  if (i < N_NODES) {
    int v = partial[i] + bsum[i >> 10];
    row_ptr[i] = v;
    cursor[i] = v;
  }
  if (i == 0) row_ptr[N_NODES] = N_EDGES;
}
__global__ void k_fill(const int* __restrict__ src, const int* __restrict__ dst,
                       const float* __restrict__ ew, int* __restrict__ cursor,
                       int* __restrict__ csr_src, float* __restrict__ csr_w) {
  int e = blockIdx.x * 256 + threadIdx.x;
  if (e >= N_EDGES) return;
  int d = dst[e];
  int p = atomicAdd(&cursor[d], 1);
  csr_src[p] = src[e];
  csr_w[p] = ew[e];
}

// ---------------- MFMA GEMM 1: [xw16|xp] = x @ [gcn_W|proj_W]  (K=128, N=128) ----
__global__ __launch_bounds__(512) void k_in_gemm_mfma(
    const float* __restrict__ x, const float* __restrict__ gcn_W,
    const float* __restrict__ proj_W, const float* __restrict__ proj_b,
    __half* __restrict__ xw16, float* __restrict__ xp) {
  __shared__ __half at[16 * 136];
  int t = threadIdx.x;
  int w = t >> 6, lane = t & 63;
  int m = lane & 15, q = lane >> 4;
  int ncol = w * 16 + m;                 // 0..127
  const float* W = (ncol < 64) ? gcn_W : proj_W;
  int nc = (ncol < 64) ? ncol : ncol - 64;
  half8 bf[4];
#pragma unroll
  for (int ch = 0; ch < 4; ++ch) {
    int kb = ch * 32 + q * 8;
#pragma unroll
    for (int j = 0; j < 8; ++j)
      bf[ch][j] = (_Float16)W[(kb + j) * 64 + nc];
  }
  float pb = (ncol >= 64) ? proj_b[nc] : 0.f;
  int nb0 = blockIdx.x * (16 * GEMM_NT);
  for (int nt = 0; nt < GEMM_NT; ++nt) {
    int nb = nb0 + nt * 16;
    {
      int row = t >> 5, col = (t & 31) * 4;
      float4 v = *reinterpret_cast<const float4*>(x + (size_t)(nb + row) * F_IN + col);
      __half2* d = reinterpret_cast<__half2*>(&at[row * 136 + col]);
      d[0] = __floats2half2_rn(v.x, v.y);
      d[1] = __floats2half2_rn(v.z, v.w);
    }
    __syncthreads();
    f32x4 acc = {0.f, 0.f, 0.f, 0.f};
#pragma unroll
    for (int ch = 0; ch < 4; ++ch) {
      half8 af = *reinterpret_cast<const half8*>(&at[m * 136 + ch * 32 + q * 8]);
      acc = __builtin_amdgcn_mfma_f32_16x16x32_f16(af, bf[ch], acc, 0, 0, 0);
    }
    if (ncol < 64) {
#pragma unroll
      for (int r = 0; r < 4; ++r)
        xw16[(size_t)(nb + q * 4 + r) * HID + nc] = __float2half(acc[r]);
    } else {
#pragma unroll
      for (int r = 0; r < 4; ++r)
        xp[(size_t)(nb + q * 4 + r) * HID + nc] = acc[r] + pb;
    }
    __syncthreads();
  }
}

// ---------------- GCN: deg/dinv from CSR (no atomics) ----------------
__global__ void k_deg(const int* __restrict__ row_ptr, const float* __restrict__ csr_w,
                      float* __restrict__ dinv) {
  int n = blockIdx.x * 256 + threadIdx.x;
  if (n >= N_NODES) return;
  float deg = 1.0f;  // self-loop weight
  int end = row_ptr[n + 1];
  for (int i = row_ptr[n]; i < end; ++i) deg += csr_w[i];
  dinv[n] = rsqrtf(deg);  // deg >= 1 always
}

// pull-gather + LN + relu + residual, one wave per node (n in SGPR), 4x ILP
__global__ __launch_bounds__(256) void k_gcn_fused(
    const int* __restrict__ row_ptr, const int* __restrict__ csr_src,
    const float* __restrict__ csr_w, const float* __restrict__ dinv,
    const __half* __restrict__ xw16, const float* __restrict__ xp,
    const float* __restrict__ gcn_b, const float* __restrict__ g,
    const float* __restrict__ bb, __half* __restrict__ h_init16) {
  int n = wave_node();
  int lane = threadIdx.x & 63;
  float di = dinv[n];
  float acc = di * di * __half2float(xw16[(size_t)n * HID + lane]);  // self loop
  int beg = row_ptr[n], end = row_ptr[n + 1];
  int i = beg;
  for (; i + 4 <= end; i += 4) {
    int s0 = __builtin_amdgcn_readfirstlane(csr_src[i]);
    int s1 = __builtin_amdgcn_readfirstlane(csr_src[i + 1]);
    int s2 = __builtin_amdgcn_readfirstlane(csr_src[i + 2]);
    int s3 = __builtin_amdgcn_readfirstlane(csr_src[i + 3]);
    float nrm0 = dinv[s0] * csr_w[i] * di;
    float nrm1 = dinv[s1] * csr_w[i + 1] * di;
    float nrm2 = dinv[s2] * csr_w[i + 2] * di;
    float nrm3 = dinv[s3] * csr_w[i + 3] * di;
    float v0 = __half2float(xw16[(size_t)s0 * HID + lane]);
    float v1 = __half2float(xw16[(size_t)s1 * HID + lane]);
    float v2 = __half2float(xw16[(size_t)s2 * HID + lane]);
    float v3 = __half2float(xw16[(size_t)s3 * HID + lane]);
    acc += nrm0 * v0 + nrm1 * v1 + nrm2 * v2 + nrm3 * v3;
  }
  for (; i < end; ++i) {
    int s = __builtin_amdgcn_readfirstlane(csr_src[i]);
    float nrm = dinv[s] * csr_w[i] * di;
    acc += nrm * __half2float(xw16[(size_t)s * HID + lane]);
  }
  float v = acc + gcn_b[lane];
  float mu = wsum(v) * (1.f / HID);
  float dv = v - mu;
  float var = wsum(dv * dv) * (1.f / HID);
  float h = dv * rsqrtf(var + 1e-5f) * g[lane] + bb[lane];
  h = h > 0.f ? h : 0.f;
  h_init16[(size_t)n * HID + lane] = __float2half(h + xp[(size_t)n * HID + lane]);
}

// ---------------- MFMA GEMM 2: [xl|xr] = h16 @ [Wl|Wr]  (K=64, N=512) ----------
__global__ __launch_bounds__(512) void k_gat_gemm_mfma(
    const __half* __restrict__ h16, const float* __restrict__ Wl,
    const float* __restrict__ Wr, __half* __restrict__ xl, __half* __restrict__ xr) {
  __shared__ __half at[16 * 72];
  int t = threadIdx.x;
  int w = t >> 6, lane = t & 63;
  int m = lane & 15, q = lane >> 4;
  half8 bf[4][2];
#pragma unroll
  for (int tt = 0; tt < 4; ++tt) {
    int c = w * 16 + tt * 128 + m;          // 0..511
    const float* W = (c < 256) ? Wl : Wr;
    int nc = (c < 256) ? c : c - 256;
#pragma unroll
    for (int ch = 0; ch < 2; ++ch) {
      int kb = ch * 32 + q * 8;
#pragma unroll
      for (int j = 0; j < 8; ++j)
        bf[tt][ch][j] = (_Float16)W[(kb + j) * 256 + nc];
    }
  }
  int nb0 = blockIdx.x * (16 * GEMM_NT);
  for (int nt = 0; nt < GEMM_NT; ++nt) {
    int nb = nb0 + nt * 16;
    {
      int row = t >> 5, col = (t & 31) * 2;
      *reinterpret_cast<__half2*>(&at[row * 72 + col]) =
          *reinterpret_cast<const __half2*>(h16 + (size_t)(nb + row) * HID + col);
    }
    __syncthreads();
    half8 a0 = *reinterpret_cast<const half8*>(&at[m * 72 + q * 8]);
    half8 a1 = *reinterpret_cast<const half8*>(&at[m * 72 + 32 + q * 8]);
#pragma unroll
    for (int tt = 0; tt < 4; ++tt) {
      f32x4 acc = {0.f, 0.f, 0.f, 0.f};
      acc = __builtin_amdgcn_mfma_f32_16x16x32_f16(a0, bf[tt][0], acc, 0, 0, 0);
      acc = __builtin_amdgcn_mfma_f32_16x16x32_f16(a1, bf[tt][1], acc, 0, 0, 0);
      int c = w * 16 + tt * 128 + m;
      __half* out = (c < 256) ? (xl + c) : (xr + (c - 256));
#pragma unroll
      for (int r = 0; r < 4; ++r)
        out[(size_t)(nb + q * 4 + r) * 256] = __float2half(acc[r]);
    }
    __syncthreads();
  }
}

// ---------------- GATv2 fused: pk-fp16 score + softmax + aggregate + mean + LN --
// 4x edge unroll: four independent gather->score->reduce->exp streams.
__global__ __launch_bounds__(256) void k_gat_fused(
    const int* __restrict__ row_ptr, const int* __restrict__ csr_src,
    const __half* __restrict__ xl, const __half* __restrict__ xr,
    const float* __restrict__ att, const float* __restrict__ gat_b,
    const float* __restrict__ g, const float* __restrict__ bb,
    const __half* __restrict__ h_init16, __half* __restrict__ h2_16) {
  int n = wave_node();
  int lane = threadIdx.x & 63;
  const __half2 c06 = __float2half2_rn(0.6f);
  const __half2 c04 = __float2half2_rn(0.4f);
  float4 atv = *reinterpret_cast<const float4*>(att + lane * 4);
  __half2 at0 = __floats2half2_rn(atv.x, atv.y);
  __half2 at1 = __floats2half2_rn(atv.z, atv.w);
  Half4 R = *reinterpret_cast<const Half4*>(xr + (size_t)n * 256 + lane * 4);
  Half4 S = *reinterpret_cast<const Half4*>(xl + (size_t)n * 256 + lane * 4);

  float q = reduce16(edge_score(S, R.a, R.b, at0, at1, c06, c04));
  float w = __expf(q);
  float den = w;
  float2 f0 = __half22float2(S.a), f1 = __half22float2(S.b);
  float4 acc = make_float4(w * f0.x, w * f0.y, w * f1.x, w * f1.y);

  int beg = row_ptr[n], end = row_ptr[n + 1];
  int i = beg;
  for (; i + 4 <= end; i += 4) {
    int s0 = __builtin_amdgcn_readfirstlane(csr_src[i]);
    int s1 = __builtin_amdgcn_readfirstlane(csr_src[i + 1]);
    int s2 = __builtin_amdgcn_readfirstlane(csr_src[i + 2]);
    int s3 = __builtin_amdgcn_readfirstlane(csr_src[i + 3]);
    Half4 A0 = *reinterpret_cast<const Half4*>(xl + (size_t)s0 * 256 + lane * 4);
    Half4 A1 = *reinterpret_cast<const Half4*>(xl + (size_t)s1 * 256 + lane * 4);
    Half4 A2 = *reinterpret_cast<const Half4*>(xl + (size_t)s2 * 256 + lane * 4);
    Half4 A3 = *reinterpret_cast<const Half4*>(xl + (size_t)s3 * 256 + lane * 4);
    float q0 = edge_score(A0, R.a, R.b, at0, at1, c06, c04);
    float q1 = edge_score(A1, R.a, R.b, at0, at1, c06, c04);
    float q2 = edge_score(A2, R.a, R.b, at0, at1, c06, c04);
    float q3 = edge_score(A3, R.a, R.b, at0, at1, c06, c04);
    q0 += __shfl_xor(q0, 1); q1 += __shfl_xor(q1, 1);
    q2 += __shfl_xor(q2, 1); q3 += __shfl_xor(q3, 1);
    q0 += __shfl_xor(q0, 2); q1 += __shfl_xor(q1, 2);
    q2 += __shfl_xor(q2, 2); q3 += __shfl_xor(q3, 2);
    q0 += __shfl_xor(q0, 4); q1 += __shfl_xor(q1, 4);
    q2 += __shfl_xor(q2, 4); q3 += __shfl_xor(q3, 4);
    q0 += __shfl_xor(q0, 8); q1 += __shfl_xor(q1, 8);
    q2 += __shfl_xor(q2, 8); q3 += __shfl_xor(q3, 8);
    float w0 = __expf(q0), w1 = __expf(q1);
    float w2 = __expf(q2), w3 = __expf(q3);
    den += (w0 + w1) + (w2 + w3);
    float2 a00 = __half22float2(A0.a), a01 = __half22float2(A0.b);
    float2 a10 = __half22float2(A1.a), a11 = __half22float2(A1.b);
    float2 a20 = __half22float2(A2.a), a21 = __half22float2(A2.b);
    float2 a30 = __half22float2(A3.a), a31 = __half22float2(A3.b);
    acc.x += (w0 * a00.x + w1 * a10.x) + (w2 * a20.x + w3 * a30.x);
    acc.y += (w0 * a00.y + w1 * a10.y) + (w2 * a20.y + w3 * a30.y);
    acc.z += (w0 * a01.x + w1 * a11.x) + (w2 * a21.x + w3 * a31.x);
    acc.w += (w0 * a01.y + w1 * a11.y) + (w2 * a21.y + w3 * a31.y);
  }
  for (; i < end; ++i) {
    int s0 = __builtin_amdgcn_readfirstlane(csr_src[i]);
    Half4 A0 = *reinterpret_cast<const Half4*>(xl + (size_t)s0 * 256 + lane * 4);
    q = reduce16(edge_score(A0, R.a, R.b, at0, at1, c06, c04));
    w = __expf(q);
    den += w;
    float2 a00 = __half22float2(A0.a), a01 = __half22float2(A0.b);
    acc.x += w * a00.x; acc.y += w * a00.y;
    acc.z += w * a01.x; acc.w += w * a01.y;
  }
  float inv = 1.f / den;
  acc.x *= inv; acc.y *= inv; acc.z *= inv; acc.w *= inv;
  // mean over heads: lanes l, l^16, l^32, l^48 hold same feature of different heads
  acc.x += __shfl_xor(acc.x, 16); acc.y += __shfl_xor(acc.y, 16);
  acc.z += __shfl_xor(acc.z, 16); acc.w += __shfl_xor(acc.w, 16);
  acc.x += __shfl_xor(acc.x, 32); acc.y += __shfl_xor(acc.y, 32);
  acc.z += __shfl_xor(acc.z, 32); acc.w += __shfl_xor(acc.w, 32);
  // redistribute: feature `lane` = component (lane&3) of lane (lane>>2)
  int srcl = lane >> 2;
  float t0 = __shfl(acc.x, srcl), t1 = __shfl(acc.y, srcl);
  float t2 = __shfl(acc.z, srcl), t3 = __shfl(acc.w, srcl);
  int r = lane & 3;
  float mean = (r == 0) ? t0 : (r == 1) ? t1 : (r == 2) ? t2 : t3;
  float val = mean * 0.25f + gat_b[lane];
  float mu = wsum(val) * (1.f / HID);
  float dv = val - mu;
  float var = wsum(dv * dv) * (1.f / HID);
  float h = dv * rsqrtf(var + 1e-5f) * g[lane] + bb[lane];
  h = h > 0.f ? h : 0.f;
  float outv = h + __half2float(h_init16[(size_t)n * HID + lane]);
  h2_16[(size_t)n * HID + lane] = __float2half(outv);
}

// ---------------- SAGE stage 1: pull mean-gather (fp32 out, n in SGPR, 4x ILP) --
__global__ __launch_bounds__(256) void k_sage_gather(
    const int* __restrict__ row_ptr, const int* __restrict__ csr_src,
    const __half* __restrict__ h2_16, float* __restrict__ nmean) {
  int n = wave_node();
  int lane = threadIdx.x & 63;
  int beg = row_ptr[n], end = row_ptr[n + 1];
  float sum = 0.f;
  int i = beg;
  for (; i + 4 <= end; i += 4) {
    int s0 = __builtin_amdgcn_readfirstlane(csr_src[i]);
    int s1 = __builtin_amdgcn_readfirstlane(csr_src[i + 1]);
    int s2 = __builtin_amdgcn_readfirstlane(csr_src[i + 2]);
    int s3 = __builtin_amdgcn_readfirstlane(csr_src[i + 3]);
    float v0 = __half2float(h2_16[(size_t)s0 * HID + lane]);
    float v1 = __half2float(h2_16[(size_t)s1 * HID + lane]);
    float v2 = __half2float(h2_16[(size_t)s2 * HID + lane]);
    float v3 = __half2float(h2_16[(size_t)s3 * HID + lane]);
    sum += v0 + v1 + v2 + v3;
  }
  for (; i < end; ++i) {
    int s = __builtin_amdgcn_readfirstlane(csr_src[i]);
    sum += __half2float(h2_16[(size_t)s * HID + lane]);
  }
  nmean[(size_t)n * HID + lane] = sum / fmaxf((float)(end - beg), 1.f);
}

// ---------------- SAGE stage 2: dense nmean@Wl + h2@Wr + LN (LDS-staged acts) ---
__global__ __launch_bounds__(64) void k_sage_gemm_ln(
    const float* __restrict__ nmean, const __half* __restrict__ h2_16,
    const float* __restrict__ Wl, const float* __restrict__ Wr,
    const float* __restrict__ sage_bl, const float* __restrict__ g,
    const float* __restrict__ bb, float* __restrict__ h3) {
  __shared__ float nt[8][HID];
  __shared__ float ht[8][HID];
  int t = threadIdx.x;
  int n0 = blockIdx.x * 8;
  {
    const float4* ng = reinterpret_cast<const float4*>(nmean + (size_t)n0 * HID);
    float4* ns = reinterpret_cast<float4*>(&nt[0][0]);
    ns[t] = ng[t];
    ns[t + 64] = ng[t + 64];
    const __half* hp = h2_16 + (size_t)n0 * HID + t * 8;
    Half4 p0 = *reinterpret_cast<const Half4*>(hp);
    Half4 p1 = *reinterpret_cast<const Half4*>(hp + 4);
    float* dsth = &ht[0][0] + t * 8;
    float2 f;
    f = __half22float2(p0.a); dsth[0] = f.x; dsth[1] = f.y;
    f = __half22float2(p0.b); dsth[2] = f.x; dsth[3] = f.y;
    f = __half22float2(p1.a); dsth[4] = f.x; dsth[5] = f.y;
    f = __half22float2(p1.b); dsth[6] = f.x; dsth[7] = f.y;
  }
  __syncthreads();
  int f = t;
  float acc[8] = {0.f,0.f,0.f,0.f,0.f,0.f,0.f,0.f};
  for (int k = 0; k < HID; k += 4) {
    float wl0 = Wl[(k + 0) * HID + f], wr0 = Wr[(k + 0) * HID + f];
    float wl1 = Wl[(k + 1) * HID + f], wr1 = Wr[(k + 1) * HID + f];
    float wl2 = Wl[(k + 2) * HID + f], wr2 = Wr[(k + 2) * HID + f];
    float wl3 = Wl[(k + 3) * HID + f], wr3 = Wr[(k + 3) * HID + f];
#pragma unroll
    for (int j = 0; j < 8; ++j) {
      float4 nv = *reinterpret_cast<const float4*>(&nt[j][k]);
      float4 hv = *reinterpret_cast<const float4*>(&ht[j][k]);
      acc[j] += nv.x * wl0 + nv.y * wl1 + nv.z * wl2 + nv.w * wl3
              + hv.x * wr0 + hv.y * wr1 + hv.z * wr2 + hv.w * wr3;
    }
  }
  float blv = sage_bl[f], gv = g[f], bbv = bb[f];
#pragma unroll
  for (int j = 0; j < 8; ++j) {
    float v = acc[j] + blv;
    float mu = wsum(v) * (1.f / HID);
    float dv = v - mu;
    float var = wsum(dv * dv) * (1.f / HID);
    float h = dv * rsqrtf(var + 1e-5f) * gv + bbv;
    h = h > 0.f ? h : 0.f;
    h3[(size_t)(n0 + j) * HID + f] = h + ht[j][f];
  }
}

// ---------------- heads ----------------
__global__ __launch_bounds__(256) void k_heads(
    const __half* __restrict__ h_init16, const __half* __restrict__ h2_16,
    const float* __restrict__ h3, const int* __restrict__ mask,
    const float* __restrict__ mort_W, const float* __restrict__ mort_b,
    const float* __restrict__ hours_W, const float* __restrict__ hours_b,
    const float* __restrict__ disc_W, const float* __restrict__ disc_b,
    float* __restrict__ out) {
  int n = wave_node();
  int lane = threadIdx.x & 63;
  float m = (mask[n] != 0) ? 1.f : 0.f;
  size_t base = (size_t)n * HID;
  float v0 = __half2float(h_init16[base + lane]) * m;
  float v1 = __half2float(h2_16[base + lane]) * m;
  float v2 = h3[base + lane] * m;
  float pm = v0 * mort_W[lane] + v1 * mort_W[64 + lane] + v2 * mort_W[128 + lane];
  float ph = v0 * hours_W[lane] + v1 * hours_W[64 + lane] + v2 * hours_W[128 + lane];
  float d0 = v0 * disc_W[lane * 4 + 0] + v1 * disc_W[(64 + lane) * 4 + 0] + v2 * disc_W[(128 + lane) * 4 + 0];
  float d1 = v0 * disc_W[lane * 4 + 1] + v1 * disc_W[(64 + lane) * 4 + 1] + v2 * disc_W[(128 + lane) * 4 + 1];
  float d2 = v0 * disc_W[lane * 4 + 2] + v1 * disc_W[(64 + lane) * 4 + 2] + v2 * disc_W[(128 + lane) * 4 + 2];
  float d3 = v0 * disc_W[lane * 4 + 3] + v1 * disc_W[(64 + lane) * 4 + 3] + v2 * disc_W[(128 + lane) * 4 + 3];
  pm = wsum(pm); ph = wsum(ph);
  d0 = wsum(d0); d1 = wsum(d1); d2 = wsum(d2); d3 = wsum(d3);
  if (lane == 0) {
    out[n] = pm + mort_b[0];
    out[N_NODES + n] = ph + hours_b[0];
    float* dd = out + 2 * N_NODES + (size_t)n * 4;
    dd[0] = d0 + disc_b[0];
    dd[1] = d1 + disc_b[1];
    dd[2] = d2 + disc_b[2];
    dd[3] = d3 + disc_b[3];
  }
}

extern "C" void kernel_launch(void* const* d_in, const int* in_sizes, int n_in,
                              void* d_out, int out_size, void* d_ws, size_t ws_size,
                              hipStream_t stream) {
  const float* x       = (const float*)d_in[0];
  const int*   ei      = (const int*)d_in[1];
  const float* ew      = (const float*)d_in[2];
  const int*   mask    = (const int*)d_in[3];
  const float* gcn_W   = (const float*)d_in[4];
  const float* gcn_b   = (const float*)d_in[5];
  const float* proj_W  = (const float*)d_in[6];
  const float* proj_b  = (const float*)d_in[7];
  const float* ln1_g   = (const float*)d_in[8];
  const float* ln1_b   = (const float*)d_in[9];
  const float* gat_Wl  = (const float*)d_in[10];
  const float* gat_Wr  = (const float*)d_in[11];
  const float* gat_att = (const float*)d_in[12];
  const float* gat_b   = (const float*)d_in[13];
  const float* ln2_g   = (const float*)d_in[14];
  const float* ln2_b   = (const float*)d_in[15];
  const float* sage_Wl = (const float*)d_in[16];
  const float* sage_bl = (const float*)d_in[17];
  const float* sage_Wr = (const float*)d_in[18];
  const float* ln3_g   = (const float*)d_in[19];
  const float* ln3_b   = (const float*)d_in[20];
  // d_in[21..24]: edge-MLP params — output unused by the reference; skipped.
  const float* mort_W  = (const float*)d_in[25];
  const float* mort_b  = (const float*)d_in[26];
  const float* hours_W = (const float*)d_in[27];
  const float* hours_b = (const float*)d_in[28];
  const float* disc_W  = (const float*)d_in[29];
  const float* disc_b  = (const float*)d_in[30];

  const int* src = ei;
  const int* dst = ei + N_EDGES;
  float* out = (float*)d_out;

  // ---- workspace layout (~52M floats ≈ 209 MB) ----
  float* ws = (float*)d_ws;
  const size_t F = (size_t)N_NODES * HID;  // 6.4M floats
  float* h3     = ws + 2 * F;
  float* xp     = h3;                              // fp32, dead before h3 written
  __half* xl    = (__half*)(ws + 3 * F);           // N*256 halfs
  __half* xw16  = xl;                              // N*64 halfs, dead before xl written
  float* nmean  = ws + 3 * F;                      // fp32 N*64, xl dead by SAGE
  __half* xr    = (__half*)(ws + 3 * F + (size_t)N_NODES * 128);
  __half* h2_16 = (__half*)(ws + 3 * F + (size_t)N_NODES * 256);
  __half* h_init16 = (__half*)(ws + 3 * F + (size_t)N_NODES * 288);
  float* tail   = ws + 3 * F + (size_t)N_NODES * 320;
  int*   csr_src = (int*)tail;           tail += N_EDGES;
  float* csr_w   = tail;                 tail += N_EDGES;
  int*   row_ptr = (int*)tail;           tail += N_NODES + 64;
  int*   cursor  = (int*)tail;           tail += N_NODES;
  int*   cnt     = (int*)tail;           tail += N_NODES;
  int*   partial = (int*)tail;           tail += N_NODES;
  int*   bsum    = (int*)tail;           tail += 128;
  float* dinv    = tail;

  const int GE = (N_EDGES + 255) / 256;
  const int GN = (N_NODES + 255) / 256;
  const int GB = N_NODES / (16 * GEMM_NT);  // 1250 blocks for MFMA GEMMs

  // --- CSR build (by dst) ---
  hipMemsetAsync(cnt, 0, N_NODES * sizeof(int), stream);
  k_hist<<<GE, 256, 0, stream>>>(dst, cnt);
  k_scan1<<<SCAN_BLK, 256, 0, stream>>>(cnt, partial, bsum);
  k_scan2<<<1, 128, 0, stream>>>(bsum);
  k_scan3<<<GN, 256, 0, stream>>>(partial, bsum, row_ptr, cursor);
  k_fill<<<GE, 256, 0, stream>>>(src, dst, ew, cursor, csr_src, csr_w);

  // --- GCN layer ---
  k_in_gemm_mfma<<<GB, 512, 0, stream>>>(x, gcn_W, proj_W, proj_b, xw16, xp);
  k_deg<<<GN, 256, 0, stream>>>(row_ptr, csr_w, dinv);
  k_gcn_fused<<<N_NODES / 4, 256, 0, stream>>>(row_ptr, csr_src, csr_w, dinv, xw16,
                                               xp, gcn_b, ln1_g, ln1_b, h_init16);

  // --- GATv2 layer ---
  k_gat_gemm_mfma<<<GB, 512, 0, stream>>>(h_init16, gat_Wl, gat_Wr, xl, xr);
  k_gat_fused<<<N_NODES / 4, 256, 0, stream>>>(row_ptr, csr_src, xl, xr, gat_att,
                                               gat_b, ln2_g, ln2_b, h_init16, h2_16);

  // --- SAGE layer ---
  k_sage_gather<<<N_NODES / 4, 256, 0, stream>>>(row_ptr, csr_src, h2_16, nmean);
  k_sage_gemm_ln<<<N_NODES / 8, 64, 0, stream>>>(nmean, h2_16, sage_Wl, sage_Wr,
                                                 sage_bl, ln3_g, ln3_b, h3);

  // --- heads ---
  k_heads<<<N_NODES / 4, 256, 0, stream>>>(h_init16, h2_16, h3, mask, mort_W, mort_b,
                                           hours_W, hours_b, disc_W, disc_b, out);
}

// Round 12
// 566.400 us; speedup vs baseline: 1.8098x; 1.0093x over previous
//
#include <hip/hip_runtime.h>
#include <hip/hip_fp16.h>
#include <math.h>

#define N_NODES 100000
#define N_EDGES 1000000
#define F_IN    128
#define HID     64
#define HEADS   4
#define NCLS    4
#define SCAN_BLK 98   // ceil(N_NODES / 1024)
#define GEMM_NT 5     // node-tiles per block in MFMA GEMMs (80 nodes/block)

typedef _Float16 half8 __attribute__((ext_vector_type(8)));
typedef _Float16 fp16x2 __attribute__((ext_vector_type(2)));
typedef float f32x4 __attribute__((ext_vector_type(4)));

// ---------------- helpers ----------------
__device__ __forceinline__ float wsum(float v) {
#pragma unroll
  for (int o = 32; o > 0; o >>= 1) v += __shfl_xor(v, o, 64);
  return v;
}
struct Half4 { __half2 a, b; };
__device__ __forceinline__ __half2 absh2(__half2 v) {
  unsigned u; __builtin_memcpy(&u, &v, 4);
  u &= 0x7FFF7FFFu;
  __half2 r; __builtin_memcpy(&r, &u, 4);
  return r;
}
__device__ __forceinline__ float fdot2f(__half2 a, __half2 b, float c) {
#if defined(__has_builtin) && __has_builtin(__builtin_amdgcn_fdot2)
  fp16x2 av, bv;
  __builtin_memcpy(&av, &a, 4); __builtin_memcpy(&bv, &b, 4);
  return __builtin_amdgcn_fdot2(av, bv, c, false);
#else
  float2 af = __half22float2(a), bf = __half22float2(b);
  return c + af.x * bf.x + af.y * bf.y;
#endif
}
// score = sum att_h * leaky(xl+xr) over this lane's 4 elems; leaky(t)=0.6t+0.4|t|
__device__ __forceinline__ float edge_score(Half4 A, __half2 Ra, __half2 Rb,
                                            __half2 at0, __half2 at1,
                                            __half2 c06, __half2 c04) {
  __half2 t0 = __hadd2(A.a, Ra), t1 = __hadd2(A.b, Rb);
  __half2 l0 = __hfma2(t0, c06, __hmul2(absh2(t0), c04));
  __half2 l1 = __hfma2(t1, c06, __hmul2(absh2(t1), c04));
  return fdot2f(l1, at1, fdot2f(l0, at0, 0.f));
}
__device__ __forceinline__ float reduce16(float q) {
  q += __shfl_xor(q, 1); q += __shfl_xor(q, 2);
  q += __shfl_xor(q, 4); q += __shfl_xor(q, 8);
  return q;
}
// wave-uniform node id -> SGPR (row_ptr/csr reads become scalar loads)
__device__ __forceinline__ int wave_node() {
  return __builtin_amdgcn_readfirstlane(blockIdx.x * 4 + (threadIdx.x >> 6));
}

// ---------------- CSR build (by dst) ----------------
__global__ void k_hist(const int* __restrict__ dst, int* __restrict__ cnt) {
  int e = blockIdx.x * 256 + threadIdx.x;
  if (e < N_EDGES) atomicAdd(&cnt[dst[e]], 1);
}
__global__ __launch_bounds__(256) void k_scan1(const int* __restrict__ cnt,
                                               int* __restrict__ partial,
                                               int* __restrict__ bsum) {
  __shared__ int lds[256];
  int t = threadIdx.x;
  int base = blockIdx.x * 1024 + t * 4;
  int v0 = (base + 0 < N_NODES) ? cnt[base + 0] : 0;
  int v1 = (base + 1 < N_NODES) ? cnt[base + 1] : 0;
  int v2 = (base + 2 < N_NODES) ? cnt[base + 2] : 0;
  int v3 = (base + 3 < N_NODES) ? cnt[base + 3] : 0;
  int s = v0 + v1 + v2 + v3;
  lds[t] = s;
  __syncthreads();
  for (int o = 1; o < 256; o <<= 1) {
    int x = (t >= o) ? lds[t - o] : 0;
    __syncthreads();
    lds[t] += x;
    __syncthreads();
  }
  int excl = lds[t] - s;
  if (base + 0 < N_NODES) partial[base + 0] = excl;
  if (base + 1 < N_NODES) partial[base + 1] = excl + v0;
  if (base + 2 < N_NODES) partial[base + 2] = excl + v0 + v1;
  if (base + 3 < N_NODES) partial[base + 3] = excl + v0 + v1 + v2;
  if (t == 255) bsum[blockIdx.x] = lds[255];
}
// scan of bsum folded in: every block redundantly scans the 98 block-sums.
__global__ __launch_bounds__(256) void k_scan3(const int* __restrict__ partial,
                                               const int* __restrict__ bsum,
                                               int* __restrict__ row_ptr,
                                               int* __restrict__ cursor) {
  __shared__ int ex[128];
  int t = threadIdx.x;
  int orig = 0;
  if (t < 128) {
    orig = (t < SCAN_BLK) ? bsum[t] : 0;
    ex[t] = orig;
  }
  __syncthreads();
  for (int o = 1; o < 128; o <<= 1) {
    int x = (t < 128 && t >= o) ? ex[t - o] : 0;
    __syncthreads();
    if (t < 128) ex[t] += x;
    __syncthreads();
  }
  if (t < 128) ex[t] -= orig;  // exclusive
  __syncthreads();
  int i = blockIdx.x * 256 + t;
  if (i < N_NODES) {
    int v = partial[i] + ex[i >> 10];
    row_ptr[i] = v;
    cursor[i] = v;
  }
  if (i == 0) row_ptr[N_NODES] = N_EDGES;
}
__global__ void k_fill(const int* __restrict__ src, const int* __restrict__ dst,
                       const float* __restrict__ ew, int* __restrict__ cursor,
                       int* __restrict__ csr_src, float* __restrict__ csr_w) {
  int e = blockIdx.x * 256 + threadIdx.x;
  if (e >= N_EDGES) return;
  int d = dst[e];
  int p = atomicAdd(&cursor[d], 1);
  csr_src[p] = src[e];
  csr_w[p] = ew[e];
}

// ---------------- MFMA GEMM 1: [xw16|xp16] = x @ [gcn_W|proj_W]  (K=128, N=128) --
__global__ __launch_bounds__(512) void k_in_gemm_mfma(
    const float* __restrict__ x, const float* __restrict__ gcn_W,
    const float* __restrict__ proj_W, const float* __restrict__ proj_b,
    __half* __restrict__ xw16, __half* __restrict__ xp16) {
  __shared__ __half at[16 * 136];
  int t = threadIdx.x;
  int w = t >> 6, lane = t & 63;
  int m = lane & 15, q = lane >> 4;
  int ncol = w * 16 + m;                 // 0..127
  const float* W = (ncol < 64) ? gcn_W : proj_W;
  int nc = (ncol < 64) ? ncol : ncol - 64;
  half8 bf[4];
#pragma unroll
  for (int ch = 0; ch < 4; ++ch) {
    int kb = ch * 32 + q * 8;
#pragma unroll
    for (int j = 0; j < 8; ++j)
      bf[ch][j] = (_Float16)W[(kb + j) * 64 + nc];
  }
  float pb = (ncol >= 64) ? proj_b[nc] : 0.f;
  int nb0 = blockIdx.x * (16 * GEMM_NT);
  for (int nt = 0; nt < GEMM_NT; ++nt) {
    int nb = nb0 + nt * 16;
    {
      int row = t >> 5, col = (t & 31) * 4;
      float4 v = *reinterpret_cast<const float4*>(x + (size_t)(nb + row) * F_IN + col);
      __half2* d = reinterpret_cast<__half2*>(&at[row * 136 + col]);
      d[0] = __floats2half2_rn(v.x, v.y);
      d[1] = __floats2half2_rn(v.z, v.w);
    }
    __syncthreads();
    f32x4 acc = {0.f, 0.f, 0.f, 0.f};
#pragma unroll
    for (int ch = 0; ch < 4; ++ch) {
      half8 af = *reinterpret_cast<const half8*>(&at[m * 136 + ch * 32 + q * 8]);
      acc = __builtin_amdgcn_mfma_f32_16x16x32_f16(af, bf[ch], acc, 0, 0, 0);
    }
    if (ncol < 64) {
#pragma unroll
      for (int r = 0; r < 4; ++r)
        xw16[(size_t)(nb + q * 4 + r) * HID + nc] = __float2half(acc[r]);
    } else {
#pragma unroll
      for (int r = 0; r < 4; ++r)
        xp16[(size_t)(nb + q * 4 + r) * HID + nc] = __float2half(acc[r] + pb);
    }
    __syncthreads();
  }
}

// ---------------- GCN: deg/dinv from CSR (no atomics) ----------------
__global__ void k_deg(const int* __restrict__ row_ptr, const float* __restrict__ csr_w,
                      float* __restrict__ dinv) {
  int n = blockIdx.x * 256 + threadIdx.x;
  if (n >= N_NODES) return;
  float deg = 1.0f;  // self-loop weight
  int end = row_ptr[n + 1];
  for (int i = row_ptr[n]; i < end; ++i) deg += csr_w[i];
  dinv[n] = rsqrtf(deg);  // deg >= 1 always
}

// pull-gather + LN + relu + residual, one wave per node (n in SGPR), 4x ILP
__global__ __launch_bounds__(256) void k_gcn_fused(
    const int* __restrict__ row_ptr, const int* __restrict__ csr_src,
    const float* __restrict__ csr_w, const float* __restrict__ dinv,
    const __half* __restrict__ xw16, const __half* __restrict__ xp16,
    const float* __restrict__ gcn_b, const float* __restrict__ g,
    const float* __restrict__ bb, __half* __restrict__ h_init16) {
  int n = wave_node();
  int lane = threadIdx.x & 63;
  float di = dinv[n];
  float acc = di * di * __half2float(xw16[(size_t)n * HID + lane]);  // self loop
  int beg = row_ptr[n], end = row_ptr[n + 1];
  int i = beg;
  for (; i + 4 <= end; i += 4) {
    int s0 = __builtin_amdgcn_readfirstlane(csr_src[i]);
    int s1 = __builtin_amdgcn_readfirstlane(csr_src[i + 1]);
    int s2 = __builtin_amdgcn_readfirstlane(csr_src[i + 2]);
    int s3 = __builtin_amdgcn_readfirstlane(csr_src[i + 3]);
    float nrm0 = dinv[s0] * csr_w[i] * di;
    float nrm1 = dinv[s1] * csr_w[i + 1] * di;
    float nrm2 = dinv[s2] * csr_w[i + 2] * di;
    float nrm3 = dinv[s3] * csr_w[i + 3] * di;
    float v0 = __half2float(xw16[(size_t)s0 * HID + lane]);
    float v1 = __half2float(xw16[(size_t)s1 * HID + lane]);
    float v2 = __half2float(xw16[(size_t)s2 * HID + lane]);
    float v3 = __half2float(xw16[(size_t)s3 * HID + lane]);
    acc += nrm0 * v0 + nrm1 * v1 + nrm2 * v2 + nrm3 * v3;
  }
  for (; i < end; ++i) {
    int s = __builtin_amdgcn_readfirstlane(csr_src[i]);
    float nrm = dinv[s] * csr_w[i] * di;
    acc += nrm * __half2float(xw16[(size_t)s * HID + lane]);
  }
  float v = acc + gcn_b[lane];
  float mu = wsum(v) * (1.f / HID);
  float dv = v - mu;
  float var = wsum(dv * dv) * (1.f / HID);
  float h = dv * rsqrtf(var + 1e-5f) * g[lane] + bb[lane];
  h = h > 0.f ? h : 0.f;
  h_init16[(size_t)n * HID + lane] =
      __float2half(h + __half2float(xp16[(size_t)n * HID + lane]));
}

// ---------------- MFMA GEMM 2: [xl|xr] = h16 @ [Wl|Wr]  (K=64, N=512) ----------
__global__ __launch_bounds__(512) void k_gat_gemm_mfma(
    const __half* __restrict__ h16, const float* __restrict__ Wl,
    const float* __restrict__ Wr, __half* __restrict__ xl, __half* __restrict__ xr) {
  __shared__ __half at[16 * 72];
  int t = threadIdx.x;
  int w = t >> 6, lane = t & 63;
  int m = lane & 15, q = lane >> 4;
  half8 bf[4][2];
#pragma unroll
  for (int tt = 0; tt < 4; ++tt) {
    int c = w * 16 + tt * 128 + m;          // 0..511
    const float* W = (c < 256) ? Wl : Wr;
    int nc = (c < 256) ? c : c - 256;
#pragma unroll
    for (int ch = 0; ch < 2; ++ch) {
      int kb = ch * 32 + q * 8;
#pragma unroll
      for (int j = 0; j < 8; ++j)
        bf[tt][ch][j] = (_Float16)W[(kb + j) * 256 + nc];
    }
  }
  int nb0 = blockIdx.x * (16 * GEMM_NT);
  for (int nt = 0; nt < GEMM_NT; ++nt) {
    int nb = nb0 + nt * 16;
    {
      int row = t >> 5, col = (t & 31) * 2;
      *reinterpret_cast<__half2*>(&at[row * 72 + col]) =
          *reinterpret_cast<const __half2*>(h16 + (size_t)(nb + row) * HID + col);
    }
    __syncthreads();
    half8 a0 = *reinterpret_cast<const half8*>(&at[m * 72 + q * 8]);
    half8 a1 = *reinterpret_cast<const half8*>(&at[m * 72 + 32 + q * 8]);
#pragma unroll
    for (int tt = 0; tt < 4; ++tt) {
      f32x4 acc = {0.f, 0.f, 0.f, 0.f};
      acc = __builtin_amdgcn_mfma_f32_16x16x32_f16(a0, bf[tt][0], acc, 0, 0, 0);
      acc = __builtin_amdgcn_mfma_f32_16x16x32_f16(a1, bf[tt][1], acc, 0, 0, 0);
      int c = w * 16 + tt * 128 + m;
      __half* out = (c < 256) ? (xl + c) : (xr + (c - 256));
#pragma unroll
      for (int r = 0; r < 4; ++r)
        out[(size_t)(nb + q * 4 + r) * 256] = __float2half(acc[r]);
    }
    __syncthreads();
  }
}

// ---------------- GATv2 fused: pk-fp16 score + softmax + aggregate + mean + LN --
__global__ __launch_bounds__(256) void k_gat_fused(
    const int* __restrict__ row_ptr, const int* __restrict__ csr_src,
    const __half* __restrict__ xl, const __half* __restrict__ xr,
    const float* __restrict__ att, const float* __restrict__ gat_b,
    const float* __restrict__ g, const float* __restrict__ bb,
    const __half* __restrict__ h_init16, __half* __restrict__ h2_16) {
  int n = wave_node();
  int lane = threadIdx.x & 63;
  const __half2 c06 = __float2half2_rn(0.6f);
  const __half2 c04 = __float2half2_rn(0.4f);
  float4 atv = *reinterpret_cast<const float4*>(att + lane * 4);
  __half2 at0 = __floats2half2_rn(atv.x, atv.y);
  __half2 at1 = __floats2half2_rn(atv.z, atv.w);
  Half4 R = *reinterpret_cast<const Half4*>(xr + (size_t)n * 256 + lane * 4);
  Half4 S = *reinterpret_cast<const Half4*>(xl + (size_t)n * 256 + lane * 4);

  float q = reduce16(edge_score(S, R.a, R.b, at0, at1, c06, c04));
  float w = __expf(q);
  float den = w;
  float2 f0 = __half22float2(S.a), f1 = __half22float2(S.b);
  float4 acc = make_float4(w * f0.x, w * f0.y, w * f1.x, w * f1.y);

  int beg = row_ptr[n], end = row_ptr[n + 1];
  int i = beg;
  for (; i + 4 <= end; i += 4) {
    int s0 = __builtin_amdgcn_readfirstlane(csr_src[i]);
    int s1 = __builtin_amdgcn_readfirstlane(csr_src[i + 1]);
    int s2 = __builtin_amdgcn_readfirstlane(csr_src[i + 2]);
    int s3 = __builtin_amdgcn_readfirstlane(csr_src[i + 3]);
    Half4 A0 = *reinterpret_cast<const Half4*>(xl + (size_t)s0 * 256 + lane * 4);
    Half4 A1 = *reinterpret_cast<const Half4*>(xl + (size_t)s1 * 256 + lane * 4);
    Half4 A2 = *reinterpret_cast<const Half4*>(xl + (size_t)s2 * 256 + lane * 4);
    Half4 A3 = *reinterpret_cast<const Half4*>(xl + (size_t)s3 * 256 + lane * 4);
    float q0 = edge_score(A0, R.a, R.b, at0, at1, c06, c04);
    float q1 = edge_score(A1, R.a, R.b, at0, at1, c06, c04);
    float q2 = edge_score(A2, R.a, R.b, at0, at1, c06, c04);
    float q3 = edge_score(A3, R.a, R.b, at0, at1, c06, c04);
    q0 += __shfl_xor(q0, 1); q1 += __shfl_xor(q1, 1);
    q2 += __shfl_xor(q2, 1); q3 += __shfl_xor(q3, 1);
    q0 += __shfl_xor(q0, 2); q1 += __shfl_xor(q1, 2);
    q2 += __shfl_xor(q2, 2); q3 += __shfl_xor(q3, 2);
    q0 += __shfl_xor(q0, 4); q1 += __shfl_xor(q1, 4);
    q2 += __shfl_xor(q2, 4); q3 += __shfl_xor(q3, 4);
    q0 += __shfl_xor(q0, 8); q1 += __shfl_xor(q1, 8);
    q2 += __shfl_xor(q2, 8); q3 += __shfl_xor(q3, 8);
    float w0 = __expf(q0), w1 = __expf(q1);
    float w2 = __expf(q2), w3 = __expf(q3);
    den += (w0 + w1) + (w2 + w3);
    float2 a00 = __half22float2(A0.a), a01 = __half22float2(A0.b);
    float2 a10 = __half22float2(A1.a), a11 = __half22float2(A1.b);
    float2 a20 = __half22float2(A2.a), a21 = __half22float2(A2.b);
    float2 a30 = __half22float2(A3.a), a31 = __half22float2(A3.b);
    acc.x += (w0 * a00.x + w1 * a10.x) + (w2 * a20.x + w3 * a30.x);
    acc.y += (w0 * a00.y + w1 * a10.y) + (w2 * a20.y + w3 * a30.y);
    acc.z += (w0 * a01.x + w1 * a11.x) + (w2 * a21.x + w3 * a31.x);
    acc.w += (w0 * a01.y + w1 * a11.y) + (w2 * a21.y + w3 * a31.y);
  }
  for (; i < end; ++i) {
    int s0 = __builtin_amdgcn_readfirstlane(csr_src[i]);
    Half4 A0 = *reinterpret_cast<const Half4*>(xl + (size_t)s0 * 256 + lane * 4);
    q = reduce16(edge_score(A0, R.a, R.b, at0, at1, c06, c04));
    w = __expf(q);
    den += w;
    float2 a00 = __half22float2(A0.a), a01 = __half22float2(A0.b);
    acc.x += w * a00.x; acc.y += w * a00.y;
    acc.z += w * a01.x; acc.w += w * a01.y;
  }
  float inv = 1.f / den;
  acc.x *= inv; acc.y *= inv; acc.z *= inv; acc.w *= inv;
  // mean over heads: lanes l, l^16, l^32, l^48 hold same feature of different heads
  acc.x += __shfl_xor(acc.x, 16); acc.y += __shfl_xor(acc.y, 16);
  acc.z += __shfl_xor(acc.z, 16); acc.w += __shfl_xor(acc.w, 16);
  acc.x += __shfl_xor(acc.x, 32); acc.y += __shfl_xor(acc.y, 32);
  acc.z += __shfl_xor(acc.z, 32); acc.w += __shfl_xor(acc.w, 32);
  // redistribute: feature `lane` = component (lane&3) of lane (lane>>2)
  int srcl = lane >> 2;
  float t0 = __shfl(acc.x, srcl), t1 = __shfl(acc.y, srcl);
  float t2 = __shfl(acc.z, srcl), t3 = __shfl(acc.w, srcl);
  int r = lane & 3;
  float mean = (r == 0) ? t0 : (r == 1) ? t1 : (r == 2) ? t2 : t3;
  float val = mean * 0.25f + gat_b[lane];
  float mu = wsum(val) * (1.f / HID);
  float dv = val - mu;
  float var = wsum(dv * dv) * (1.f / HID);
  float h = dv * rsqrtf(var + 1e-5f) * g[lane] + bb[lane];
  h = h > 0.f ? h : 0.f;
  float outv = h + __half2float(h_init16[(size_t)n * HID + lane]);
  h2_16[(size_t)n * HID + lane] = __float2half(outv);
}

// ---------------- SAGE stage 1: pull mean-gather (fp16 out, n in SGPR, 4x ILP) --
__global__ __launch_bounds__(256) void k_sage_gather(
    const int* __restrict__ row_ptr, const int* __restrict__ csr_src,
    const __half* __restrict__ h2_16, __half* __restrict__ nmean16) {
  int n = wave_node();
  int lane = threadIdx.x & 63;
  int beg = row_ptr[n], end = row_ptr[n + 1];
  float sum = 0.f;
  int i = beg;
  for (; i + 4 <= end; i += 4) {
    int s0 = __builtin_amdgcn_readfirstlane(csr_src[i]);
    int s1 = __builtin_amdgcn_readfirstlane(csr_src[i + 1]);
    int s2 = __builtin_amdgcn_readfirstlane(csr_src[i + 2]);
    int s3 = __builtin_amdgcn_readfirstlane(csr_src[i + 3]);
    float v0 = __half2float(h2_16[(size_t)s0 * HID + lane]);
    float v1 = __half2float(h2_16[(size_t)s1 * HID + lane]);
    float v2 = __half2float(h2_16[(size_t)s2 * HID + lane]);
    float v3 = __half2float(h2_16[(size_t)s3 * HID + lane]);
    sum += v0 + v1 + v2 + v3;
  }
  for (; i < end; ++i) {
    int s = __builtin_amdgcn_readfirstlane(csr_src[i]);
    sum += __half2float(h2_16[(size_t)s * HID + lane]);
  }
  nmean16[(size_t)n * HID + lane] =
      __float2half(sum / fmaxf((float)(end - beg), 1.f));
}

// ---------------- SAGE stage 2 + heads (fused): h3 never materialized ----------
__global__ __launch_bounds__(64) void k_sage_gemm_ln_heads(
    const __half* __restrict__ nmean16, const __half* __restrict__ h2_16,
    const __half* __restrict__ h_init16,
    const float* __restrict__ Wl, const float* __restrict__ Wr,
    const float* __restrict__ sage_bl, const float* __restrict__ g,
    const float* __restrict__ bb, const int* __restrict__ mask,
    const float* __restrict__ mort_W, const float* __restrict__ mort_b,
    const float* __restrict__ hours_W, const float* __restrict__ hours_b,
    const float* __restrict__ disc_W, const float* __restrict__ disc_b,
    float* __restrict__ out) {
  __shared__ float nt[8][HID];
  __shared__ float ht[8][HID];
  int t = threadIdx.x;
  int n0 = blockIdx.x * 8;
  {
    const __half* np = nmean16 + (size_t)n0 * HID + t * 8;
    const __half* hp = h2_16 + (size_t)n0 * HID + t * 8;
    Half4 n0v = *reinterpret_cast<const Half4*>(np);
    Half4 n1v = *reinterpret_cast<const Half4*>(np + 4);
    Half4 p0 = *reinterpret_cast<const Half4*>(hp);
    Half4 p1 = *reinterpret_cast<const Half4*>(hp + 4);
    float* dn = &nt[0][0] + t * 8;
    float* dh = &ht[0][0] + t * 8;
    float2 f;
    f = __half22float2(n0v.a); dn[0] = f.x; dn[1] = f.y;
    f = __half22float2(n0v.b); dn[2] = f.x; dn[3] = f.y;
    f = __half22float2(n1v.a); dn[4] = f.x; dn[5] = f.y;
    f = __half22float2(n1v.b); dn[6] = f.x; dn[7] = f.y;
    f = __half22float2(p0.a);  dh[0] = f.x; dh[1] = f.y;
    f = __half22float2(p0.b);  dh[2] = f.x; dh[3] = f.y;
    f = __half22float2(p1.a);  dh[4] = f.x; dh[5] = f.y;
    f = __half22float2(p1.b);  dh[6] = f.x; dh[7] = f.y;
  }
  __syncthreads();
  int f = t;
  float acc[8] = {0.f,0.f,0.f,0.f,0.f,0.f,0.f,0.f};
  for (int k = 0; k < HID; k += 4) {
    float wl0 = Wl[(k + 0) * HID + f], wr0 = Wr[(k + 0) * HID + f];
    float wl1 = Wl[(k + 1) * HID + f], wr1 = Wr[(k + 1) * HID + f];
    float wl2 = Wl[(k + 2) * HID + f], wr2 = Wr[(k + 2) * HID + f];
    float wl3 = Wl[(k + 3) * HID + f], wr3 = Wr[(k + 3) * HID + f];
#pragma unroll
    for (int j = 0; j < 8; ++j) {
      float4 nv = *reinterpret_cast<const float4*>(&nt[j][k]);
      float4 hv = *reinterpret_cast<const float4*>(&ht[j][k]);
      acc[j] += nv.x * wl0 + nv.y * wl1 + nv.z * wl2 + nv.w * wl3
              + hv.x * wr0 + hv.y * wr1 + hv.z * wr2 + hv.w * wr3;
    }
  }
  float blv = sage_bl[f], gv = g[f], bbv = bb[f];
  float mw0 = mort_W[f], mw1 = mort_W[64 + f], mw2 = mort_W[128 + f];
  float hw0 = hours_W[f], hw1 = hours_W[64 + f], hw2 = hours_W[128 + f];
  float dwv[12];
#pragma unroll
  for (int rr = 0; rr < 3; ++rr)
#pragma unroll
    for (int c = 0; c < 4; ++c)
      dwv[rr * 4 + c] = disc_W[(rr * 64 + f) * 4 + c];
#pragma unroll
  for (int j = 0; j < 8; ++j) {
    float v = acc[j] + blv;
    float mu = wsum(v) * (1.f / HID);
    float dv = v - mu;
    float var = wsum(dv * dv) * (1.f / HID);
    float h = dv * rsqrtf(var + 1e-5f) * gv + bbv;
    h = h > 0.f ? h : 0.f;
    int n = n0 + j;
    float m = (mask[n] != 0) ? 1.f : 0.f;
    float v2 = (h + ht[j][f]) * m;                        // h3
    float v1 = ht[j][f] * m;                              // h2
    float v0 = __half2float(h_init16[(size_t)n * HID + f]) * m;
    float pm = v0 * mw0 + v1 * mw1 + v2 * mw2;
    float ph = v0 * hw0 + v1 * hw1 + v2 * hw2;
    float d0 = v0 * dwv[0] + v1 * dwv[4] + v2 * dwv[8];
    float d1 = v0 * dwv[1] + v1 * dwv[5] + v2 * dwv[9];
    float d2 = v0 * dwv[2] + v1 * dwv[6] + v2 * dwv[10];
    float d3 = v0 * dwv[3] + v1 * dwv[7] + v2 * dwv[11];
    pm = wsum(pm); ph = wsum(ph);
    d0 = wsum(d0); d1 = wsum(d1); d2 = wsum(d2); d3 = wsum(d3);
    if (f == 0) {
      out[n] = pm + mort_b[0];
      out[N_NODES + n] = ph + hours_b[0];
      float* dd = out + 2 * N_NODES + (size_t)n * 4;
      dd[0] = d0 + disc_b[0];
      dd[1] = d1 + disc_b[1];
      dd[2] = d2 + disc_b[2];
      dd[3] = d3 + disc_b[3];
    }
  }
}

extern "C" void kernel_launch(void* const* d_in, const int* in_sizes, int n_in,
                              void* d_out, int out_size, void* d_ws, size_t ws_size,
                              hipStream_t stream) {
  const float* x       = (const float*)d_in[0];
  const int*   ei      = (const int*)d_in[1];
  const float* ew      = (const float*)d_in[2];
  const int*   mask    = (const int*)d_in[3];
  const float* gcn_W   = (const float*)d_in[4];
  const float* gcn_b   = (const float*)d_in[5];
  const float* proj_W  = (const float*)d_in[6];
  const float* proj_b  = (const float*)d_in[7];
  const float* ln1_g   = (const float*)d_in[8];
  const float* ln1_b   = (const float*)d_in[9];
  const float* gat_Wl  = (const float*)d_in[10];
  const float* gat_Wr  = (const float*)d_in[11];
  const float* gat_att = (const float*)d_in[12];
  const float* gat_b   = (const float*)d_in[13];
  const float* ln2_g   = (const float*)d_in[14];
  const float* ln2_b   = (const float*)d_in[15];
  const float* sage_Wl = (const float*)d_in[16];
  const float* sage_bl = (const float*)d_in[17];
  const float* sage_Wr = (const float*)d_in[18];
  const float* ln3_g   = (const float*)d_in[19];
  const float* ln3_b   = (const float*)d_in[20];
  // d_in[21..24]: edge-MLP params — output unused by the reference; skipped.
  const float* mort_W  = (const float*)d_in[25];
  const float* mort_b  = (const float*)d_in[26];
  const float* hours_W = (const float*)d_in[27];
  const float* hours_b = (const float*)d_in[28];
  const float* disc_W  = (const float*)d_in[29];
  const float* disc_b  = (const float*)d_in[30];

  const int* src = ei;
  const int* dst = ei + N_EDGES;
  float* out = (float*)d_out;

  // ---- workspace layout ----
  float* ws = (float*)d_ws;
  const size_t F = (size_t)N_NODES * HID;  // 6.4M floats
  __half* xp16  = (__half*)(ws + 2 * F);           // N*64 halfs
  __half* xl    = (__half*)(ws + 3 * F);           // N*256 halfs
  __half* xw16  = xl;                              // N*64 halfs, dead before xl written
  __half* nmean16 = (__half*)(ws + 3 * F);         // N*64 halfs, xl dead by SAGE
  __half* xr    = (__half*)(ws + 3 * F + (size_t)N_NODES * 128);
  __half* h2_16 = (__half*)(ws + 3 * F + (size_t)N_NODES * 256);
  __half* h_init16 = (__half*)(ws + 3 * F + (size_t)N_NODES * 288);
  float* tail   = ws + 3 * F + (size_t)N_NODES * 320;
  int*   csr_src = (int*)tail;           tail += N_EDGES;
  float* csr_w   = tail;                 tail += N_EDGES;
  int*   row_ptr = (int*)tail;           tail += N_NODES + 64;
  int*   cursor  = (int*)tail;           tail += N_NODES;
  int*   cnt     = (int*)tail;           tail += N_NODES;
  int*   partial = (int*)tail;           tail += N_NODES;
  int*   bsum    = (int*)tail;           tail += 128;
  float* dinv    = tail;

  const int GE = (N_EDGES + 255) / 256;
  const int GN = (N_NODES + 255) / 256;
  const int GB = N_NODES / (16 * GEMM_NT);  // 1250 blocks for MFMA GEMMs

  // --- CSR build (by dst) ---
  hipMemsetAsync(cnt, 0, N_NODES * sizeof(int), stream);
  k_hist<<<GE, 256, 0, stream>>>(dst, cnt);
  k_scan1<<<SCAN_BLK, 256, 0, stream>>>(cnt, partial, bsum);
  k_scan3<<<GN, 256, 0, stream>>>(partial, bsum, row_ptr, cursor);
  k_fill<<<GE, 256, 0, stream>>>(src, dst, ew, cursor, csr_src, csr_w);

  // --- GCN layer ---
  k_in_gemm_mfma<<<GB, 512, 0, stream>>>(x, gcn_W, proj_W, proj_b, xw16, xp16);
  k_deg<<<GN, 256, 0, stream>>>(row_ptr, csr_w, dinv);
  k_gcn_fused<<<N_NODES / 4, 256, 0, stream>>>(row_ptr, csr_src, csr_w, dinv, xw16,
                                               xp16, gcn_b, ln1_g, ln1_b, h_init16);

  // --- GATv2 layer ---
  k_gat_gemm_mfma<<<GB, 512, 0, stream>>>(h_init16, gat_Wl, gat_Wr, xl, xr);
  k_gat_fused<<<N_NODES / 4, 256, 0, stream>>>(row_ptr, csr_src, xl, xr, gat_att,
                                               gat_b, ln2_g, ln2_b, h_init16, h2_16);

  // --- SAGE layer + heads (fused) ---
  k_sage_gather<<<N_NODES / 4, 256, 0, stream>>>(row_ptr, csr_src, h2_16, nmean16);
  k_sage_gemm_ln_heads<<<N_NODES / 8, 64, 0, stream>>>(
      nmean16, h2_16, h_init16, sage_Wl, sage_Wr, sage_bl, ln3_g, ln3_b, mask,
      mort_W, mort_b, hours_W, hours_b, disc_W, disc_b, out);
}